// Round 1
// baseline (1749.297 us; speedup 1.0000x reference)
//
#include <hip/hip_runtime.h>
#include <math.h>

#define B_  2
#define T_  2048
#define D_  1024
#define H_  16
#define HD_ 64
#define CD_ 3072   // 3*D

// ---------------- GEMM NT: C[M,N] = A[M,K] * B[N,K]^T  (fp32) ----------------
#define BM 128
#define BN 128
#define BKK 16

__global__ __launch_bounds__(256)
void gemm_nt(const float* __restrict__ A, const float* __restrict__ Bm,
             float* __restrict__ C, int M, int N, int K) {
    __shared__ float As[BKK][BM + 4];
    __shared__ float Bs[BKK][BN + 4];
    const int bm = blockIdx.y * BM;
    const int bn = blockIdx.x * BN;
    const int tid = threadIdx.x;
    const int tx = tid & 15;   // -> n
    const int ty = tid >> 4;   // -> m

    float acc[8][8];
#pragma unroll
    for (int i = 0; i < 8; ++i)
#pragma unroll
        for (int j = 0; j < 8; ++j) acc[i][j] = 0.f;

    for (int k0 = 0; k0 < K; k0 += BKK) {
#pragma unroll
        for (int i = 0; i < 2; ++i) {
            int s = tid + i * 256;        // 0..511
            int m = s >> 2;               // 0..127
            int kq = (s & 3) << 2;        // 0,4,8,12
            float4 va = *(const float4*)(A + (size_t)(bm + m) * K + k0 + kq);
            As[kq + 0][m] = va.x; As[kq + 1][m] = va.y;
            As[kq + 2][m] = va.z; As[kq + 3][m] = va.w;
            float4 vb = *(const float4*)(Bm + (size_t)(bn + m) * K + k0 + kq);
            Bs[kq + 0][m] = vb.x; Bs[kq + 1][m] = vb.y;
            Bs[kq + 2][m] = vb.z; Bs[kq + 3][m] = vb.w;
        }
        __syncthreads();
#pragma unroll
        for (int k = 0; k < BKK; ++k) {
            float a[8], b[8];
#pragma unroll
            for (int i = 0; i < 8; ++i) a[i] = As[k][ty * 8 + i];
#pragma unroll
            for (int j = 0; j < 8; ++j) b[j] = Bs[k][tx * 8 + j];
#pragma unroll
            for (int i = 0; i < 8; ++i)
#pragma unroll
                for (int j = 0; j < 8; ++j)
                    acc[i][j] = fmaf(a[i], b[j], acc[i][j]);
        }
        __syncthreads();
    }
#pragma unroll
    for (int i = 0; i < 8; ++i) {
        float* cp = C + (size_t)(bm + ty * 8 + i) * N + bn + tx * 8;
#pragma unroll
        for (int j = 0; j < 8; j += 4) {
            float4 v = make_float4(acc[i][j], acc[i][j + 1], acc[i][j + 2], acc[i][j + 3]);
            *(float4*)(cp + j) = v;
        }
    }
}

// ---------------- beta / g projections ----------------
__global__ __launch_bounds__(256)
void proj_bg(const float* __restrict__ x, const float* __restrict__ Wb,
             const float* __restrict__ Wa, const float* __restrict__ dt_bias,
             const float* __restrict__ A_log,
             float* __restrict__ beta, float* __restrict__ g) {
    const int m = blockIdx.x;               // row in [0, B*T)
    const float* xr = x + (size_t)m * D_;
    __shared__ float xs[D_];
    for (int i = threadIdx.x; i < D_; i += 256) xs[i] = xr[i];
    __syncthreads();
    const int wave = threadIdx.x >> 6;
    const int lane = threadIdx.x & 63;
    for (int d = wave; d < 32; d += 4) {    // 0..15 -> beta, 16..31 -> g
        const float* w = (d < 16) ? (Wb + (size_t)d * D_) : (Wa + (size_t)(d - 16) * D_);
        float s = 0.f;
        for (int i = lane; i < D_; i += 64) s += xs[i] * w[i];
#pragma unroll
        for (int off = 32; off > 0; off >>= 1) s += __shfl_down(s, off, 64);
        if (lane == 0) {
            if (d < 16) {
                beta[(size_t)m * H_ + d] = 1.f / (1.f + expf(-s));
            } else {
                int h = d - 16;
                float spin = s + dt_bias[h];
                float sp = (spin > 20.f) ? spin : log1pf(expf(spin));
                g[(size_t)m * H_ + h] = -expf(A_log[h]) * sp;
            }
        }
    }
}

// ---------------- causal depthwise conv (K=4) + SiLU ----------------
__global__ __launch_bounds__(256)
void conv_silu(const float* __restrict__ mixed, const float* __restrict__ conv_w,
               float* __restrict__ qkv) {
    int idx = blockIdx.x * 256 + threadIdx.x;   // over B*T*CD
    const int total = B_ * T_ * CD_;
    if (idx >= total) return;
    int c = idx % CD_;
    int t = (idx / CD_) % T_;
    float4 w = *(const float4*)(conv_w + (size_t)c * 4);
    const float* base = mixed + idx;
    float s = base[0] * w.w;
    if (t >= 1) s += base[-CD_] * w.z;
    if (t >= 2) s += base[-2 * CD_] * w.y;
    if (t >= 3) s += base[-3 * CD_] * w.x;
    qkv[idx] = s / (1.f + expf(-s));            // silu
}

// ---------------- l2norm on q and k head-vectors (in place) ----------------
__global__ __launch_bounds__(256)
void l2norm_qk(float* __restrict__ qkv) {
    const int vec = blockIdx.x * 4 + (threadIdx.x >> 6);  // [0, 2*B*T*H)
    const int lane = threadIdx.x & 63;
    const int part = vec >> 16;          // B*T*H = 65536: 0 = q, 1 = k
    const int r = vec & 65535;
    const int h = r & 15;
    const size_t bt = (size_t)(r >> 4);
    float* p = qkv + bt * CD_ + (size_t)part * D_ + h * HD_ + lane;
    float v = *p;
    float s = v * v;
#pragma unroll
    for (int off = 32; off > 0; off >>= 1) s += __shfl_xor(s, off, 64);
    float scale = rsqrtf(s + 1e-6f);
    if (part == 0) scale *= 0.125f;      // HD^-0.5
    *p = v * scale;
}

// ---------------- sequential gated scan ----------------
// 64 blocks: one per (b,h,vhalf). 256 threads: vcol = vhalf*32 + tid>>3,
// d-chunk = (tid&7)*8. State S[8] in registers. Distance-2 prefetch.
__global__ __launch_bounds__(256)
void scan_kernel(const float* __restrict__ qkv, const float* __restrict__ beta,
                 const float* __restrict__ gg, float* __restrict__ o) {
    const int blk = blockIdx.x;          // 0..63
    const int bh = blk >> 1;
    const int vhalf = blk & 1;
    const int b = bh >> 4, h = bh & 15;
    const int tid = threadIdx.x;
    const int vcol = vhalf * 32 + (tid >> 3);
    const int dbase = (tid & 7) << 3;

    const float* qp = qkv + (size_t)b * T_ * CD_ + h * HD_ + dbase;
    const float* kp = qp + D_;
    const float* vp = qkv + (size_t)b * T_ * CD_ + 2 * D_ + h * HD_ + vcol;
    const float* gp = gg + (size_t)b * T_ * H_ + h;
    const float* bp = beta + (size_t)b * T_ * H_ + h;
    float* op = o + (size_t)b * T_ * D_ + h * HD_ + vcol;

    float S[8];
#pragma unroll
    for (int i = 0; i < 8; ++i) S[i] = 0.f;

    float4 k1[2], q1[2], k2[2], q2[2];
    float v1, g1v, b1v, v2, g2v, b2v;
    // prologue: t=0 -> set1, t=1 -> set2
#pragma unroll
    for (int i = 0; i < 2; ++i) {
        k1[i] = *(const float4*)(kp + i * 4);
        q1[i] = *(const float4*)(qp + i * 4);
        k2[i] = *(const float4*)(kp + CD_ + i * 4);
        q2[i] = *(const float4*)(qp + CD_ + i * 4);
    }
    v1 = vp[0];   g1v = gp[0];  b1v = bp[0];
    v2 = vp[CD_]; g2v = gp[H_]; b2v = bp[H_];

    for (int t = 0; t < T_; ++t) {
        float4 ck[2], cq[2];
        ck[0] = k1[0]; ck[1] = k1[1]; cq[0] = q1[0]; cq[1] = q1[1];
        float cv = v1, cgv = g1v, cbv = b1v;
        // shift set2 -> set1
        k1[0] = k2[0]; k1[1] = k2[1]; q1[0] = q2[0]; q1[1] = q2[1];
        v1 = v2; g1v = g2v; b1v = b2v;
        // load t+2 -> set2
        if (t + 2 < T_) {
            const float* kpn = kp + (size_t)(t + 2) * CD_;
            const float* qpn = qp + (size_t)(t + 2) * CD_;
#pragma unroll
            for (int i = 0; i < 2; ++i) {
                k2[i] = *(const float4*)(kpn + i * 4);
                q2[i] = *(const float4*)(qpn + i * 4);
            }
            v2 = vp[(size_t)(t + 2) * CD_];
            g2v = gp[(size_t)(t + 2) * H_];
            b2v = bp[(size_t)(t + 2) * H_];
        }

        float a = expf(cgv);
        float kvs = cv * cbv;
        float po = 0.f;
#pragma unroll
        for (int i = 0; i < 2; ++i) {
            S[4 * i + 0] = fmaf(S[4 * i + 0], a, ck[i].x * kvs); po = fmaf(cq[i].x, S[4 * i + 0], po);
            S[4 * i + 1] = fmaf(S[4 * i + 1], a, ck[i].y * kvs); po = fmaf(cq[i].y, S[4 * i + 1], po);
            S[4 * i + 2] = fmaf(S[4 * i + 2], a, ck[i].z * kvs); po = fmaf(cq[i].z, S[4 * i + 2], po);
            S[4 * i + 3] = fmaf(S[4 * i + 3], a, ck[i].w * kvs); po = fmaf(cq[i].w, S[4 * i + 3], po);
        }
        po += __shfl_xor(po, 1, 64);
        po += __shfl_xor(po, 2, 64);
        po += __shfl_xor(po, 4, 64);
        if ((tid & 7) == 0) op[(size_t)t * D_] = po;
    }
}

// ---------------- gated RMSNorm over head dim ----------------
__global__ __launch_bounds__(256)
void rmsnorm_gate(const float* __restrict__ o, const float* __restrict__ z,
                  float* __restrict__ normed) {
    const int vec = blockIdx.x * 4 + (threadIdx.x >> 6);  // [0, B*T*H)
    const int lane = threadIdx.x & 63;
    const size_t bt = (size_t)(vec >> 4);
    const int h = vec & 15;
    const size_t off = bt * D_ + h * HD_ + lane;
    float ov = o[off];
    float s = ov * ov;
#pragma unroll
    for (int w = 32; w > 0; w >>= 1) s += __shfl_xor(s, w, 64);
    float inv = rsqrtf(s * (1.f / 64.f) + 1e-6f);
    float zv = z[off];
    float sz = zv / (1.f + expf(-zv));   // silu(z)
    normed[off] = ov * inv * sz;
}

extern "C" void kernel_launch(void* const* d_in, const int* in_sizes, int n_in,
                              void* d_out, int out_size, void* d_ws, size_t ws_size,
                              hipStream_t stream) {
    const float* x       = (const float*)d_in[0];
    const float* W_qkv   = (const float*)d_in[1];
    const float* conv_w  = (const float*)d_in[2];
    const float* W_z     = (const float*)d_in[3];
    const float* W_b     = (const float*)d_in[4];
    const float* W_a     = (const float*)d_in[5];
    const float* dt_bias = (const float*)d_in[6];
    const float* A_log   = (const float*)d_in[7];
    const float* W_out   = (const float*)d_in[8];
    float* out = (float*)d_out;

    float* ws     = (float*)d_ws;
    float* mixed  = ws;                  // 12,582,912 floats (48 MB)
    float* qkv    = ws + 12582912;       // 12,582,912 floats (48 MB)
    float* z      = ws + 25165824;       //  4,194,304 floats (16 MB)
    float* betab  = ws + 29360128;       //     65,536
    float* gb     = ws + 29425664;       //     65,536
    float* o      = ws;                  // reuse mixed (dead after conv)
    float* normed = ws + 4194304;        // reuse mixed upper part

    const int M = B_ * T_;               // 4096
    dim3 blk(256);

    gemm_nt<<<dim3(CD_ / BN, M / BM), blk, 0, stream>>>(x, W_qkv, mixed, M, CD_, D_);
    gemm_nt<<<dim3(D_ / BN, M / BM), blk, 0, stream>>>(x, W_z, z, M, D_, D_);
    proj_bg<<<dim3(M), blk, 0, stream>>>(x, W_b, W_a, dt_bias, A_log, betab, gb);
    conv_silu<<<dim3((M * CD_) / 256), blk, 0, stream>>>(mixed, conv_w, qkv);
    l2norm_qk<<<dim3(2 * M * H_ / 4), blk, 0, stream>>>(qkv);
    scan_kernel<<<dim3(64), blk, 0, stream>>>(qkv, betab, gb, o);
    rmsnorm_gate<<<dim3(M * H_ / 4), blk, 0, stream>>>(o, z, normed);
    gemm_nt<<<dim3(D_ / BN, M / BM), blk, 0, stream>>>(normed, W_out, out, M, D_, D_);
}

// Round 2
// 833.565 us; speedup vs baseline: 2.0986x; 2.0986x over previous
//
#include <hip/hip_runtime.h>
#include <math.h>

#define B_  2
#define T_  2048
#define D_  1024
#define H_  16
#define HD_ 64
#define CD_ 3072   // 3*D
#define L_  64     // chunk length
#define NC_ 32     // T/L chunks
#define PS  65     // padded LDS stride

// ---------------- GEMM NT: C[M,N] = A[M,K] * B[N,K]^T  (fp32) ----------------
#define BM 128
#define BN 128
#define BKK 16

__global__ __launch_bounds__(256)
void gemm_nt(const float* __restrict__ A, const float* __restrict__ Bm,
             float* __restrict__ C, int M, int N, int K) {
    __shared__ float As[BKK][BM + 4];
    __shared__ float Bs[BKK][BN + 4];
    const int bm = blockIdx.y * BM;
    const int bn = blockIdx.x * BN;
    const int tid = threadIdx.x;
    const int tx = tid & 15;   // -> n
    const int ty = tid >> 4;   // -> m

    float acc[8][8];
#pragma unroll
    for (int i = 0; i < 8; ++i)
#pragma unroll
        for (int j = 0; j < 8; ++j) acc[i][j] = 0.f;

    for (int k0 = 0; k0 < K; k0 += BKK) {
#pragma unroll
        for (int i = 0; i < 2; ++i) {
            int s = tid + i * 256;        // 0..511
            int m = s >> 2;               // 0..127
            int kq = (s & 3) << 2;        // 0,4,8,12
            float4 va = *(const float4*)(A + (size_t)(bm + m) * K + k0 + kq);
            As[kq + 0][m] = va.x; As[kq + 1][m] = va.y;
            As[kq + 2][m] = va.z; As[kq + 3][m] = va.w;
            float4 vb = *(const float4*)(Bm + (size_t)(bn + m) * K + k0 + kq);
            Bs[kq + 0][m] = vb.x; Bs[kq + 1][m] = vb.y;
            Bs[kq + 2][m] = vb.z; Bs[kq + 3][m] = vb.w;
        }
        __syncthreads();
#pragma unroll
        for (int k = 0; k < BKK; ++k) {
            float a[8], b[8];
#pragma unroll
            for (int i = 0; i < 8; ++i) a[i] = As[k][ty * 8 + i];
#pragma unroll
            for (int j = 0; j < 8; ++j) b[j] = Bs[k][tx * 8 + j];
#pragma unroll
            for (int i = 0; i < 8; ++i)
#pragma unroll
                for (int j = 0; j < 8; ++j)
                    acc[i][j] = fmaf(a[i], b[j], acc[i][j]);
        }
        __syncthreads();
    }
#pragma unroll
    for (int i = 0; i < 8; ++i) {
        float* cp = C + (size_t)(bm + ty * 8 + i) * N + bn + tx * 8;
#pragma unroll
        for (int j = 0; j < 8; j += 4) {
            float4 v = make_float4(acc[i][j], acc[i][j + 1], acc[i][j + 2], acc[i][j + 3]);
            *(float4*)(cp + j) = v;
        }
    }
}

// ---------------- beta / g projections ----------------
__global__ __launch_bounds__(256)
void proj_bg(const float* __restrict__ x, const float* __restrict__ Wb,
             const float* __restrict__ Wa, const float* __restrict__ dt_bias,
             const float* __restrict__ A_log,
             float* __restrict__ beta, float* __restrict__ g) {
    const int m = blockIdx.x;               // row in [0, B*T)
    const float* xr = x + (size_t)m * D_;
    __shared__ float xs[D_];
    for (int i = threadIdx.x; i < D_; i += 256) xs[i] = xr[i];
    __syncthreads();
    const int wave = threadIdx.x >> 6;
    const int lane = threadIdx.x & 63;
    for (int d = wave; d < 32; d += 4) {    // 0..15 -> beta, 16..31 -> g
        const float* w = (d < 16) ? (Wb + (size_t)d * D_) : (Wa + (size_t)(d - 16) * D_);
        float s = 0.f;
        for (int i = lane; i < D_; i += 64) s += xs[i] * w[i];
#pragma unroll
        for (int off = 32; off > 0; off >>= 1) s += __shfl_down(s, off, 64);
        if (lane == 0) {
            if (d < 16) {
                beta[(size_t)m * H_ + d] = 1.f / (1.f + expf(-s));
            } else {
                int h = d - 16;
                float spin = s + dt_bias[h];
                float sp = (spin > 20.f) ? spin : log1pf(expf(spin));
                g[(size_t)m * H_ + h] = -expf(A_log[h]) * sp;
            }
        }
    }
}

// ---------------- causal depthwise conv (K=4) + SiLU ----------------
__global__ __launch_bounds__(256)
void conv_silu(const float* __restrict__ mixed, const float* __restrict__ conv_w,
               float* __restrict__ qkv) {
    int idx = blockIdx.x * 256 + threadIdx.x;   // over B*T*CD
    const int total = B_ * T_ * CD_;
    if (idx >= total) return;
    int c = idx % CD_;
    int t = (idx / CD_) % T_;
    float4 w = *(const float4*)(conv_w + (size_t)c * 4);
    const float* base = mixed + idx;
    float s = base[0] * w.w;
    if (t >= 1) s += base[-CD_] * w.z;
    if (t >= 2) s += base[-2 * CD_] * w.y;
    if (t >= 3) s += base[-3 * CD_] * w.x;
    qkv[idx] = s / (1.f + expf(-s));            // silu
}

// ---------------- l2norm on q and k head-vectors (in place) ----------------
__global__ __launch_bounds__(256)
void l2norm_qk(float* __restrict__ qkv) {
    const int vec = blockIdx.x * 4 + (threadIdx.x >> 6);  // [0, 2*B*T*H)
    const int lane = threadIdx.x & 63;
    const int part = vec >> 16;          // B*T*H = 65536: 0 = q, 1 = k
    const int r = vec & 65535;
    const int h = r & 15;
    const size_t bt = (size_t)(r >> 4);
    float* p = qkv + bt * CD_ + (size_t)part * D_ + h * HD_ + lane;
    float v = *p;
    float s = v * v;
#pragma unroll
    for (int off = 32; off > 0; off >>= 1) s += __shfl_xor(s, off, 64);
    float scale = rsqrtf(s + 1e-6f);
    if (part == 0) scale *= 0.125f;      // HD^-0.5
    *p = v * scale;
}

// ---------------- chunked gated scan: phase 1 (per-chunk dS, cum, a_c) -------
__global__ __launch_bounds__(256)
void chunk_phase1(const float* __restrict__ qkv, const float* __restrict__ beta,
                  const float* __restrict__ gg, float* __restrict__ dS,
                  float* __restrict__ cum, float* __restrict__ ac) {
    const int cid = blockIdx.x;           // (b*H+h)*NC + c
    const int c = cid & (NC_ - 1);
    const int bh = cid >> 5;
    const int b = bh >> 4, h = bh & 15;
    const int tid = threadIdx.x;
    const int t0 = c * L_;

    __shared__ float kS[L_][PS];
    __shared__ float vS[L_][PS];
    __shared__ float cumS[L_];
    __shared__ float wS[L_];

    for (int i = tid; i < L_ * 16; i += 256) {
        int s = i >> 4;
        int dq = (i & 15) << 2;
        const float* rowk = qkv + (size_t)(b * T_ + t0 + s) * CD_ + D_ + h * HD_ + dq;
        float4 t4 = *(const float4*)rowk;
        kS[s][dq] = t4.x; kS[s][dq + 1] = t4.y; kS[s][dq + 2] = t4.z; kS[s][dq + 3] = t4.w;
        t4 = *(const float4*)(rowk + D_);
        vS[s][dq] = t4.x; vS[s][dq + 1] = t4.y; vS[s][dq + 2] = t4.z; vS[s][dq + 3] = t4.w;
    }
    if (tid == 0) {
        float s = 0.f;
        for (int i = 0; i < L_; ++i) {
            s += gg[(size_t)(b * T_ + t0 + i) * H_ + h];
            cumS[i] = s;
        }
    }
    __syncthreads();
    const float cumEnd = cumS[L_ - 1];
    if (tid < L_) {
        wS[tid] = expf(cumEnd - cumS[tid]) * beta[(size_t)(b * T_ + t0 + tid) * H_ + h];
        cum[(size_t)bh * T_ + t0 + tid] = cumS[tid];
    }
    if (tid == 0) ac[cid] = expf(cumEnd);
    __syncthreads();

    const int d = tid >> 2;
    const int v0 = (tid & 3) << 4;
    float acc[16];
#pragma unroll
    for (int j = 0; j < 16; ++j) acc[j] = 0.f;
    for (int s = 0; s < L_; ++s) {
        float kw = kS[s][d] * wS[s];
#pragma unroll
        for (int j = 0; j < 16; ++j)
            acc[j] = fmaf(kw, vS[s][v0 + j], acc[j]);
    }
    float* outp = dS + (size_t)cid * 4096 + d * 64 + v0;
#pragma unroll
    for (int j = 0; j < 16; j += 4)
        *(float4*)(outp + j) = make_float4(acc[j], acc[j + 1], acc[j + 2], acc[j + 3]);
}

// ---------------- phase 2: scan over chunks (independent per state entry) ----
__global__ __launch_bounds__(256)
void chunk_phase2(const float* __restrict__ dS, const float* __restrict__ ac,
                  float* __restrict__ states) {
    const int gid = blockIdx.x * 256 + threadIdx.x;  // B*H*4096 = 131072
    const int bh = gid >> 12;
    const int e = gid & 4095;
    float s = 0.f;
    for (int c = 0; c < NC_; ++c) {
        size_t off = (size_t)(bh * NC_ + c) * 4096 + e;
        states[off] = s;                 // state ENTERING chunk c
        s = fmaf(ac[bh * NC_ + c], s, dS[off]);
    }
}

// ---------------- phase 3: per-chunk output -----------------------------
__global__ __launch_bounds__(256)
void chunk_phase3(const float* __restrict__ qkv, const float* __restrict__ beta,
                  const float* __restrict__ cum, const float* __restrict__ states,
                  float* __restrict__ o) {
    const int cid = blockIdx.x;
    const int c = cid & (NC_ - 1);
    const int bh = cid >> 5;
    const int b = bh >> 4, h = bh & 15;
    const int tid = threadIdx.x;
    const int t0 = c * L_;

    __shared__ float qS[L_][PS];
    __shared__ float kS[L_][PS];   // reused as P after QK^T
    __shared__ float vS[L_][PS];
    __shared__ float sS[L_][PS];   // S_in [d][v]
    __shared__ float cumS[L_], betaS[L_];

    for (int i = tid; i < L_ * 16; i += 256) {
        int s = i >> 4;
        int dq = (i & 15) << 2;
        const float* rowq = qkv + (size_t)(b * T_ + t0 + s) * CD_ + h * HD_ + dq;
        float4 t4 = *(const float4*)rowq;
        qS[s][dq] = t4.x; qS[s][dq + 1] = t4.y; qS[s][dq + 2] = t4.z; qS[s][dq + 3] = t4.w;
        t4 = *(const float4*)(rowq + D_);
        kS[s][dq] = t4.x; kS[s][dq + 1] = t4.y; kS[s][dq + 2] = t4.z; kS[s][dq + 3] = t4.w;
        t4 = *(const float4*)(rowq + 2 * D_);
        vS[s][dq] = t4.x; vS[s][dq + 1] = t4.y; vS[s][dq + 2] = t4.z; vS[s][dq + 3] = t4.w;
        t4 = *(const float4*)(states + (size_t)cid * 4096 + s * 64 + dq);
        sS[s][dq] = t4.x; sS[s][dq + 1] = t4.y; sS[s][dq + 2] = t4.z; sS[s][dq + 3] = t4.w;
    }
    if (tid < L_) {
        cumS[tid] = cum[(size_t)bh * T_ + t0 + tid];
        betaS[tid] = beta[(size_t)(b * T_ + t0 + tid) * H_ + h];
    }
    __syncthreads();

    const int t = tid >> 2;
    const int j0 = (tid & 3) << 4;
    const float ct = cumS[t];

    float p[16];
#pragma unroll
    for (int jj = 0; jj < 16; ++jj) {
        int s = j0 + jj;
        if (s <= t) {
            float acc = 0.f;
            for (int d = 0; d < L_; ++d) acc = fmaf(qS[t][d], kS[s][d], acc);
            p[jj] = expf(ct - cumS[s]) * betaS[s] * acc;
        } else {
            p[jj] = 0.f;
        }
    }
    __syncthreads();
#pragma unroll
    for (int jj = 0; jj < 16; ++jj) kS[t][j0 + jj] = p[jj];
    __syncthreads();

    float accO[16];
#pragma unroll
    for (int jj = 0; jj < 16; ++jj) accO[jj] = 0.f;
    for (int d = 0; d < L_; ++d) {
        float qd = qS[t][d];
#pragma unroll
        for (int jj = 0; jj < 16; ++jj)
            accO[jj] = fmaf(qd, sS[d][j0 + jj], accO[jj]);
    }
    const float ect = expf(ct);
#pragma unroll
    for (int jj = 0; jj < 16; ++jj) accO[jj] *= ect;
    for (int s = 0; s < L_; ++s) {
        float pts = kS[t][s];
#pragma unroll
        for (int jj = 0; jj < 16; ++jj)
            accO[jj] = fmaf(pts, vS[s][j0 + jj], accO[jj]);
    }
    float* op = o + (size_t)(b * T_ + t0 + t) * D_ + h * HD_ + j0;
#pragma unroll
    for (int jj = 0; jj < 16; jj += 4)
        *(float4*)(op + jj) = make_float4(accO[jj], accO[jj + 1], accO[jj + 2], accO[jj + 3]);
}

// ---------------- gated RMSNorm over head dim ----------------
__global__ __launch_bounds__(256)
void rmsnorm_gate(const float* __restrict__ o, const float* __restrict__ z,
                  float* __restrict__ normed) {
    const int vec = blockIdx.x * 4 + (threadIdx.x >> 6);  // [0, B*T*H)
    const int lane = threadIdx.x & 63;
    const size_t bt = (size_t)(vec >> 4);
    const int h = vec & 15;
    const size_t off = bt * D_ + h * HD_ + lane;
    float ov = o[off];
    float s = ov * ov;
#pragma unroll
    for (int w = 32; w > 0; w >>= 1) s += __shfl_xor(s, w, 64);
    float inv = rsqrtf(s * (1.f / 64.f) + 1e-6f);
    float zv = z[off];
    float sz = zv / (1.f + expf(-zv));   // silu(z)
    normed[off] = ov * inv * sz;
}

extern "C" void kernel_launch(void* const* d_in, const int* in_sizes, int n_in,
                              void* d_out, int out_size, void* d_ws, size_t ws_size,
                              hipStream_t stream) {
    const float* x       = (const float*)d_in[0];
    const float* W_qkv   = (const float*)d_in[1];
    const float* conv_w  = (const float*)d_in[2];
    const float* W_z     = (const float*)d_in[3];
    const float* W_b     = (const float*)d_in[4];
    const float* W_a     = (const float*)d_in[5];
    const float* dt_bias = (const float*)d_in[6];
    const float* A_log   = (const float*)d_in[7];
    const float* W_out   = (const float*)d_in[8];
    float* out = (float*)d_out;

    float* ws     = (float*)d_ws;
    float* mixed  = ws;                  // [0, 12582912)  48 MB, dead after conv
    float* qkv    = ws + 12582912;       // [.., 25165824) 48 MB, dead after phase3
    float* z      = ws + 25165824;       // 16 MB
    float* betab  = ws + 29360128;       // 65,536
    float* gb     = ws + 29425664;       // 65,536
    // carved out of the dead `mixed` region:
    float* dS     = ws;                  // 4,194,304 floats (phase1 -> phase2)
    float* states = ws + 4194304;        // 4,194,304 floats (phase2 -> phase3)
    float* cum    = ws + 8388608;        // 65,536
    float* ac     = ws + 8454144;        // 1,024
    float* o      = ws;                  // reuse dS region (dead after phase2)
    float* normed = ws + 12582912;       // reuse qkv region (dead after phase3)

    const int M = B_ * T_;               // 4096
    dim3 blk(256);

    gemm_nt<<<dim3(CD_ / BN, M / BM), blk, 0, stream>>>(x, W_qkv, mixed, M, CD_, D_);
    gemm_nt<<<dim3(D_ / BN, M / BM), blk, 0, stream>>>(x, W_z, z, M, D_, D_);
    proj_bg<<<dim3(M), blk, 0, stream>>>(x, W_b, W_a, dt_bias, A_log, betab, gb);
    conv_silu<<<dim3((M * CD_) / 256), blk, 0, stream>>>(mixed, conv_w, qkv);
    l2norm_qk<<<dim3(2 * M * H_ / 4), blk, 0, stream>>>(qkv);
    chunk_phase1<<<dim3(B_ * H_ * NC_), blk, 0, stream>>>(qkv, betab, gb, dS, cum, ac);
    chunk_phase2<<<dim3(B_ * H_ * 4096 / 256), blk, 0, stream>>>(dS, ac, states);
    chunk_phase3<<<dim3(B_ * H_ * NC_), blk, 0, stream>>>(qkv, betab, cum, states, o);
    rmsnorm_gate<<<dim3(M * H_ / 4), blk, 0, stream>>>(o, z, normed);
    gemm_nt<<<dim3(D_ / BN, M / BM), blk, 0, stream>>>(normed, W_out, out, M, D_, D_);
}

// Round 3
// 396.187 us; speedup vs baseline: 4.4153x; 2.1040x over previous
//
#include <hip/hip_runtime.h>
#include <math.h>

#define B_  2
#define T_  2048
#define D_  1024
#define H_  16
#define HD_ 64
#define CD_ 3072   // 3*D
#define L_  64     // chunk length
#define NC_ 32     // T/L chunks
#define PS  65     // padded LDS stride

typedef __attribute__((ext_vector_type(8))) short bf16x8;
typedef __attribute__((ext_vector_type(4))) float f32x4;
typedef __attribute__((ext_vector_type(4))) unsigned short u16x4;

__device__ __forceinline__ unsigned short f2bf(float f) {
    unsigned int u = __float_as_uint(f);
    unsigned int r = (u + 0x7fffu + ((u >> 16) & 1u)) >> 16;
    return (unsigned short)r;
}

// ---------------- fp32 -> bf16 conversion (x4 vectorized) ----------------
__global__ __launch_bounds__(256)
void cvt_bf16(const float* __restrict__ in, unsigned short* __restrict__ out, int n4) {
    int i = blockIdx.x * 256 + threadIdx.x;
    if (i >= n4) return;
    float4 a = ((const float4*)in)[i];
    u16x4 o;
    o.x = f2bf(a.x); o.y = f2bf(a.y); o.z = f2bf(a.z); o.w = f2bf(a.w);
    ((u16x4*)out)[i] = o;
}

// ---------------- bf16 MFMA GEMM NT: C[M,N] = A[M,K] * B[N,K]^T ----------------
// m97 structure: 128x128 tile, BK=32, 4 waves, global_load_lds width=16.
__global__ __launch_bounds__(256)
void gemm_bt_bf16(const unsigned short* __restrict__ A,
                  const unsigned short* __restrict__ Bw,
                  float* __restrict__ C, int M, int N, int K) {
    __shared__ short As[128 * 32];
    __shared__ short Bs[128 * 32];
    const int tid = threadIdx.x;
    const int bm = blockIdx.y * 128;
    const int bn = blockIdx.x * 128;
    const int wave = tid >> 6;
    const int lane = tid & 63;
    const int wm = (wave >> 1) * 64;
    const int wn = (wave & 1) * 64;
    const int lr = lane & 15;
    const int lk = lane >> 4;

    f32x4 acc[4][4] = {};

    // staging: thread t covers LDS bytes [t*16, t*16+16) (+4096 for 2nd issue)
    const int srow = tid >> 2;           // 0..63
    const int scol = (tid & 3) << 3;     // bf16 col: 0,8,16,24
    const unsigned short* Ag = A + (size_t)(bm + srow) * K + scol;
    const unsigned short* Bg = Bw + (size_t)(bn + srow) * K + scol;

    short* AsP = As + tid * 8;           // byte offset t*16
    short* BsP = Bs + tid * 8;

    const short* pA = As + (wm + lr) * 32 + lk * 8;
    const short* pB = Bs + (wn + lr) * 32 + lk * 8;

    for (int k0 = 0; k0 < K; k0 += 32) {
        __builtin_amdgcn_global_load_lds(
            (const __attribute__((address_space(1))) void*)(Ag + k0),
            (__attribute__((address_space(3))) void*)AsP, 16, 0, 0);
        __builtin_amdgcn_global_load_lds(
            (const __attribute__((address_space(1))) void*)(Ag + (size_t)64 * K + k0),
            (__attribute__((address_space(3))) void*)(AsP + 2048), 16, 0, 0);
        __builtin_amdgcn_global_load_lds(
            (const __attribute__((address_space(1))) void*)(Bg + k0),
            (__attribute__((address_space(3))) void*)BsP, 16, 0, 0);
        __builtin_amdgcn_global_load_lds(
            (const __attribute__((address_space(1))) void*)(Bg + (size_t)64 * K + k0),
            (__attribute__((address_space(3))) void*)(BsP + 2048), 16, 0, 0);
        __syncthreads();   // drains vmcnt before barrier (compiler-inserted)

        bf16x8 a[4], b[4];
#pragma unroll
        for (int mi = 0; mi < 4; ++mi) a[mi] = *(const bf16x8*)(pA + mi * 16 * 32);
#pragma unroll
        for (int ni = 0; ni < 4; ++ni) b[ni] = *(const bf16x8*)(pB + ni * 16 * 32);
#pragma unroll
        for (int mi = 0; mi < 4; ++mi)
#pragma unroll
            for (int ni = 0; ni < 4; ++ni)
                acc[mi][ni] = __builtin_amdgcn_mfma_f32_16x16x32_bf16(
                    a[mi], b[ni], acc[mi][ni], 0, 0, 0);
        __syncthreads();   // protect LDS before next stage
    }

    const int r0 = lk * 4;
#pragma unroll
    for (int mi = 0; mi < 4; ++mi)
#pragma unroll
        for (int ni = 0; ni < 4; ++ni) {
            float* cp = C + (size_t)(bm + wm + mi * 16 + r0) * N + bn + wn + ni * 16 + lr;
#pragma unroll
            for (int r = 0; r < 4; ++r)
                cp[(size_t)r * N] = acc[mi][ni][r];
        }
}

// ---------------- beta / g projections (fp32) ----------------
__global__ __launch_bounds__(256)
void proj_bg(const float* __restrict__ x, const float* __restrict__ Wb,
             const float* __restrict__ Wa, const float* __restrict__ dt_bias,
             const float* __restrict__ A_log,
             float* __restrict__ beta, float* __restrict__ g) {
    const int m = blockIdx.x;               // row in [0, B*T)
    const float* xr = x + (size_t)m * D_;
    __shared__ float xs[D_];
    for (int i = threadIdx.x; i < D_; i += 256) xs[i] = xr[i];
    __syncthreads();
    const int wave = threadIdx.x >> 6;
    const int lane = threadIdx.x & 63;
    for (int d = wave; d < 32; d += 4) {    // 0..15 -> beta, 16..31 -> g
        const float* w = (d < 16) ? (Wb + (size_t)d * D_) : (Wa + (size_t)(d - 16) * D_);
        float s = 0.f;
        for (int i = lane; i < D_; i += 64) s += xs[i] * w[i];
#pragma unroll
        for (int off = 32; off > 0; off >>= 1) s += __shfl_down(s, off, 64);
        if (lane == 0) {
            if (d < 16) {
                beta[(size_t)m * H_ + d] = 1.f / (1.f + expf(-s));
            } else {
                int h = d - 16;
                float spin = s + dt_bias[h];
                float sp = (spin > 20.f) ? spin : log1pf(expf(spin));
                g[(size_t)m * H_ + h] = -expf(A_log[h]) * sp;
            }
        }
    }
}

// ---------------- causal depthwise conv (K=4) + SiLU, x4 vectorized ----------
__global__ __launch_bounds__(256)
void conv_silu4(const float* __restrict__ mixed, const float* __restrict__ conv_w,
                float* __restrict__ qkv) {
    int idx = blockIdx.x * 256 + threadIdx.x;   // over B*T*CD/4
    const int cq = idx % (CD_ / 4);
    const int bt = idx / (CD_ / 4);
    const int t = bt % T_;
    const int c0 = cq << 2;
    const float* base = mixed + (size_t)bt * CD_ + c0;
    const float4 zero = make_float4(0.f, 0.f, 0.f, 0.f);
    float4 m0 = *(const float4*)base;
    float4 m1 = (t >= 1) ? *(const float4*)(base - CD_) : zero;
    float4 m2 = (t >= 2) ? *(const float4*)(base - 2 * CD_) : zero;
    float4 m3 = (t >= 3) ? *(const float4*)(base - 3 * CD_) : zero;
    const float4* w = (const float4*)(conv_w + (size_t)c0 * 4);
    float4 w0 = w[0], w1 = w[1], w2 = w[2], w3 = w[3];
    float s0 = m0.x * w0.w + m1.x * w0.z + m2.x * w0.y + m3.x * w0.x;
    float s1 = m0.y * w1.w + m1.y * w1.z + m2.y * w1.y + m3.y * w1.x;
    float s2 = m0.z * w2.w + m1.z * w2.z + m2.z * w2.y + m3.z * w2.x;
    float s3 = m0.w * w3.w + m1.w * w3.z + m2.w * w3.y + m3.w * w3.x;
    float4 r;
    r.x = s0 / (1.f + expf(-s0));
    r.y = s1 / (1.f + expf(-s1));
    r.z = s2 / (1.f + expf(-s2));
    r.w = s3 / (1.f + expf(-s3));
    *(float4*)(qkv + (size_t)bt * CD_ + c0) = r;
}

// ---------------- l2norm on q and k head-vectors (in place) ----------------
__global__ __launch_bounds__(256)
void l2norm_qk(float* __restrict__ qkv) {
    const int vec = blockIdx.x * 4 + (threadIdx.x >> 6);  // [0, 2*B*T*H)
    const int lane = threadIdx.x & 63;
    const int part = vec >> 16;          // B*T*H = 65536: 0 = q, 1 = k
    const int r = vec & 65535;
    const int h = r & 15;
    const size_t bt = (size_t)(r >> 4);
    float* p = qkv + bt * CD_ + (size_t)part * D_ + h * HD_ + lane;
    float v = *p;
    float s = v * v;
#pragma unroll
    for (int off = 32; off > 0; off >>= 1) s += __shfl_xor(s, off, 64);
    float scale = rsqrtf(s + 1e-6f);
    if (part == 0) scale *= 0.125f;      // HD^-0.5
    *p = v * scale;
}

// ---------------- chunked gated scan: phase 1 (per-chunk dS, cum, a_c) -------
__global__ __launch_bounds__(256)
void chunk_phase1(const float* __restrict__ qkv, const float* __restrict__ beta,
                  const float* __restrict__ gg, float* __restrict__ dS,
                  float* __restrict__ cum, float* __restrict__ ac) {
    const int cid = blockIdx.x;           // (b*H+h)*NC + c
    const int c = cid & (NC_ - 1);
    const int bh = cid >> 5;
    const int b = bh >> 4, h = bh & 15;
    const int tid = threadIdx.x;
    const int t0 = c * L_;

    __shared__ float kS[L_][PS];
    __shared__ float vS[L_][PS];
    __shared__ float cumS[L_];
    __shared__ float wS[L_];

    for (int i = tid; i < L_ * 16; i += 256) {
        int s = i >> 4;
        int dq = (i & 15) << 2;
        const float* rowk = qkv + (size_t)(b * T_ + t0 + s) * CD_ + D_ + h * HD_ + dq;
        float4 t4 = *(const float4*)rowk;
        kS[s][dq] = t4.x; kS[s][dq + 1] = t4.y; kS[s][dq + 2] = t4.z; kS[s][dq + 3] = t4.w;
        t4 = *(const float4*)(rowk + D_);
        vS[s][dq] = t4.x; vS[s][dq + 1] = t4.y; vS[s][dq + 2] = t4.z; vS[s][dq + 3] = t4.w;
    }
    if (tid == 0) {
        float s = 0.f;
        for (int i = 0; i < L_; ++i) {
            s += gg[(size_t)(b * T_ + t0 + i) * H_ + h];
            cumS[i] = s;
        }
    }
    __syncthreads();
    const float cumEnd = cumS[L_ - 1];
    if (tid < L_) {
        wS[tid] = expf(cumEnd - cumS[tid]) * beta[(size_t)(b * T_ + t0 + tid) * H_ + h];
        cum[(size_t)bh * T_ + t0 + tid] = cumS[tid];
    }
    if (tid == 0) ac[cid] = expf(cumEnd);
    __syncthreads();

    const int d = tid >> 2;
    const int v0 = (tid & 3) << 4;
    float acc[16];
#pragma unroll
    for (int j = 0; j < 16; ++j) acc[j] = 0.f;
    for (int s = 0; s < L_; ++s) {
        float kw = kS[s][d] * wS[s];
#pragma unroll
        for (int j = 0; j < 16; ++j)
            acc[j] = fmaf(kw, vS[s][v0 + j], acc[j]);
    }
    float* outp = dS + (size_t)cid * 4096 + d * 64 + v0;
#pragma unroll
    for (int j = 0; j < 16; j += 4)
        *(float4*)(outp + j) = make_float4(acc[j], acc[j + 1], acc[j + 2], acc[j + 3]);
}

// ---------------- phase 2: scan over chunks, IN PLACE (dS -> states) ---------
__global__ __launch_bounds__(256)
void chunk_phase2(float* __restrict__ dS, const float* __restrict__ ac) {
    const int gid = blockIdx.x * 256 + threadIdx.x;  // B*H*4096 = 131072
    const int bh = gid >> 12;
    const int e = gid & 4095;
    float s = 0.f;
    for (int c = 0; c < NC_; ++c) {
        size_t off = (size_t)(bh * NC_ + c) * 4096 + e;
        float tmp = dS[off];
        dS[off] = s;                 // state ENTERING chunk c
        s = fmaf(ac[bh * NC_ + c], s, tmp);
    }
}

// ---------------- phase 3: per-chunk output -----------------------------
__global__ __launch_bounds__(256)
void chunk_phase3(const float* __restrict__ qkv, const float* __restrict__ beta,
                  const float* __restrict__ cum, const float* __restrict__ states,
                  float* __restrict__ o) {
    const int cid = blockIdx.x;
    const int c = cid & (NC_ - 1);
    const int bh = cid >> 5;
    const int b = bh >> 4, h = bh & 15;
    const int tid = threadIdx.x;
    const int t0 = c * L_;

    __shared__ float qS[L_][PS];
    __shared__ float kS[L_][PS];   // reused as P after QK^T
    __shared__ float vS[L_][PS];
    __shared__ float sS[L_][PS];   // S_in [d][v]
    __shared__ float cumS[L_], betaS[L_];

    for (int i = tid; i < L_ * 16; i += 256) {
        int s = i >> 4;
        int dq = (i & 15) << 2;
        const float* rowq = qkv + (size_t)(b * T_ + t0 + s) * CD_ + h * HD_ + dq;
        float4 t4 = *(const float4*)rowq;
        qS[s][dq] = t4.x; qS[s][dq + 1] = t4.y; qS[s][dq + 2] = t4.z; qS[s][dq + 3] = t4.w;
        t4 = *(const float4*)(rowq + D_);
        kS[s][dq] = t4.x; kS[s][dq + 1] = t4.y; kS[s][dq + 2] = t4.z; kS[s][dq + 3] = t4.w;
        t4 = *(const float4*)(rowq + 2 * D_);
        vS[s][dq] = t4.x; vS[s][dq + 1] = t4.y; vS[s][dq + 2] = t4.z; vS[s][dq + 3] = t4.w;
        t4 = *(const float4*)(states + (size_t)cid * 4096 + s * 64 + dq);
        sS[s][dq] = t4.x; sS[s][dq + 1] = t4.y; sS[s][dq + 2] = t4.z; sS[s][dq + 3] = t4.w;
    }
    if (tid < L_) {
        cumS[tid] = cum[(size_t)bh * T_ + t0 + tid];
        betaS[tid] = beta[(size_t)(b * T_ + t0 + tid) * H_ + h];
    }
    __syncthreads();

    const int t = tid >> 2;
    const int j0 = (tid & 3) << 4;
    const float ct = cumS[t];

    float p[16];
#pragma unroll
    for (int jj = 0; jj < 16; ++jj) {
        int s = j0 + jj;
        if (s <= t) {
            float acc = 0.f;
            for (int d = 0; d < L_; ++d) acc = fmaf(qS[t][d], kS[s][d], acc);
            p[jj] = expf(ct - cumS[s]) * betaS[s] * acc;
        } else {
            p[jj] = 0.f;
        }
    }
    __syncthreads();
#pragma unroll
    for (int jj = 0; jj < 16; ++jj) kS[t][j0 + jj] = p[jj];
    __syncthreads();

    float accO[16];
#pragma unroll
    for (int jj = 0; jj < 16; ++jj) accO[jj] = 0.f;
    for (int d = 0; d < L_; ++d) {
        float qd = qS[t][d];
#pragma unroll
        for (int jj = 0; jj < 16; ++jj)
            accO[jj] = fmaf(qd, sS[d][j0 + jj], accO[jj]);
    }
    const float ect = expf(ct);
#pragma unroll
    for (int jj = 0; jj < 16; ++jj) accO[jj] *= ect;
    for (int s = 0; s < L_; ++s) {
        float pts = kS[t][s];
#pragma unroll
        for (int jj = 0; jj < 16; ++jj)
            accO[jj] = fmaf(pts, vS[s][j0 + jj], accO[jj]);
    }
    float* op = o + (size_t)(b * T_ + t0 + t) * D_ + h * HD_ + j0;
#pragma unroll
    for (int jj = 0; jj < 16; jj += 4)
        *(float4*)(op + jj) = make_float4(accO[jj], accO[jj + 1], accO[jj + 2], accO[jj + 3]);
}

// ---------------- gated RMSNorm over head dim, bf16 output ----------------
__global__ __launch_bounds__(256)
void rmsnorm_gate(const float* __restrict__ o, const float* __restrict__ z,
                  unsigned short* __restrict__ normed) {
    const int vec = blockIdx.x * 4 + (threadIdx.x >> 6);  // [0, B*T*H)
    const int lane = threadIdx.x & 63;
    const size_t bt = (size_t)(vec >> 4);
    const int h = vec & 15;
    const size_t off = bt * D_ + h * HD_ + lane;
    float ov = o[off];
    float s = ov * ov;
#pragma unroll
    for (int w = 32; w > 0; w >>= 1) s += __shfl_xor(s, w, 64);
    float inv = rsqrtf(s * (1.f / 64.f) + 1e-6f);
    float zv = z[off];
    float sz = zv / (1.f + expf(-zv));   // silu(z)
    normed[off] = f2bf(ov * inv * sz);
}

extern "C" void kernel_launch(void* const* d_in, const int* in_sizes, int n_in,
                              void* d_out, int out_size, void* d_ws, size_t ws_size,
                              hipStream_t stream) {
    const float* x       = (const float*)d_in[0];
    const float* W_qkv   = (const float*)d_in[1];
    const float* conv_w  = (const float*)d_in[2];
    const float* W_z     = (const float*)d_in[3];
    const float* W_b     = (const float*)d_in[4];
    const float* W_a     = (const float*)d_in[5];
    const float* dt_bias = (const float*)d_in[6];
    const float* A_log   = (const float*)d_in[7];
    const float* W_out   = (const float*)d_in[8];
    float* out = (float*)d_out;

    float* ws = (float*)d_ws;
    // Region A [0, 12582912): mixed (fp32) until conv; then overlays:
    float* mixed  = ws;
    float* dS     = ws;                        // 4M floats (phase1->2->3, in-place states)
    float* o      = ws + 4194304;              // 4M floats (phase3 -> rmsnorm)
    float* betab  = ws + 8388608;              // 65,536
    float* gb     = ws + 8454144;              // 65,536
    float* cum    = ws + 8519680;              // 65,536
    float* ac     = ws + 8585216;              // 1,024
    unsigned short* Woutb = (unsigned short*)(ws + 8586240);   // 1M bf16
    // Region B [12582912, 25165824): xb/Wqkvb/Wzb until conv; then qkv; then normed_b
    float* qkv    = ws + 12582912;
    unsigned short* xb    = (unsigned short*)(ws + 12582912);  // 4M bf16
    unsigned short* Wqkvb = (unsigned short*)(ws + 14680064);  // 3M bf16
    unsigned short* Wzb   = (unsigned short*)(ws + 16252928);  // 1M bf16
    unsigned short* normb = (unsigned short*)(ws + 12582912);  // 4M bf16 (after phase3)
    // Region C
    float* z      = ws + 25165824;             // 4M floats

    const int M = B_ * T_;                     // 4096
    dim3 blk(256);

    cvt_bf16<<<dim3(4096), blk, 0, stream>>>(x, xb, 1048576);
    cvt_bf16<<<dim3(3072), blk, 0, stream>>>(W_qkv, Wqkvb, 786432);
    cvt_bf16<<<dim3(1024), blk, 0, stream>>>(W_z, Wzb, 262144);

    gemm_bt_bf16<<<dim3(CD_ / 128, M / 128), blk, 0, stream>>>(xb, Wqkvb, mixed, M, CD_, D_);
    gemm_bt_bf16<<<dim3(D_ / 128, M / 128), blk, 0, stream>>>(xb, Wzb, z, M, D_, D_);

    conv_silu4<<<dim3((M * CD_ / 4) / 256), blk, 0, stream>>>(mixed, conv_w, qkv);

    cvt_bf16<<<dim3(1024), blk, 0, stream>>>(W_out, Woutb, 262144);
    proj_bg<<<dim3(M), blk, 0, stream>>>(x, W_b, W_a, dt_bias, A_log, betab, gb);
    l2norm_qk<<<dim3(2 * M * H_ / 4), blk, 0, stream>>>(qkv);

    chunk_phase1<<<dim3(B_ * H_ * NC_), blk, 0, stream>>>(qkv, betab, gb, dS, cum, ac);
    chunk_phase2<<<dim3(B_ * H_ * 4096 / 256), blk, 0, stream>>>(dS, ac);
    chunk_phase3<<<dim3(B_ * H_ * NC_), blk, 0, stream>>>(qkv, betab, cum, dS, o);

    rmsnorm_gate<<<dim3(M * H_ / 4), blk, 0, stream>>>(o, z, normb);
    gemm_bt_bf16<<<dim3(D_ / 128, M / 128), blk, 0, stream>>>(normb, Woutb, out, M, D_, D_);
}

// Round 4
// 291.094 us; speedup vs baseline: 6.0094x; 1.3610x over previous
//
#include <hip/hip_runtime.h>
#include <math.h>

#define B_  2
#define T_  2048
#define D_  1024
#define H_  16
#define HD_ 64
#define CD_ 3072   // 3*D
#define L_  64     // chunk length
#define NC_ 32     // T/L chunks
#define TS  72     // padded LDS stride in shorts (144 B, 16B-aligned rows)

typedef __attribute__((ext_vector_type(8))) short bf16x8;
typedef __attribute__((ext_vector_type(4))) float f32x4;
typedef __attribute__((ext_vector_type(4))) unsigned short u16x4;

__device__ __forceinline__ unsigned short f2bf(float f) {
    unsigned int u = __float_as_uint(f);
    unsigned int r = (u + 0x7fffu + ((u >> 16) & 1u)) >> 16;
    return (unsigned short)r;
}
__device__ __forceinline__ float bf2f(unsigned short u) {
    return __uint_as_float(((unsigned int)u) << 16);
}

// ---------------- fp32 -> bf16 conversion (x4 vectorized) ----------------
__global__ __launch_bounds__(256)
void cvt_bf16(const float* __restrict__ in, unsigned short* __restrict__ out, int n4) {
    int i = blockIdx.x * 256 + threadIdx.x;
    if (i >= n4) return;
    float4 a = ((const float4*)in)[i];
    u16x4 o;
    o.x = f2bf(a.x); o.y = f2bf(a.y); o.z = f2bf(a.z); o.w = f2bf(a.w);
    ((u16x4*)out)[i] = o;
}

// ---------------- bf16 MFMA GEMM NT: C[M,N] = A[M,K] * B[N,K]^T ----------------
__global__ __launch_bounds__(256)
void gemm_bt_bf16(const unsigned short* __restrict__ A,
                  const unsigned short* __restrict__ Bw,
                  float* __restrict__ C, int M, int N, int K) {
    __shared__ short As[128 * 32];
    __shared__ short Bs[128 * 32];
    const int tid = threadIdx.x;
    const int bm = blockIdx.y * 128;
    const int bn = blockIdx.x * 128;
    const int wave = tid >> 6;
    const int lane = tid & 63;
    const int wm = (wave >> 1) * 64;
    const int wn = (wave & 1) * 64;
    const int lr = lane & 15;
    const int lk = lane >> 4;

    f32x4 acc[4][4] = {};

    const int srow = tid >> 2;           // 0..63
    const int scol = (tid & 3) << 3;     // bf16 col: 0,8,16,24
    const unsigned short* Ag = A + (size_t)(bm + srow) * K + scol;
    const unsigned short* Bg = Bw + (size_t)(bn + srow) * K + scol;

    short* AsP = As + tid * 8;
    short* BsP = Bs + tid * 8;

    const short* pA = As + (wm + lr) * 32 + lk * 8;
    const short* pB = Bs + (wn + lr) * 32 + lk * 8;

    for (int k0 = 0; k0 < K; k0 += 32) {
        __builtin_amdgcn_global_load_lds(
            (const __attribute__((address_space(1))) void*)(Ag + k0),
            (__attribute__((address_space(3))) void*)AsP, 16, 0, 0);
        __builtin_amdgcn_global_load_lds(
            (const __attribute__((address_space(1))) void*)(Ag + (size_t)64 * K + k0),
            (__attribute__((address_space(3))) void*)(AsP + 2048), 16, 0, 0);
        __builtin_amdgcn_global_load_lds(
            (const __attribute__((address_space(1))) void*)(Bg + k0),
            (__attribute__((address_space(3))) void*)BsP, 16, 0, 0);
        __builtin_amdgcn_global_load_lds(
            (const __attribute__((address_space(1))) void*)(Bg + (size_t)64 * K + k0),
            (__attribute__((address_space(3))) void*)(BsP + 2048), 16, 0, 0);
        __syncthreads();

        bf16x8 a[4], b[4];
#pragma unroll
        for (int mi = 0; mi < 4; ++mi) a[mi] = *(const bf16x8*)(pA + mi * 16 * 32);
#pragma unroll
        for (int ni = 0; ni < 4; ++ni) b[ni] = *(const bf16x8*)(pB + ni * 16 * 32);
#pragma unroll
        for (int mi = 0; mi < 4; ++mi)
#pragma unroll
            for (int ni = 0; ni < 4; ++ni)
                acc[mi][ni] = __builtin_amdgcn_mfma_f32_16x16x32_bf16(
                    a[mi], b[ni], acc[mi][ni], 0, 0, 0);
        __syncthreads();
    }

    const int r0 = lk * 4;
#pragma unroll
    for (int mi = 0; mi < 4; ++mi)
#pragma unroll
        for (int ni = 0; ni < 4; ++ni) {
            float* cp = C + (size_t)(bm + wm + mi * 16 + r0) * N + bn + wn + ni * 16 + lr;
#pragma unroll
            for (int r = 0; r < 4; ++r)
                cp[(size_t)r * N] = acc[mi][ni][r];
        }
}

// ---------------- beta / g projections (fp32) ----------------
__global__ __launch_bounds__(256)
void proj_bg(const float* __restrict__ x, const float* __restrict__ Wb,
             const float* __restrict__ Wa, const float* __restrict__ dt_bias,
             const float* __restrict__ A_log,
             float* __restrict__ beta, float* __restrict__ g) {
    const int m = blockIdx.x;
    const float* xr = x + (size_t)m * D_;
    __shared__ float xs[D_];
    for (int i = threadIdx.x; i < D_; i += 256) xs[i] = xr[i];
    __syncthreads();
    const int wave = threadIdx.x >> 6;
    const int lane = threadIdx.x & 63;
    for (int d = wave; d < 32; d += 4) {
        const float* w = (d < 16) ? (Wb + (size_t)d * D_) : (Wa + (size_t)(d - 16) * D_);
        float s = 0.f;
        for (int i = lane; i < D_; i += 64) s += xs[i] * w[i];
#pragma unroll
        for (int off = 32; off > 0; off >>= 1) s += __shfl_down(s, off, 64);
        if (lane == 0) {
            if (d < 16) {
                beta[(size_t)m * H_ + d] = 1.f / (1.f + expf(-s));
            } else {
                int h = d - 16;
                float spin = s + dt_bias[h];
                float sp = (spin > 20.f) ? spin : log1pf(expf(spin));
                g[(size_t)m * H_ + h] = -expf(A_log[h]) * sp;
            }
        }
    }
}

// -------- causal depthwise conv (K=4) + SiLU, x4 vectorized, bf16 out --------
__global__ __launch_bounds__(256)
void conv_silu4(const float* __restrict__ mixed, const float* __restrict__ conv_w,
                unsigned short* __restrict__ qkvb) {
    int idx = blockIdx.x * 256 + threadIdx.x;   // over B*T*CD/4
    const int cq = idx % (CD_ / 4);
    const int bt = idx / (CD_ / 4);
    const int t = bt % T_;
    const int c0 = cq << 2;
    const float* base = mixed + (size_t)bt * CD_ + c0;
    const float4 zero = make_float4(0.f, 0.f, 0.f, 0.f);
    float4 m0 = *(const float4*)base;
    float4 m1 = (t >= 1) ? *(const float4*)(base - CD_) : zero;
    float4 m2 = (t >= 2) ? *(const float4*)(base - 2 * CD_) : zero;
    float4 m3 = (t >= 3) ? *(const float4*)(base - 3 * CD_) : zero;
    const float4* w = (const float4*)(conv_w + (size_t)c0 * 4);
    float4 w0 = w[0], w1 = w[1], w2 = w[2], w3 = w[3];
    float s0 = m0.x * w0.w + m1.x * w0.z + m2.x * w0.y + m3.x * w0.x;
    float s1 = m0.y * w1.w + m1.y * w1.z + m2.y * w1.y + m3.y * w1.x;
    float s2 = m0.z * w2.w + m1.z * w2.z + m2.z * w2.y + m3.z * w2.x;
    float s3 = m0.w * w3.w + m1.w * w3.z + m2.w * w3.y + m3.w * w3.x;
    u16x4 r;
    r.x = f2bf(s0 / (1.f + expf(-s0)));
    r.y = f2bf(s1 / (1.f + expf(-s1)));
    r.z = f2bf(s2 / (1.f + expf(-s2)));
    r.w = f2bf(s3 / (1.f + expf(-s3)));
    *(u16x4*)(qkvb + (size_t)bt * CD_ + c0) = r;
}

// ---------------- l2norm on q and k head-vectors (in place, bf16) ------------
__global__ __launch_bounds__(256)
void l2norm_qk(unsigned short* __restrict__ qkvb) {
    const int vec = blockIdx.x * 4 + (threadIdx.x >> 6);  // [0, 2*B*T*H)
    const int lane = threadIdx.x & 63;
    const int part = vec >> 16;          // B*T*H = 65536: 0 = q, 1 = k
    const int r = vec & 65535;
    const int h = r & 15;
    const size_t bt = (size_t)(r >> 4);
    unsigned short* p = qkvb + bt * CD_ + (size_t)part * D_ + h * HD_ + lane;
    float v = bf2f(*p);
    float s = v * v;
#pragma unroll
    for (int off = 32; off > 0; off >>= 1) s += __shfl_xor(s, off, 64);
    float scale = rsqrtf(s + 1e-6f);
    if (part == 0) scale *= 0.125f;      // HD^-0.5
    *p = f2bf(v * scale);
}

// ------------ phase 1 (MFMA): per-chunk dS^T[v][d], cum, a_c ------------
__global__ __launch_bounds__(256)
void chunk_phase1(const unsigned short* __restrict__ qkvb,
                  const float* __restrict__ beta, const float* __restrict__ gg,
                  float* __restrict__ dST, float* __restrict__ cum,
                  float* __restrict__ ac) {
    const int cid = blockIdx.x;           // (b*H+h)*NC + c
    const int c = cid & (NC_ - 1);
    const int bh = cid >> 5;
    const int b = bh >> 4, h = bh & 15;
    const int tid = threadIdx.x;
    const int wave = tid >> 6, lane = tid & 63;
    const int t0 = c * L_;

    __shared__ __align__(16) short kT[64 * TS];   // [d][s]
    __shared__ __align__(16) short vT[64 * TS];   // [v][s], weighted
    __shared__ float cumS[64], wS[64];

    // each lane loads row s=lane, cols wave*16..+16 of k and v
    const unsigned short* rowp = qkvb + (size_t)(b * T_ + t0 + lane) * CD_ + h * HD_ + wave * 16;
    bf16x8 k0 = *(const bf16x8*)(rowp + D_);
    bf16x8 k1 = *(const bf16x8*)(rowp + D_ + 8);
    bf16x8 v0 = *(const bf16x8*)(rowp + 2 * D_);
    bf16x8 v1 = *(const bf16x8*)(rowp + 2 * D_ + 8);

    if (wave == 0) {   // parallel inclusive scan of g over the 64 timesteps
        float s = gg[(size_t)(b * T_ + t0 + lane) * H_ + h];
#pragma unroll
        for (int off = 1; off < 64; off <<= 1) {
            float up = __shfl_up(s, off, 64);
            if (lane >= off) s += up;
        }
        cumS[lane] = s;
        float cend = __shfl(s, 63, 64);
        wS[lane] = expf(cend - s) * beta[(size_t)(b * T_ + t0 + lane) * H_ + h];
        cum[(size_t)bh * T_ + t0 + lane] = s;
        if (lane == 63) ac[cid] = expf(cend);
    }
    __syncthreads();
    const float w = wS[lane];
#pragma unroll
    for (int j = 0; j < 8; ++j) {
        kT[(wave * 16 + j) * TS + lane] = k0[j];
        kT[(wave * 16 + 8 + j) * TS + lane] = k1[j];
        vT[(wave * 16 + j) * TS + lane] = f2bf(bf2f((unsigned short)v0[j]) * w);
        vT[(wave * 16 + 8 + j) * TS + lane] = f2bf(bf2f((unsigned short)v1[j]) * w);
    }
    __syncthreads();

    const int lr = lane & 15, lk = lane >> 4;
    f32x4 acc[4] = {};
    const short* pA = vT + (wave * 16 + lr) * TS + lk * 8;
#pragma unroll
    for (int kk = 0; kk < 2; ++kk) {
        bf16x8 a = *(const bf16x8*)(pA + kk * 32);
#pragma unroll
        for (int n = 0; n < 4; ++n) {
            bf16x8 bfr = *(const bf16x8*)(kT + (n * 16 + lr) * TS + lk * 8 + kk * 32);
            acc[n] = __builtin_amdgcn_mfma_f32_16x16x32_bf16(a, bfr, acc[n], 0, 0, 0);
        }
    }
    // C: col=lane&15 -> d, row=(lane>>4)*4+r -> v
#pragma unroll
    for (int n = 0; n < 4; ++n) {
        float* op = dST + (size_t)cid * 4096 + (wave * 16 + lk * 4) * 64 + n * 16 + lr;
#pragma unroll
        for (int r = 0; r < 4; ++r)
            op[r * 64] = acc[n][r];
    }
}

// ---------------- phase 2: scan over chunks, IN PLACE (dST -> states) --------
__global__ __launch_bounds__(256)
void chunk_phase2(float* __restrict__ dST, const float* __restrict__ ac) {
    const int gid = blockIdx.x * 256 + threadIdx.x;  // B*H*4096 = 131072
    const int bh = gid >> 12;
    const int e = gid & 4095;
    float s = 0.f;
    for (int c = 0; c < NC_; ++c) {
        size_t off = (size_t)(bh * NC_ + c) * 4096 + e;
        float tmp = dST[off];
        dST[off] = s;                 // state ENTERING chunk c (transposed layout)
        s = fmaf(ac[bh * NC_ + c], s, tmp);
    }
}

// ------------ phase 3 (MFMA): O = exp(ct)*Q*S_in + (decayed P)*V ------------
__global__ __launch_bounds__(256)
void chunk_phase3(const unsigned short* __restrict__ qkvb,
                  const float* __restrict__ beta, const float* __restrict__ cum,
                  const float* __restrict__ states,   // dST layout [cid][v][d] fp32
                  float* __restrict__ o) {
    const int cid = blockIdx.x;
    const int c = cid & (NC_ - 1);
    const int bh = cid >> 5;
    const int b = bh >> 4, h = bh & 15;
    const int tid = threadIdx.x;
    const int wave = tid >> 6, lane = tid & 63;
    const int t0 = c * L_;

    __shared__ __align__(16) short vT[64 * TS];   // [v][s]
    __shared__ __align__(16) short sT[64 * TS];   // S_in^T bf16 [v][d]
    __shared__ __align__(16) short pS[64 * TS];   // P [t][s] bf16
    __shared__ float cumS[64], betaS[64];

    {   // stage vT (transpose): lane = row s, wave covers v-cols wave*16..+16
        const unsigned short* rowp = qkvb + (size_t)(b * T_ + t0 + lane) * CD_ + 2 * D_ + h * HD_ + wave * 16;
        bf16x8 v0 = *(const bf16x8*)rowp;
        bf16x8 v1 = *(const bf16x8*)(rowp + 8);
#pragma unroll
        for (int j = 0; j < 8; ++j) {
            vT[(wave * 16 + j) * TS + lane] = v0[j];
            vT[(wave * 16 + 8 + j) * TS + lane] = v1[j];
        }
    }
    {   // stage sT: natural row-major copy, fp32 -> bf16
        const float* sp = states + (size_t)cid * 4096 + (tid >> 2) * 64 + (tid & 3) * 16;
        short* dp = sT + (tid >> 2) * TS + (tid & 3) * 16;
#pragma unroll
        for (int j = 0; j < 16; j += 4) {
            float4 f = *(const float4*)(sp + j);
            dp[j] = f2bf(f.x); dp[j + 1] = f2bf(f.y);
            dp[j + 2] = f2bf(f.z); dp[j + 3] = f2bf(f.w);
        }
    }
    if (tid < 64) {
        cumS[tid] = cum[(size_t)bh * T_ + t0 + tid];
        betaS[tid] = beta[(size_t)(b * T_ + t0 + tid) * H_ + h];
    }
    __syncthreads();

    const int lr = lane & 15, lk = lane >> 4;
    // Q A-fragments direct from global (L2-hot): rows t0 + wave*16 + lr
    const unsigned short* qrow = qkvb + (size_t)(b * T_ + t0 + wave * 16 + lr) * CD_ + h * HD_;
    bf16x8 qf0 = *(const bf16x8*)(qrow + lk * 8);
    bf16x8 qf1 = *(const bf16x8*)(qrow + 32 + lk * 8);

    // QK^T (K B-frags direct from global)
    f32x4 pacc[4] = {};
#pragma unroll
    for (int n = 0; n < 4; ++n) {
        const unsigned short* krow = qkvb + (size_t)(b * T_ + t0 + n * 16 + lr) * CD_ + D_ + h * HD_;
        bf16x8 b0 = *(const bf16x8*)(krow + lk * 8);
        bf16x8 b1 = *(const bf16x8*)(krow + 32 + lk * 8);
        pacc[n] = __builtin_amdgcn_mfma_f32_16x16x32_bf16(qf0, b0, pacc[n], 0, 0, 0);
        pacc[n] = __builtin_amdgcn_mfma_f32_16x16x32_bf16(qf1, b1, pacc[n], 0, 0, 0);
    }
    // decay + mask + beta -> pS (bf16)
#pragma unroll
    for (int n = 0; n < 4; ++n) {
        int s = n * 16 + lr;
        float cs = cumS[s], bs = betaS[s];
#pragma unroll
        for (int r = 0; r < 4; ++r) {
            int t = wave * 16 + lk * 4 + r;
            float pv = (s <= t) ? expf(cumS[t] - cs) * bs * pacc[n][r] : 0.f;
            pS[t * TS + s] = f2bf(pv);
        }
    }
    __syncthreads();

    // O = Q * S_in^T-frags
    f32x4 oacc[4] = {};
#pragma unroll
    for (int n = 0; n < 4; ++n) {
        const short* srow = sT + (n * 16 + lr) * TS + lk * 8;
        bf16x8 b0 = *(const bf16x8*)srow;
        bf16x8 b1 = *(const bf16x8*)(srow + 32);
        oacc[n] = __builtin_amdgcn_mfma_f32_16x16x32_bf16(qf0, b0, oacc[n], 0, 0, 0);
        oacc[n] = __builtin_amdgcn_mfma_f32_16x16x32_bf16(qf1, b1, oacc[n], 0, 0, 0);
    }
    // scale rows by exp(ct)
    float ect[4];
#pragma unroll
    for (int r = 0; r < 4; ++r) ect[r] = expf(cumS[wave * 16 + lk * 4 + r]);
#pragma unroll
    for (int n = 0; n < 4; ++n)
#pragma unroll
        for (int r = 0; r < 4; ++r) oacc[n][r] *= ect[r];
    // + P * V
    const short* prow = pS + (wave * 16 + lr) * TS + lk * 8;
    bf16x8 pf0 = *(const bf16x8*)prow;
    bf16x8 pf1 = *(const bf16x8*)(prow + 32);
#pragma unroll
    for (int n = 0; n < 4; ++n) {
        const short* vrow = vT + (n * 16 + lr) * TS + lk * 8;
        bf16x8 b0 = *(const bf16x8*)vrow;
        bf16x8 b1 = *(const bf16x8*)(vrow + 32);
        oacc[n] = __builtin_amdgcn_mfma_f32_16x16x32_bf16(pf0, b0, oacc[n], 0, 0, 0);
        oacc[n] = __builtin_amdgcn_mfma_f32_16x16x32_bf16(pf1, b1, oacc[n], 0, 0, 0);
    }
    // write O rows
#pragma unroll
    for (int n = 0; n < 4; ++n) {
        float* op = o + (size_t)(b * T_ + t0 + wave * 16 + lk * 4) * D_ + h * HD_ + n * 16 + lr;
#pragma unroll
        for (int r = 0; r < 4; ++r)
            op[(size_t)r * D_] = oacc[n][r];
    }
}

// ---------------- gated RMSNorm over head dim, bf16 output ----------------
__global__ __launch_bounds__(256)
void rmsnorm_gate(const float* __restrict__ o, const float* __restrict__ z,
                  unsigned short* __restrict__ normed) {
    const int vec = blockIdx.x * 4 + (threadIdx.x >> 6);  // [0, B*T*H)
    const int lane = threadIdx.x & 63;
    const size_t bt = (size_t)(vec >> 4);
    const int h = vec & 15;
    const size_t off = bt * D_ + h * HD_ + lane;
    float ov = o[off];
    float s = ov * ov;
#pragma unroll
    for (int w = 32; w > 0; w >>= 1) s += __shfl_xor(s, w, 64);
    float inv = rsqrtf(s * (1.f / 64.f) + 1e-6f);
    float zv = z[off];
    float sz = zv / (1.f + expf(-zv));   // silu(z)
    normed[off] = f2bf(ov * inv * sz);
}

extern "C" void kernel_launch(void* const* d_in, const int* in_sizes, int n_in,
                              void* d_out, int out_size, void* d_ws, size_t ws_size,
                              hipStream_t stream) {
    const float* x       = (const float*)d_in[0];
    const float* W_qkv   = (const float*)d_in[1];
    const float* conv_w  = (const float*)d_in[2];
    const float* W_z     = (const float*)d_in[3];
    const float* W_b     = (const float*)d_in[4];
    const float* W_a     = (const float*)d_in[5];
    const float* dt_bias = (const float*)d_in[6];
    const float* A_log   = (const float*)d_in[7];
    const float* W_out   = (const float*)d_in[8];
    float* out = (float*)d_out;

    float* ws = (float*)d_ws;
    // Region A [0, 12582912): mixed fp32 until conv; overlays AFTER conv:
    float* mixed  = ws;
    float* dST    = ws;                        // 4M floats (ph1 -> ph2 in-place -> ph3)
    float* o      = ws + 4194304;              // 4M floats (ph3 -> rmsnorm)
    float* betab  = ws + 8388608;              // 65,536
    float* gb     = ws + 8454144;              // 65,536
    float* cum    = ws + 8519680;              // 65,536
    float* ac     = ws + 8585216;              // 1,024
    unsigned short* Woutb = (unsigned short*)(ws + 8586240);   // 1M bf16
    // Region B [12582912, 18874368): xb/Wqkvb/Wzb pre-conv; qkvb after; normb last
    unsigned short* xb    = (unsigned short*)(ws + 12582912);  // 4M bf16
    unsigned short* Wqkvb = (unsigned short*)(ws + 14680064);  // 3M bf16
    unsigned short* Wzb   = (unsigned short*)(ws + 16252928);  // 1M bf16
    unsigned short* qkvb  = (unsigned short*)(ws + 12582912);  // 12.6M bf16
    unsigned short* normb = (unsigned short*)(ws + 12582912);  // 4M bf16 (after ph3)
    // Region C
    float* z      = ws + 18874368;             // 4M floats

    const int M = B_ * T_;                     // 4096
    dim3 blk(256);

    cvt_bf16<<<dim3(4096), blk, 0, stream>>>(x, xb, 1048576);
    cvt_bf16<<<dim3(3072), blk, 0, stream>>>(W_qkv, Wqkvb, 786432);
    cvt_bf16<<<dim3(1024), blk, 0, stream>>>(W_z, Wzb, 262144);

    gemm_bt_bf16<<<dim3(CD_ / 128, M / 128), blk, 0, stream>>>(xb, Wqkvb, mixed, M, CD_, D_);
    gemm_bt_bf16<<<dim3(D_ / 128, M / 128), blk, 0, stream>>>(xb, Wzb, z, M, D_, D_);

    conv_silu4<<<dim3((M * CD_ / 4) / 256), blk, 0, stream>>>(mixed, conv_w, qkvb);

    cvt_bf16<<<dim3(1024), blk, 0, stream>>>(W_out, Woutb, 262144);
    proj_bg<<<dim3(M), blk, 0, stream>>>(x, W_b, W_a, dt_bias, A_log, betab, gb);
    l2norm_qk<<<dim3(2 * M * H_ / 4), blk, 0, stream>>>(qkvb);

    chunk_phase1<<<dim3(B_ * H_ * NC_), blk, 0, stream>>>(qkvb, betab, gb, dST, cum, ac);
    chunk_phase2<<<dim3(B_ * H_ * 4096 / 256), blk, 0, stream>>>(dST, ac);
    chunk_phase3<<<dim3(B_ * H_ * NC_), blk, 0, stream>>>(qkvb, betab, cum, dST, o);

    rmsnorm_gate<<<dim3(M * H_ / 4), blk, 0, stream>>>(o, z, normb);
    gemm_bt_bf16<<<dim3(D_ / 128, M / 128), blk, 0, stream>>>(normb, Woutb, out, M, D_, D_);
}

// Round 5
// 272.755 us; speedup vs baseline: 6.4134x; 1.0672x over previous
//
#include <hip/hip_runtime.h>
#include <math.h>

#define B_  2
#define T_  2048
#define D_  1024
#define H_  16
#define HD_ 64
#define CD_ 3072   // 3*D
#define L_  64     // chunk length
#define NC_ 32     // T/L chunks
#define TS  72     // padded LDS stride in shorts (144 B, 16B-aligned rows)

typedef __attribute__((ext_vector_type(8))) short bf16x8;
typedef __attribute__((ext_vector_type(4))) float f32x4;
typedef __attribute__((ext_vector_type(4))) unsigned short u16x4;

__device__ __forceinline__ unsigned short f2bf(float f) {
    unsigned int u = __float_as_uint(f);
    unsigned int r = (u + 0x7fffu + ((u >> 16) & 1u)) >> 16;
    return (unsigned short)r;
}
__device__ __forceinline__ float bf2f(unsigned short u) {
    return __uint_as_float(((unsigned int)u) << 16);
}

// ---------------- fp32 -> bf16 conversion (x4 vectorized) ----------------
__global__ __launch_bounds__(256)
void cvt_bf16(const float* __restrict__ in, unsigned short* __restrict__ out, int n4) {
    int i = blockIdx.x * 256 + threadIdx.x;
    if (i >= n4) return;
    float4 a = ((const float4*)in)[i];
    u16x4 o;
    o.x = f2bf(a.x); o.y = f2bf(a.y); o.z = f2bf(a.z); o.w = f2bf(a.w);
    ((u16x4*)out)[i] = o;
}

// ---------------- bf16 MFMA GEMM NT: C[M,N] = A[M,K] * B[N,K]^T ----------------
__global__ __launch_bounds__(256)
void gemm_bt_bf16(const unsigned short* __restrict__ A,
                  const unsigned short* __restrict__ Bw,
                  float* __restrict__ C, int M, int N, int K) {
    __shared__ short As[128 * 32];
    __shared__ short Bs[128 * 32];
    const int tid = threadIdx.x;
    const int bm = blockIdx.y * 128;
    const int bn = blockIdx.x * 128;
    const int wave = tid >> 6;
    const int lane = tid & 63;
    const int wm = (wave >> 1) * 64;
    const int wn = (wave & 1) * 64;
    const int lr = lane & 15;
    const int lk = lane >> 4;

    f32x4 acc[4][4] = {};

    const int srow = tid >> 2;           // 0..63
    const int scol = (tid & 3) << 3;     // bf16 col: 0,8,16,24
    const unsigned short* Ag = A + (size_t)(bm + srow) * K + scol;
    const unsigned short* Bg = Bw + (size_t)(bn + srow) * K + scol;

    short* AsP = As + tid * 8;
    short* BsP = Bs + tid * 8;

    const short* pA = As + (wm + lr) * 32 + lk * 8;
    const short* pB = Bs + (wn + lr) * 32 + lk * 8;

    for (int k0 = 0; k0 < K; k0 += 32) {
        __builtin_amdgcn_global_load_lds(
            (const __attribute__((address_space(1))) void*)(Ag + k0),
            (__attribute__((address_space(3))) void*)AsP, 16, 0, 0);
        __builtin_amdgcn_global_load_lds(
            (const __attribute__((address_space(1))) void*)(Ag + (size_t)64 * K + k0),
            (__attribute__((address_space(3))) void*)(AsP + 2048), 16, 0, 0);
        __builtin_amdgcn_global_load_lds(
            (const __attribute__((address_space(1))) void*)(Bg + k0),
            (__attribute__((address_space(3))) void*)BsP, 16, 0, 0);
        __builtin_amdgcn_global_load_lds(
            (const __attribute__((address_space(1))) void*)(Bg + (size_t)64 * K + k0),
            (__attribute__((address_space(3))) void*)(BsP + 2048), 16, 0, 0);
        __syncthreads();

        bf16x8 a[4], b[4];
#pragma unroll
        for (int mi = 0; mi < 4; ++mi) a[mi] = *(const bf16x8*)(pA + mi * 16 * 32);
#pragma unroll
        for (int ni = 0; ni < 4; ++ni) b[ni] = *(const bf16x8*)(pB + ni * 16 * 32);
#pragma unroll
        for (int mi = 0; mi < 4; ++mi)
#pragma unroll
            for (int ni = 0; ni < 4; ++ni)
                acc[mi][ni] = __builtin_amdgcn_mfma_f32_16x16x32_bf16(
                    a[mi], b[ni], acc[mi][ni], 0, 0, 0);
        __syncthreads();
    }

    const int r0 = lk * 4;
#pragma unroll
    for (int mi = 0; mi < 4; ++mi)
#pragma unroll
        for (int ni = 0; ni < 4; ++ni) {
            float* cp = C + (size_t)(bm + wm + mi * 16 + r0) * N + bn + wn + ni * 16 + lr;
#pragma unroll
            for (int r = 0; r < 4; ++r)
                cp[(size_t)r * N] = acc[mi][ni][r];
        }
}

// -------- beta / g projections, tiled skinny GEMM (fp32, full reuse) --------
__global__ __launch_bounds__(256)
void proj_bg2(const float* __restrict__ x, const float* __restrict__ Wb,
              const float* __restrict__ Wa, const float* __restrict__ dt_bias,
              const float* __restrict__ A_log,
              float* __restrict__ beta, float* __restrict__ g) {
    const int m0 = blockIdx.x * 32;        // 128 blocks x 32 rows
    const int tid = threadIdx.x;
    __shared__ float xs[32][65];
    __shared__ float ws[32][65];
    const int mi = tid >> 3;               // 0..31 (row)
    const int n0 = (tid & 7) << 2;         // 0,4,...,28 (col group)
    const int sr = tid >> 3;               // staging row 0..31
    const int sc = (tid & 7) << 3;         // staging col 0,8,..,56

    float acc[4] = {0.f, 0.f, 0.f, 0.f};
    const float* wrow = (sr < 16) ? (Wb + (size_t)sr * D_) : (Wa + (size_t)(sr - 16) * D_);

    for (int k0 = 0; k0 < D_; k0 += 64) {
        float4 a0 = *(const float4*)(x + (size_t)(m0 + sr) * D_ + k0 + sc);
        float4 a1 = *(const float4*)(x + (size_t)(m0 + sr) * D_ + k0 + sc + 4);
        float4 b0 = *(const float4*)(wrow + k0 + sc);
        float4 b1 = *(const float4*)(wrow + k0 + sc + 4);
        xs[sr][sc + 0] = a0.x; xs[sr][sc + 1] = a0.y; xs[sr][sc + 2] = a0.z; xs[sr][sc + 3] = a0.w;
        xs[sr][sc + 4] = a1.x; xs[sr][sc + 5] = a1.y; xs[sr][sc + 6] = a1.z; xs[sr][sc + 7] = a1.w;
        ws[sr][sc + 0] = b0.x; ws[sr][sc + 1] = b0.y; ws[sr][sc + 2] = b0.z; ws[sr][sc + 3] = b0.w;
        ws[sr][sc + 4] = b1.x; ws[sr][sc + 5] = b1.y; ws[sr][sc + 6] = b1.z; ws[sr][sc + 7] = b1.w;
        __syncthreads();
#pragma unroll 16
        for (int kk = 0; kk < 64; ++kk) {
            float av = xs[mi][kk];
#pragma unroll
            for (int j = 0; j < 4; ++j)
                acc[j] = fmaf(av, ws[n0 + j][kk], acc[j]);
        }
        __syncthreads();
    }
#pragma unroll
    for (int j = 0; j < 4; ++j) {
        int n = n0 + j;
        float s = acc[j];
        if (n < 16) {
            beta[(size_t)(m0 + mi) * H_ + n] = 1.f / (1.f + expf(-s));
        } else {
            int h = n - 16;
            float spin = s + dt_bias[h];
            float sp = (spin > 20.f) ? spin : log1pf(expf(spin));
            g[(size_t)(m0 + mi) * H_ + h] = -expf(A_log[h]) * sp;
        }
    }
}

// -------- causal depthwise conv (K=4) + SiLU, x4 vectorized, bf16 out --------
__global__ __launch_bounds__(256)
void conv_silu4(const float* __restrict__ mixed, const float* __restrict__ conv_w,
                unsigned short* __restrict__ qkvb) {
    int idx = blockIdx.x * 256 + threadIdx.x;   // over B*T*CD/4
    const int cq = idx % (CD_ / 4);
    const int bt = idx / (CD_ / 4);
    const int t = bt % T_;
    const int c0 = cq << 2;
    const float* base = mixed + (size_t)bt * CD_ + c0;
    const float4 zero = make_float4(0.f, 0.f, 0.f, 0.f);
    float4 m0 = *(const float4*)base;
    float4 m1 = (t >= 1) ? *(const float4*)(base - CD_) : zero;
    float4 m2 = (t >= 2) ? *(const float4*)(base - 2 * CD_) : zero;
    float4 m3 = (t >= 3) ? *(const float4*)(base - 3 * CD_) : zero;
    const float4* w = (const float4*)(conv_w + (size_t)c0 * 4);
    float4 w0 = w[0], w1 = w[1], w2 = w[2], w3 = w[3];
    float s0 = m0.x * w0.w + m1.x * w0.z + m2.x * w0.y + m3.x * w0.x;
    float s1 = m0.y * w1.w + m1.y * w1.z + m2.y * w1.y + m3.y * w1.x;
    float s2 = m0.z * w2.w + m1.z * w2.z + m2.z * w2.y + m3.z * w2.x;
    float s3 = m0.w * w3.w + m1.w * w3.z + m2.w * w3.y + m3.w * w3.x;
    u16x4 r;
    r.x = f2bf(s0 / (1.f + expf(-s0)));
    r.y = f2bf(s1 / (1.f + expf(-s1)));
    r.z = f2bf(s2 / (1.f + expf(-s2)));
    r.w = f2bf(s3 / (1.f + expf(-s3)));
    *(u16x4*)(qkvb + (size_t)bt * CD_ + c0) = r;
}

// ---------------- l2norm on q and k head-vectors (in place, bf16) ------------
__global__ __launch_bounds__(256)
void l2norm_qk(unsigned short* __restrict__ qkvb) {
    const int vec = blockIdx.x * 4 + (threadIdx.x >> 6);  // [0, 2*B*T*H)
    const int lane = threadIdx.x & 63;
    const int part = vec >> 16;          // B*T*H = 65536: 0 = q, 1 = k
    const int r = vec & 65535;
    const int h = r & 15;
    const size_t bt = (size_t)(r >> 4);
    unsigned short* p = qkvb + bt * CD_ + (size_t)part * D_ + h * HD_ + lane;
    float v = bf2f(*p);
    float s = v * v;
#pragma unroll
    for (int off = 32; off > 0; off >>= 1) s += __shfl_xor(s, off, 64);
    float scale = rsqrtf(s + 1e-6f);
    if (part == 0) scale *= 0.125f;      // HD^-0.5
    *p = f2bf(v * scale);
}

// ------------ phase 1 (MFMA): per-chunk dS^T[v][d], cum, a_c ------------
__global__ __launch_bounds__(256)
void chunk_phase1(const unsigned short* __restrict__ qkvb,
                  const float* __restrict__ beta, const float* __restrict__ gg,
                  float* __restrict__ dST, float* __restrict__ cum,
                  float* __restrict__ ac) {
    const int cid = blockIdx.x;           // (b*H+h)*NC + c
    const int c = cid & (NC_ - 1);
    const int bh = cid >> 5;
    const int b = bh >> 4, h = bh & 15;
    const int tid = threadIdx.x;
    const int wave = tid >> 6, lane = tid & 63;
    const int t0 = c * L_;

    __shared__ __align__(16) short kT[64 * TS];   // [d][s]
    __shared__ __align__(16) short vT[64 * TS];   // [v][s], weighted
    __shared__ float cumS[64], wS[64];

    // each lane loads row s=lane, cols wave*16..+16 of k and v
    const unsigned short* rowp = qkvb + (size_t)(b * T_ + t0 + lane) * CD_ + h * HD_ + wave * 16;
    bf16x8 k0 = *(const bf16x8*)(rowp + D_);
    bf16x8 k1 = *(const bf16x8*)(rowp + D_ + 8);
    bf16x8 v0 = *(const bf16x8*)(rowp + 2 * D_);
    bf16x8 v1 = *(const bf16x8*)(rowp + 2 * D_ + 8);

    if (wave == 0) {   // parallel inclusive scan of g over the 64 timesteps
        float s = gg[(size_t)(b * T_ + t0 + lane) * H_ + h];
#pragma unroll
        for (int off = 1; off < 64; off <<= 1) {
            float up = __shfl_up(s, off, 64);
            if (lane >= off) s += up;
        }
        cumS[lane] = s;
        float cend = __shfl(s, 63, 64);
        wS[lane] = expf(cend - s) * beta[(size_t)(b * T_ + t0 + lane) * H_ + h];
        cum[(size_t)bh * T_ + t0 + lane] = s;
        if (lane == 63) ac[cid] = expf(cend);
    }
    __syncthreads();
    const float w = wS[lane];
#pragma unroll
    for (int j = 0; j < 8; ++j) {
        kT[(wave * 16 + j) * TS + lane] = k0[j];
        kT[(wave * 16 + 8 + j) * TS + lane] = k1[j];
        vT[(wave * 16 + j) * TS + lane] = f2bf(bf2f((unsigned short)v0[j]) * w);
        vT[(wave * 16 + 8 + j) * TS + lane] = f2bf(bf2f((unsigned short)v1[j]) * w);
    }
    __syncthreads();

    const int lr = lane & 15, lk = lane >> 4;
    f32x4 acc[4] = {};
    const short* pA = vT + (wave * 16 + lr) * TS + lk * 8;
#pragma unroll
    for (int kk = 0; kk < 2; ++kk) {
        bf16x8 a = *(const bf16x8*)(pA + kk * 32);
#pragma unroll
        for (int n = 0; n < 4; ++n) {
            bf16x8 bfr = *(const bf16x8*)(kT + (n * 16 + lr) * TS + lk * 8 + kk * 32);
            acc[n] = __builtin_amdgcn_mfma_f32_16x16x32_bf16(a, bfr, acc[n], 0, 0, 0);
        }
    }
    // C: col=lane&15 -> d, row=(lane>>4)*4+r -> v
#pragma unroll
    for (int n = 0; n < 4; ++n) {
        float* op = dST + (size_t)cid * 4096 + (wave * 16 + lk * 4) * 64 + n * 16 + lr;
#pragma unroll
        for (int r = 0; r < 4; ++r)
            op[r * 64] = acc[n][r];
    }
}

// ---------------- phase 2: scan over chunks, IN PLACE (dST -> states) --------
__global__ __launch_bounds__(256)
void chunk_phase2(float* __restrict__ dST, const float* __restrict__ ac) {
    const int gid = blockIdx.x * 256 + threadIdx.x;  // B*H*4096 = 131072
    const int bh = gid >> 12;
    const int e = gid & 4095;
    float s = 0.f;
    for (int c = 0; c < NC_; ++c) {
        size_t off = (size_t)(bh * NC_ + c) * 4096 + e;
        float tmp = dST[off];
        dST[off] = s;                 // state ENTERING chunk c (transposed layout)
        s = fmaf(ac[bh * NC_ + c], s, tmp);
    }
}

// ------------ phase 3 (MFMA): O = exp(ct)*Q*S_in + (decayed P)*V ------------
__global__ __launch_bounds__(256)
void chunk_phase3(const unsigned short* __restrict__ qkvb,
                  const float* __restrict__ beta, const float* __restrict__ cum,
                  const float* __restrict__ states,   // dST layout [cid][v][d] fp32
                  float* __restrict__ o) {
    const int cid = blockIdx.x;
    const int c = cid & (NC_ - 1);
    const int bh = cid >> 5;
    const int b = bh >> 4, h = bh & 15;
    const int tid = threadIdx.x;
    const int wave = tid >> 6, lane = tid & 63;
    const int t0 = c * L_;

    __shared__ __align__(16) short vT[64 * TS];   // [v][s]
    __shared__ __align__(16) short sT[64 * TS];   // S_in^T bf16 [v][d]
    __shared__ __align__(16) short pS[64 * TS];   // P [t][s] bf16
    __shared__ float cumS[64], betaS[64];

    {   // stage vT (transpose): lane = row s, wave covers v-cols wave*16..+16
        const unsigned short* rowp = qkvb + (size_t)(b * T_ + t0 + lane) * CD_ + 2 * D_ + h * HD_ + wave * 16;
        bf16x8 v0 = *(const bf16x8*)rowp;
        bf16x8 v1 = *(const bf16x8*)(rowp + 8);
#pragma unroll
        for (int j = 0; j < 8; ++j) {
            vT[(wave * 16 + j) * TS + lane] = v0[j];
            vT[(wave * 16 + 8 + j) * TS + lane] = v1[j];
        }
    }
    {   // stage sT: natural row-major copy, fp32 -> bf16
        const float* sp = states + (size_t)cid * 4096 + (tid >> 2) * 64 + (tid & 3) * 16;
        short* dp = sT + (tid >> 2) * TS + (tid & 3) * 16;
#pragma unroll
        for (int j = 0; j < 16; j += 4) {
            float4 f = *(const float4*)(sp + j);
            dp[j] = f2bf(f.x); dp[j + 1] = f2bf(f.y);
            dp[j + 2] = f2bf(f.z); dp[j + 3] = f2bf(f.w);
        }
    }
    if (tid < 64) {
        cumS[tid] = cum[(size_t)bh * T_ + t0 + tid];
        betaS[tid] = beta[(size_t)(b * T_ + t0 + tid) * H_ + h];
    }
    __syncthreads();

    const int lr = lane & 15, lk = lane >> 4;
    // Q A-fragments direct from global (L2-hot): rows t0 + wave*16 + lr
    const unsigned short* qrow = qkvb + (size_t)(b * T_ + t0 + wave * 16 + lr) * CD_ + h * HD_;
    bf16x8 qf0 = *(const bf16x8*)(qrow + lk * 8);
    bf16x8 qf1 = *(const bf16x8*)(qrow + 32 + lk * 8);

    // QK^T (K B-frags direct from global)
    f32x4 pacc[4] = {};
#pragma unroll
    for (int n = 0; n < 4; ++n) {
        const unsigned short* krow = qkvb + (size_t)(b * T_ + t0 + n * 16 + lr) * CD_ + D_ + h * HD_;
        bf16x8 b0 = *(const bf16x8*)(krow + lk * 8);
        bf16x8 b1 = *(const bf16x8*)(krow + 32 + lk * 8);
        pacc[n] = __builtin_amdgcn_mfma_f32_16x16x32_bf16(qf0, b0, pacc[n], 0, 0, 0);
        pacc[n] = __builtin_amdgcn_mfma_f32_16x16x32_bf16(qf1, b1, pacc[n], 0, 0, 0);
    }
    // decay + mask + beta -> pS (bf16)
#pragma unroll
    for (int n = 0; n < 4; ++n) {
        int s = n * 16 + lr;
        float cs = cumS[s], bs = betaS[s];
#pragma unroll
        for (int r = 0; r < 4; ++r) {
            int t = wave * 16 + lk * 4 + r;
            float pv = (s <= t) ? expf(cumS[t] - cs) * bs * pacc[n][r] : 0.f;
            pS[t * TS + s] = f2bf(pv);
        }
    }
    __syncthreads();

    // O = Q * S_in^T-frags
    f32x4 oacc[4] = {};
#pragma unroll
    for (int n = 0; n < 4; ++n) {
        const short* srow = sT + (n * 16 + lr) * TS + lk * 8;
        bf16x8 b0 = *(const bf16x8*)srow;
        bf16x8 b1 = *(const bf16x8*)(srow + 32);
        oacc[n] = __builtin_amdgcn_mfma_f32_16x16x32_bf16(qf0, b0, oacc[n], 0, 0, 0);
        oacc[n] = __builtin_amdgcn_mfma_f32_16x16x32_bf16(qf1, b1, oacc[n], 0, 0, 0);
    }
    // scale rows by exp(ct)
    float ect[4];
#pragma unroll
    for (int r = 0; r < 4; ++r) ect[r] = expf(cumS[wave * 16 + lk * 4 + r]);
#pragma unroll
    for (int n = 0; n < 4; ++n)
#pragma unroll
        for (int r = 0; r < 4; ++r) oacc[n][r] *= ect[r];
    // + P * V
    const short* prow = pS + (wave * 16 + lr) * TS + lk * 8;
    bf16x8 pf0 = *(const bf16x8*)prow;
    bf16x8 pf1 = *(const bf16x8*)(prow + 32);
#pragma unroll
    for (int n = 0; n < 4; ++n) {
        const short* vrow = vT + (n * 16 + lr) * TS + lk * 8;
        bf16x8 b0 = *(const bf16x8*)vrow;
        bf16x8 b1 = *(const bf16x8*)(vrow + 32);
        oacc[n] = __builtin_amdgcn_mfma_f32_16x16x32_bf16(pf0, b0, oacc[n], 0, 0, 0);
        oacc[n] = __builtin_amdgcn_mfma_f32_16x16x32_bf16(pf1, b1, oacc[n], 0, 0, 0);
    }
    // write O rows
#pragma unroll
    for (int n = 0; n < 4; ++n) {
        float* op = o + (size_t)(b * T_ + t0 + wave * 16 + lk * 4) * D_ + h * HD_ + n * 16 + lr;
#pragma unroll
        for (int r = 0; r < 4; ++r)
            op[(size_t)r * D_] = oacc[n][r];
    }
}

// ---------------- gated RMSNorm over head dim, bf16 output ----------------
__global__ __launch_bounds__(256)
void rmsnorm_gate(const float* __restrict__ o, const float* __restrict__ z,
                  unsigned short* __restrict__ normed) {
    const int vec = blockIdx.x * 4 + (threadIdx.x >> 6);  // [0, B*T*H)
    const int lane = threadIdx.x & 63;
    const size_t bt = (size_t)(vec >> 4);
    const int h = vec & 15;
    const size_t off = bt * D_ + h * HD_ + lane;
    float ov = o[off];
    float s = ov * ov;
#pragma unroll
    for (int w = 32; w > 0; w >>= 1) s += __shfl_xor(s, w, 64);
    float inv = rsqrtf(s * (1.f / 64.f) + 1e-6f);
    float zv = z[off];
    float sz = zv / (1.f + expf(-zv));   // silu(z)
    normed[off] = f2bf(ov * inv * sz);
}

extern "C" void kernel_launch(void* const* d_in, const int* in_sizes, int n_in,
                              void* d_out, int out_size, void* d_ws, size_t ws_size,
                              hipStream_t stream) {
    const float* x       = (const float*)d_in[0];
    const float* W_qkv   = (const float*)d_in[1];
    const float* conv_w  = (const float*)d_in[2];
    const float* W_z     = (const float*)d_in[3];
    const float* W_b     = (const float*)d_in[4];
    const float* W_a     = (const float*)d_in[5];
    const float* dt_bias = (const float*)d_in[6];
    const float* A_log   = (const float*)d_in[7];
    const float* W_out   = (const float*)d_in[8];
    float* out = (float*)d_out;

    float* ws = (float*)d_ws;
    // Region A [0, 12582912): mixed fp32 until conv; overlays AFTER conv:
    float* mixed  = ws;
    float* dST    = ws;                        // 4M floats (ph1 -> ph2 in-place -> ph3)
    float* o      = ws + 4194304;              // 4M floats (ph3 -> rmsnorm)
    float* betab  = ws + 8388608;              // 65,536
    float* gb     = ws + 8454144;              // 65,536
    float* cum    = ws + 8519680;              // 65,536
    float* ac     = ws + 8585216;              // 1,024
    unsigned short* Woutb = (unsigned short*)(ws + 8586240);   // 1M bf16
    // Region B [12582912, 18874368): xb/Wqkvb/Wzb pre-conv; qkvb after; normb last
    unsigned short* xb    = (unsigned short*)(ws + 12582912);  // 4M bf16
    unsigned short* Wqkvb = (unsigned short*)(ws + 14680064);  // 3M bf16
    unsigned short* Wzb   = (unsigned short*)(ws + 16252928);  // 1M bf16
    unsigned short* qkvb  = (unsigned short*)(ws + 12582912);  // 12.6M bf16
    unsigned short* normb = (unsigned short*)(ws + 12582912);  // 4M bf16 (after ph3)
    // Region C
    float* z      = ws + 18874368;             // 4M floats

    const int M = B_ * T_;                     // 4096
    dim3 blk(256);

    cvt_bf16<<<dim3(4096), blk, 0, stream>>>(x, xb, 1048576);
    cvt_bf16<<<dim3(3072), blk, 0, stream>>>(W_qkv, Wqkvb, 786432);
    cvt_bf16<<<dim3(1024), blk, 0, stream>>>(W_z, Wzb, 262144);

    gemm_bt_bf16<<<dim3(CD_ / 128, M / 128), blk, 0, stream>>>(xb, Wqkvb, mixed, M, CD_, D_);
    gemm_bt_bf16<<<dim3(D_ / 128, M / 128), blk, 0, stream>>>(xb, Wzb, z, M, D_, D_);

    conv_silu4<<<dim3((M * CD_ / 4) / 256), blk, 0, stream>>>(mixed, conv_w, qkvb);

    cvt_bf16<<<dim3(1024), blk, 0, stream>>>(W_out, Woutb, 262144);
    proj_bg2<<<dim3(M / 32), blk, 0, stream>>>(x, W_b, W_a, dt_bias, A_log, betab, gb);
    l2norm_qk<<<dim3(2 * M * H_ / 4), blk, 0, stream>>>(qkvb);

    chunk_phase1<<<dim3(B_ * H_ * NC_), blk, 0, stream>>>(qkvb, betab, gb, dST, cum, ac);
    chunk_phase2<<<dim3(B_ * H_ * 4096 / 256), blk, 0, stream>>>(dST, ac);
    chunk_phase3<<<dim3(B_ * H_ * NC_), blk, 0, stream>>>(qkvb, betab, cum, dST, o);

    rmsnorm_gate<<<dim3(M * H_ / 4), blk, 0, stream>>>(o, z, normb);
    gemm_bt_bf16<<<dim3(D_ / 128, M / 128), blk, 0, stream>>>(normb, Woutb, out, M, D_, D_);
}

// Round 6
// 237.239 us; speedup vs baseline: 7.3736x; 1.1497x over previous
//
#include <hip/hip_runtime.h>
#include <math.h>

#define B_  2
#define T_  2048
#define D_  1024
#define H_  16
#define HD_ 64
#define CD_ 3072   // 3*D
#define L_  64     // chunk length
#define NC_ 32     // T/L chunks
#define TS  72     // padded LDS stride in shorts (144 B, 16B-aligned rows)

typedef __attribute__((ext_vector_type(8))) short bf16x8;
typedef __attribute__((ext_vector_type(4))) float f32x4;
typedef __attribute__((ext_vector_type(4))) unsigned short u16x4;

__device__ __forceinline__ unsigned short f2bf(float f) {
    unsigned int u = __float_as_uint(f);
    unsigned int r = (u + 0x7fffu + ((u >> 16) & 1u)) >> 16;
    return (unsigned short)r;
}
__device__ __forceinline__ float bf2f(unsigned short u) {
    return __uint_as_float(((unsigned int)u) << 16);
}

// ---------------- fp32 -> bf16 conversion (x4 vectorized) ----------------
__global__ __launch_bounds__(256)
void cvt_bf16(const float* __restrict__ in, unsigned short* __restrict__ out, int n4) {
    int i = blockIdx.x * 256 + threadIdx.x;
    if (i >= n4) return;
    float4 a = ((const float4*)in)[i];
    u16x4 o;
    o.x = f2bf(a.x); o.y = f2bf(a.y); o.z = f2bf(a.z); o.w = f2bf(a.w);
    ((u16x4*)out)[i] = o;
}

// ---------------- bf16 MFMA GEMM NT: C[M,N] = A[M,K] * B[N,K]^T ----------------
__global__ __launch_bounds__(256)
void gemm_bt_bf16(const unsigned short* __restrict__ A,
                  const unsigned short* __restrict__ Bw,
                  float* __restrict__ C, int M, int N, int K) {
    __shared__ short As[128 * 32];
    __shared__ short Bs[128 * 32];
    const int tid = threadIdx.x;
    const int bm = blockIdx.y * 128;
    const int bn = blockIdx.x * 128;
    const int wave = tid >> 6;
    const int lane = tid & 63;
    const int wm = (wave >> 1) * 64;
    const int wn = (wave & 1) * 64;
    const int lr = lane & 15;
    const int lk = lane >> 4;

    f32x4 acc[4][4] = {};

    const int srow = tid >> 2;           // 0..63
    const int scol = (tid & 3) << 3;     // bf16 col: 0,8,16,24
    const unsigned short* Ag = A + (size_t)(bm + srow) * K + scol;
    const unsigned short* Bg = Bw + (size_t)(bn + srow) * K + scol;

    short* AsP = As + tid * 8;
    short* BsP = Bs + tid * 8;

    const short* pA = As + (wm + lr) * 32 + lk * 8;
    const short* pB = Bs + (wn + lr) * 32 + lk * 8;

    for (int k0 = 0; k0 < K; k0 += 32) {
        __builtin_amdgcn_global_load_lds(
            (const __attribute__((address_space(1))) void*)(Ag + k0),
            (__attribute__((address_space(3))) void*)AsP, 16, 0, 0);
        __builtin_amdgcn_global_load_lds(
            (const __attribute__((address_space(1))) void*)(Ag + (size_t)64 * K + k0),
            (__attribute__((address_space(3))) void*)(AsP + 2048), 16, 0, 0);
        __builtin_amdgcn_global_load_lds(
            (const __attribute__((address_space(1))) void*)(Bg + k0),
            (__attribute__((address_space(3))) void*)BsP, 16, 0, 0);
        __builtin_amdgcn_global_load_lds(
            (const __attribute__((address_space(1))) void*)(Bg + (size_t)64 * K + k0),
            (__attribute__((address_space(3))) void*)(BsP + 2048), 16, 0, 0);
        __syncthreads();

        bf16x8 a[4], b[4];
#pragma unroll
        for (int mi = 0; mi < 4; ++mi) a[mi] = *(const bf16x8*)(pA + mi * 16 * 32);
#pragma unroll
        for (int ni = 0; ni < 4; ++ni) b[ni] = *(const bf16x8*)(pB + ni * 16 * 32);
#pragma unroll
        for (int mi = 0; mi < 4; ++mi)
#pragma unroll
            for (int ni = 0; ni < 4; ++ni)
                acc[mi][ni] = __builtin_amdgcn_mfma_f32_16x16x32_bf16(
                    a[mi], b[ni], acc[mi][ni], 0, 0, 0);
        __syncthreads();
    }

    const int r0 = lk * 4;
#pragma unroll
    for (int mi = 0; mi < 4; ++mi)
#pragma unroll
        for (int ni = 0; ni < 4; ++ni) {
            float* cp = C + (size_t)(bm + wm + mi * 16 + r0) * N + bn + wn + ni * 16 + lr;
#pragma unroll
            for (int r = 0; r < 4; ++r)
                cp[(size_t)r * N] = acc[mi][ni][r];
        }
}

// ------- beta/g projection, split-K partials (fp32): 128 Mtiles x 8 Kslices -------
#define PJS 129   // padded fp32 LDS stride
__global__ __launch_bounds__(256)
void proj_bg_partial(const float* __restrict__ x, const float* __restrict__ Wb,
                     const float* __restrict__ Wa, float* __restrict__ partial) {
    const int m0 = (blockIdx.x >> 3) * 32;   // M-tile
    const int ks = blockIdx.x & 7;           // K-slice
    const int k0 = ks * 128;
    const int tid = threadIdx.x;
    __shared__ float xs[32 * PJS];
    __shared__ float wsh[32 * PJS];
    const int sr = tid >> 3;                 // 0..31
    const int sc = (tid & 7) << 4;           // 0,16,...,112
    const int mi = tid >> 3;                 // row 0..31
    const int n0 = (tid & 3) << 3;           // 0,8,16,24 (8 cols/thread)
    // note: output mapping below uses mi2/n02 (32 rows x 4 col-groups x 8)
    const int mi2 = tid >> 3;
    const int n02 = (tid & 7) << 2;          // 0,4,...,28 (4 cols/thread)

    {   // stage x[32][128] and W[32][128] slices
        const float* xrow = x + (size_t)(m0 + sr) * D_ + k0 + sc;
        const float* wrow = ((sr < 16) ? (Wb + (size_t)sr * D_) : (Wa + (size_t)(sr - 16) * D_)) + k0 + sc;
#pragma unroll
        for (int j = 0; j < 16; j += 4) {
            float4 a = *(const float4*)(xrow + j);
            float4 b = *(const float4*)(wrow + j);
            xs[sr * PJS + sc + j + 0] = a.x; xs[sr * PJS + sc + j + 1] = a.y;
            xs[sr * PJS + sc + j + 2] = a.z; xs[sr * PJS + sc + j + 3] = a.w;
            wsh[sr * PJS + sc + j + 0] = b.x; wsh[sr * PJS + sc + j + 1] = b.y;
            wsh[sr * PJS + sc + j + 2] = b.z; wsh[sr * PJS + sc + j + 3] = b.w;
        }
    }
    __syncthreads();

    float acc[4] = {0.f, 0.f, 0.f, 0.f};
#pragma unroll 8
    for (int kk = 0; kk < 128; ++kk) {
        float av = xs[mi2 * PJS + kk];
#pragma unroll
        for (int j = 0; j < 4; ++j)
            acc[j] = fmaf(av, wsh[(n02 + j) * PJS + kk], acc[j]);
    }
    float* op = partial + (size_t)ks * (4096 * 32) + (size_t)(m0 + mi2) * 32 + n02;
    *(float4*)op = make_float4(acc[0], acc[1], acc[2], acc[3]);
}

__global__ __launch_bounds__(256)
void proj_bg_reduce(const float* __restrict__ partial, const float* __restrict__ dt_bias,
                    const float* __restrict__ A_log,
                    float* __restrict__ beta, float* __restrict__ g) {
    const int gid = blockIdx.x * 256 + threadIdx.x;   // [0, 4096*32)
    const int m = gid >> 5;
    const int n = gid & 31;
    float s = 0.f;
#pragma unroll
    for (int ks = 0; ks < 8; ++ks)
        s += partial[(size_t)ks * (4096 * 32) + gid];
    if (n < 16) {
        beta[(size_t)m * H_ + n] = 1.f / (1.f + expf(-s));
    } else {
        int h = n - 16;
        float spin = s + dt_bias[h];
        float sp = (spin > 20.f) ? spin : log1pf(expf(spin));
        g[(size_t)m * H_ + h] = -expf(A_log[h]) * sp;
    }
}

// -------- causal depthwise conv (K=4) + SiLU, x4 vectorized, bf16 out --------
__global__ __launch_bounds__(256)
void conv_silu4(const float* __restrict__ mixed, const float* __restrict__ conv_w,
                unsigned short* __restrict__ qkvb) {
    int idx = blockIdx.x * 256 + threadIdx.x;   // over B*T*CD/4
    const int cq = idx % (CD_ / 4);
    const int bt = idx / (CD_ / 4);
    const int t = bt % T_;
    const int c0 = cq << 2;
    const float* base = mixed + (size_t)bt * CD_ + c0;
    const float4 zero = make_float4(0.f, 0.f, 0.f, 0.f);
    float4 m0 = *(const float4*)base;
    float4 m1 = (t >= 1) ? *(const float4*)(base - CD_) : zero;
    float4 m2 = (t >= 2) ? *(const float4*)(base - 2 * CD_) : zero;
    float4 m3 = (t >= 3) ? *(const float4*)(base - 3 * CD_) : zero;
    const float4* w = (const float4*)(conv_w + (size_t)c0 * 4);
    float4 w0 = w[0], w1 = w[1], w2 = w[2], w3 = w[3];
    float s0 = m0.x * w0.w + m1.x * w0.z + m2.x * w0.y + m3.x * w0.x;
    float s1 = m0.y * w1.w + m1.y * w1.z + m2.y * w1.y + m3.y * w1.x;
    float s2 = m0.z * w2.w + m1.z * w2.z + m2.z * w2.y + m3.z * w2.x;
    float s3 = m0.w * w3.w + m1.w * w3.z + m2.w * w3.y + m3.w * w3.x;
    u16x4 r;
    r.x = f2bf(s0 / (1.f + expf(-s0)));
    r.y = f2bf(s1 / (1.f + expf(-s1)));
    r.z = f2bf(s2 / (1.f + expf(-s2)));
    r.w = f2bf(s3 / (1.f + expf(-s3)));
    *(u16x4*)(qkvb + (size_t)bt * CD_ + c0) = r;
}

// ---------------- l2norm on q and k head-vectors (in place, bf16) ------------
__global__ __launch_bounds__(256)
void l2norm_qk(unsigned short* __restrict__ qkvb) {
    const int vec = blockIdx.x * 4 + (threadIdx.x >> 6);  // [0, 2*B*T*H)
    const int lane = threadIdx.x & 63;
    const int part = vec >> 16;          // B*T*H = 65536: 0 = q, 1 = k
    const int r = vec & 65535;
    const int h = r & 15;
    const size_t bt = (size_t)(r >> 4);
    unsigned short* p = qkvb + bt * CD_ + (size_t)part * D_ + h * HD_ + lane;
    float v = bf2f(*p);
    float s = v * v;
#pragma unroll
    for (int off = 32; off > 0; off >>= 1) s += __shfl_xor(s, off, 64);
    float scale = rsqrtf(s + 1e-6f);
    if (part == 0) scale *= 0.125f;      // HD^-0.5
    *p = f2bf(v * scale);
}

// ------------ phase 1 (MFMA): per-chunk dS^T[v][d], cum, a_c ------------
__global__ __launch_bounds__(256)
void chunk_phase1(const unsigned short* __restrict__ qkvb,
                  const float* __restrict__ beta, const float* __restrict__ gg,
                  float* __restrict__ dST, float* __restrict__ cum,
                  float* __restrict__ ac) {
    const int cid = blockIdx.x;           // (b*H+h)*NC + c
    const int c = cid & (NC_ - 1);
    const int bh = cid >> 5;
    const int b = bh >> 4, h = bh & 15;
    const int tid = threadIdx.x;
    const int wave = tid >> 6, lane = tid & 63;
    const int t0 = c * L_;

    __shared__ __align__(16) short kT[64 * TS];   // [d][s]
    __shared__ __align__(16) short vT[64 * TS];   // [v][s], weighted
    __shared__ float cumS[64], wS[64];

    const unsigned short* rowp = qkvb + (size_t)(b * T_ + t0 + lane) * CD_ + h * HD_ + wave * 16;
    bf16x8 k0 = *(const bf16x8*)(rowp + D_);
    bf16x8 k1 = *(const bf16x8*)(rowp + D_ + 8);
    bf16x8 v0 = *(const bf16x8*)(rowp + 2 * D_);
    bf16x8 v1 = *(const bf16x8*)(rowp + 2 * D_ + 8);

    if (wave == 0) {   // parallel inclusive scan of g over the 64 timesteps
        float s = gg[(size_t)(b * T_ + t0 + lane) * H_ + h];
#pragma unroll
        for (int off = 1; off < 64; off <<= 1) {
            float up = __shfl_up(s, off, 64);
            if (lane >= off) s += up;
        }
        cumS[lane] = s;
        float cend = __shfl(s, 63, 64);
        wS[lane] = expf(cend - s) * beta[(size_t)(b * T_ + t0 + lane) * H_ + h];
        cum[(size_t)bh * T_ + t0 + lane] = s;
        if (lane == 63) ac[cid] = expf(cend);
    }
    __syncthreads();
    const float w = wS[lane];
#pragma unroll
    for (int j = 0; j < 8; ++j) {
        kT[(wave * 16 + j) * TS + lane] = k0[j];
        kT[(wave * 16 + 8 + j) * TS + lane] = k1[j];
        vT[(wave * 16 + j) * TS + lane] = f2bf(bf2f((unsigned short)v0[j]) * w);
        vT[(wave * 16 + 8 + j) * TS + lane] = f2bf(bf2f((unsigned short)v1[j]) * w);
    }
    __syncthreads();

    const int lr = lane & 15, lk = lane >> 4;
    f32x4 acc[4] = {};
    const short* pA = vT + (wave * 16 + lr) * TS + lk * 8;
#pragma unroll
    for (int kk = 0; kk < 2; ++kk) {
        bf16x8 a = *(const bf16x8*)(pA + kk * 32);
#pragma unroll
        for (int n = 0; n < 4; ++n) {
            bf16x8 bfr = *(const bf16x8*)(kT + (n * 16 + lr) * TS + lk * 8 + kk * 32);
            acc[n] = __builtin_amdgcn_mfma_f32_16x16x32_bf16(a, bfr, acc[n], 0, 0, 0);
        }
    }
#pragma unroll
    for (int n = 0; n < 4; ++n) {
        float* op = dST + (size_t)cid * 4096 + (wave * 16 + lk * 4) * 64 + n * 16 + lr;
#pragma unroll
        for (int r = 0; r < 4; ++r)
            op[r * 64] = acc[n][r];
    }
}

// ---------------- phase 2: scan over chunks, IN PLACE (dST -> states) --------
__global__ __launch_bounds__(256)
void chunk_phase2(float* __restrict__ dST, const float* __restrict__ ac) {
    const int gid = blockIdx.x * 256 + threadIdx.x;  // B*H*4096 = 131072
    const int bh = gid >> 12;
    const int e = gid & 4095;
    float s = 0.f;
    for (int c = 0; c < NC_; ++c) {
        size_t off = (size_t)(bh * NC_ + c) * 4096 + e;
        float tmp = dST[off];
        dST[off] = s;                 // state ENTERING chunk c (transposed layout)
        s = fmaf(ac[bh * NC_ + c], s, tmp);
    }
}

// ------------ phase 3 (MFMA): O = exp(ct)*Q*S_in + (decayed P)*V ------------
__global__ __launch_bounds__(256)
void chunk_phase3(const unsigned short* __restrict__ qkvb,
                  const float* __restrict__ beta, const float* __restrict__ cum,
                  const float* __restrict__ states,   // dST layout [cid][v][d] fp32
                  float* __restrict__ o) {
    const int cid = blockIdx.x;
    const int c = cid & (NC_ - 1);
    const int bh = cid >> 5;
    const int b = bh >> 4, h = bh & 15;
    const int tid = threadIdx.x;
    const int wave = tid >> 6, lane = tid & 63;
    const int t0 = c * L_;

    __shared__ __align__(16) short vT[64 * TS];   // [v][s]
    __shared__ __align__(16) short sT[64 * TS];   // S_in^T bf16 [v][d]
    __shared__ __align__(16) short pS[64 * TS];   // P [t][s] bf16
    __shared__ float cumS[64], betaS[64];

    {
        const unsigned short* rowp = qkvb + (size_t)(b * T_ + t0 + lane) * CD_ + 2 * D_ + h * HD_ + wave * 16;
        bf16x8 v0 = *(const bf16x8*)rowp;
        bf16x8 v1 = *(const bf16x8*)(rowp + 8);
#pragma unroll
        for (int j = 0; j < 8; ++j) {
            vT[(wave * 16 + j) * TS + lane] = v0[j];
            vT[(wave * 16 + 8 + j) * TS + lane] = v1[j];
        }
    }
    {
        const float* sp = states + (size_t)cid * 4096 + (tid >> 2) * 64 + (tid & 3) * 16;
        short* dp = sT + (tid >> 2) * TS + (tid & 3) * 16;
#pragma unroll
        for (int j = 0; j < 16; j += 4) {
            float4 f = *(const float4*)(sp + j);
            dp[j] = f2bf(f.x); dp[j + 1] = f2bf(f.y);
            dp[j + 2] = f2bf(f.z); dp[j + 3] = f2bf(f.w);
        }
    }
    if (tid < 64) {
        cumS[tid] = cum[(size_t)bh * T_ + t0 + tid];
        betaS[tid] = beta[(size_t)(b * T_ + t0 + tid) * H_ + h];
    }
    __syncthreads();

    const int lr = lane & 15, lk = lane >> 4;
    const unsigned short* qrow = qkvb + (size_t)(b * T_ + t0 + wave * 16 + lr) * CD_ + h * HD_;
    bf16x8 qf0 = *(const bf16x8*)(qrow + lk * 8);
    bf16x8 qf1 = *(const bf16x8*)(qrow + 32 + lk * 8);

    f32x4 pacc[4] = {};
#pragma unroll
    for (int n = 0; n < 4; ++n) {
        const unsigned short* krow = qkvb + (size_t)(b * T_ + t0 + n * 16 + lr) * CD_ + D_ + h * HD_;
        bf16x8 b0 = *(const bf16x8*)(krow + lk * 8);
        bf16x8 b1 = *(const bf16x8*)(krow + 32 + lk * 8);
        pacc[n] = __builtin_amdgcn_mfma_f32_16x16x32_bf16(qf0, b0, pacc[n], 0, 0, 0);
        pacc[n] = __builtin_amdgcn_mfma_f32_16x16x32_bf16(qf1, b1, pacc[n], 0, 0, 0);
    }
#pragma unroll
    for (int n = 0; n < 4; ++n) {
        int s = n * 16 + lr;
        float cs = cumS[s], bs = betaS[s];
#pragma unroll
        for (int r = 0; r < 4; ++r) {
            int t = wave * 16 + lk * 4 + r;
            float pv = (s <= t) ? expf(cumS[t] - cs) * bs * pacc[n][r] : 0.f;
            pS[t * TS + s] = f2bf(pv);
        }
    }
    __syncthreads();

    f32x4 oacc[4] = {};
#pragma unroll
    for (int n = 0; n < 4; ++n) {
        const short* srow = sT + (n * 16 + lr) * TS + lk * 8;
        bf16x8 b0 = *(const bf16x8*)srow;
        bf16x8 b1 = *(const bf16x8*)(srow + 32);
        oacc[n] = __builtin_amdgcn_mfma_f32_16x16x32_bf16(qf0, b0, oacc[n], 0, 0, 0);
        oacc[n] = __builtin_amdgcn_mfma_f32_16x16x32_bf16(qf1, b1, oacc[n], 0, 0, 0);
    }
    float ect[4];
#pragma unroll
    for (int r = 0; r < 4; ++r) ect[r] = expf(cumS[wave * 16 + lk * 4 + r]);
#pragma unroll
    for (int n = 0; n < 4; ++n)
#pragma unroll
        for (int r = 0; r < 4; ++r) oacc[n][r] *= ect[r];
    const short* prow = pS + (wave * 16 + lr) * TS + lk * 8;
    bf16x8 pf0 = *(const bf16x8*)prow;
    bf16x8 pf1 = *(const bf16x8*)(prow + 32);
#pragma unroll
    for (int n = 0; n < 4; ++n) {
        const short* vrow = vT + (n * 16 + lr) * TS + lk * 8;
        bf16x8 b0 = *(const bf16x8*)vrow;
        bf16x8 b1 = *(const bf16x8*)(vrow + 32);
        oacc[n] = __builtin_amdgcn_mfma_f32_16x16x32_bf16(pf0, b0, oacc[n], 0, 0, 0);
        oacc[n] = __builtin_amdgcn_mfma_f32_16x16x32_bf16(pf1, b1, oacc[n], 0, 0, 0);
    }
#pragma unroll
    for (int n = 0; n < 4; ++n) {
        float* op = o + (size_t)(b * T_ + t0 + wave * 16 + lk * 4) * D_ + h * HD_ + n * 16 + lr;
#pragma unroll
        for (int r = 0; r < 4; ++r)
            op[(size_t)r * D_] = oacc[n][r];
    }
}

// ---------------- gated RMSNorm over head dim, bf16 output ----------------
__global__ __launch_bounds__(256)
void rmsnorm_gate(const float* __restrict__ o, const float* __restrict__ z,
                  unsigned short* __restrict__ normed) {
    const int vec = blockIdx.x * 4 + (threadIdx.x >> 6);  // [0, B*T*H)
    const int lane = threadIdx.x & 63;
    const size_t bt = (size_t)(vec >> 4);
    const int h = vec & 15;
    const size_t off = bt * D_ + h * HD_ + lane;
    float ov = o[off];
    float s = ov * ov;
#pragma unroll
    for (int w = 32; w > 0; w >>= 1) s += __shfl_xor(s, w, 64);
    float inv = rsqrtf(s * (1.f / 64.f) + 1e-6f);
    float zv = z[off];
    float sz = zv / (1.f + expf(-zv));   // silu(z)
    normed[off] = f2bf(ov * inv * sz);
}

extern "C" void kernel_launch(void* const* d_in, const int* in_sizes, int n_in,
                              void* d_out, int out_size, void* d_ws, size_t ws_size,
                              hipStream_t stream) {
    const float* x       = (const float*)d_in[0];
    const float* W_qkv   = (const float*)d_in[1];
    const float* conv_w  = (const float*)d_in[2];
    const float* W_z     = (const float*)d_in[3];
    const float* W_b     = (const float*)d_in[4];
    const float* W_a     = (const float*)d_in[5];
    const float* dt_bias = (const float*)d_in[6];
    const float* A_log   = (const float*)d_in[7];
    const float* W_out   = (const float*)d_in[8];
    float* out = (float*)d_out;

    float* ws = (float*)d_ws;
    // Region A [0, 12582912): mixed fp32 until conv; overlays AFTER conv:
    float* mixed  = ws;
    float* dST    = ws;                        // 4M floats (ph1 -> ph2 in-place -> ph3)
    float* o      = ws + 4194304;              // 4M floats (ph3 -> rmsnorm)
    float* betab  = ws + 8388608;              // 65,536
    float* gb     = ws + 8454144;              // 65,536
    float* cum    = ws + 8519680;              // 65,536
    float* ac     = ws + 8585216;              // 1,024
    unsigned short* Woutb = (unsigned short*)(ws + 8586240);   // 1M bf16
    // Region B [12582912, 18874368): xb/Wqkvb/Wzb pre-conv; qkvb after; normb last
    unsigned short* xb    = (unsigned short*)(ws + 12582912);  // 4M bf16
    unsigned short* Wqkvb = (unsigned short*)(ws + 14680064);  // 3M bf16
    unsigned short* Wzb   = (unsigned short*)(ws + 16252928);  // 1M bf16
    unsigned short* qkvb  = (unsigned short*)(ws + 12582912);  // 12.6M bf16
    unsigned short* normb = (unsigned short*)(ws + 12582912);  // 4M bf16 (after ph3)
    // Region C
    float* z      = ws + 18874368;             // 4M floats
    float* bgpart = ws + 23068672;             // 8*4096*32 = 1,048,576 floats (4 MB)

    const int M = B_ * T_;                     // 4096
    dim3 blk(256);

    cvt_bf16<<<dim3(4096), blk, 0, stream>>>(x, xb, 1048576);
    cvt_bf16<<<dim3(3072), blk, 0, stream>>>(W_qkv, Wqkvb, 786432);
    cvt_bf16<<<dim3(1024), blk, 0, stream>>>(W_z, Wzb, 262144);

    gemm_bt_bf16<<<dim3(CD_ / 128, M / 128), blk, 0, stream>>>(xb, Wqkvb, mixed, M, CD_, D_);
    gemm_bt_bf16<<<dim3(D_ / 128, M / 128), blk, 0, stream>>>(xb, Wzb, z, M, D_, D_);

    conv_silu4<<<dim3((M * CD_ / 4) / 256), blk, 0, stream>>>(mixed, conv_w, qkvb);

    cvt_bf16<<<dim3(1024), blk, 0, stream>>>(W_out, Woutb, 262144);
    proj_bg_partial<<<dim3(1024), blk, 0, stream>>>(x, W_b, W_a, bgpart);
    proj_bg_reduce<<<dim3(512), blk, 0, stream>>>(bgpart, dt_bias, A_log, betab, gb);
    l2norm_qk<<<dim3(2 * M * H_ / 4), blk, 0, stream>>>(qkvb);

    chunk_phase1<<<dim3(B_ * H_ * NC_), blk, 0, stream>>>(qkvb, betab, gb, dST, cum, ac);
    chunk_phase2<<<dim3(B_ * H_ * 4096 / 256), blk, 0, stream>>>(dST, ac);
    chunk_phase3<<<dim3(B_ * H_ * NC_), blk, 0, stream>>>(qkvb, betab, cum, dST, o);

    rmsnorm_gate<<<dim3(M * H_ / 4), blk, 0, stream>>>(o, z, normb);
    gemm_bt_bf16<<<dim3(D_ / 128, M / 128), blk, 0, stream>>>(normb, Woutb, out, M, D_, D_);
}

// Round 7
// 206.794 us; speedup vs baseline: 8.4591x; 1.1472x over previous
//
#include <hip/hip_runtime.h>
#include <math.h>

#define B_  2
#define T_  2048
#define D_  1024
#define H_  16
#define HD_ 64
#define CD_ 3072   // 3*D
#define L_  64     // chunk length
#define NC_ 32     // T/L chunks
#define TS  72     // padded LDS stride in shorts (144 B, 16B-aligned rows)
#define TT  8      // conv time-tile

typedef __attribute__((ext_vector_type(8))) short bf16x8;
typedef __attribute__((ext_vector_type(4))) float f32x4;
typedef __attribute__((ext_vector_type(4))) unsigned short u16x4;

__device__ __forceinline__ unsigned short f2bf(float f) {
    unsigned int u = __float_as_uint(f);
    unsigned int r = (u + 0x7fffu + ((u >> 16) & 1u)) >> 16;
    return (unsigned short)r;
}
__device__ __forceinline__ float bf2f(unsigned short u) {
    return __uint_as_float(((unsigned int)u) << 16);
}

// ---------------- fp32 -> bf16 conversion (x4 vectorized) ----------------
__global__ __launch_bounds__(256)
void cvt_bf16(const float* __restrict__ in, unsigned short* __restrict__ out, int n4) {
    int i = blockIdx.x * 256 + threadIdx.x;
    if (i >= n4) return;
    float4 a = ((const float4*)in)[i];
    u16x4 o;
    o.x = f2bf(a.x); o.y = f2bf(a.y); o.z = f2bf(a.z); o.w = f2bf(a.w);
    ((u16x4*)out)[i] = o;
}

// ------- bf16 MFMA GEMM NT: C[M,N] = A[M,K] * B[N,K]^T; OBF: bf16 C -------
template<int OBF>
__global__ __launch_bounds__(256)
void gemm_bt_bf16(const unsigned short* __restrict__ A,
                  const unsigned short* __restrict__ Bw,
                  void* __restrict__ Cv, int M, int N, int K) {
    __shared__ short As[128 * 32];
    __shared__ short Bs[128 * 32];
    const int tid = threadIdx.x;
    const int bm = blockIdx.y * 128;
    const int bn = blockIdx.x * 128;
    const int wave = tid >> 6;
    const int lane = tid & 63;
    const int wm = (wave >> 1) * 64;
    const int wn = (wave & 1) * 64;
    const int lr = lane & 15;
    const int lk = lane >> 4;

    f32x4 acc[4][4] = {};

    const int srow = tid >> 2;           // 0..63
    const int scol = (tid & 3) << 3;     // bf16 col: 0,8,16,24
    const unsigned short* Ag = A + (size_t)(bm + srow) * K + scol;
    const unsigned short* Bg = Bw + (size_t)(bn + srow) * K + scol;

    short* AsP = As + tid * 8;
    short* BsP = Bs + tid * 8;

    const short* pA = As + (wm + lr) * 32 + lk * 8;
    const short* pB = Bs + (wn + lr) * 32 + lk * 8;

    for (int k0 = 0; k0 < K; k0 += 32) {
        __builtin_amdgcn_global_load_lds(
            (const __attribute__((address_space(1))) void*)(Ag + k0),
            (__attribute__((address_space(3))) void*)AsP, 16, 0, 0);
        __builtin_amdgcn_global_load_lds(
            (const __attribute__((address_space(1))) void*)(Ag + (size_t)64 * K + k0),
            (__attribute__((address_space(3))) void*)(AsP + 2048), 16, 0, 0);
        __builtin_amdgcn_global_load_lds(
            (const __attribute__((address_space(1))) void*)(Bg + k0),
            (__attribute__((address_space(3))) void*)BsP, 16, 0, 0);
        __builtin_amdgcn_global_load_lds(
            (const __attribute__((address_space(1))) void*)(Bg + (size_t)64 * K + k0),
            (__attribute__((address_space(3))) void*)(BsP + 2048), 16, 0, 0);
        __syncthreads();

        bf16x8 a[4], b[4];
#pragma unroll
        for (int mi = 0; mi < 4; ++mi) a[mi] = *(const bf16x8*)(pA + mi * 16 * 32);
#pragma unroll
        for (int ni = 0; ni < 4; ++ni) b[ni] = *(const bf16x8*)(pB + ni * 16 * 32);
#pragma unroll
        for (int mi = 0; mi < 4; ++mi)
#pragma unroll
            for (int ni = 0; ni < 4; ++ni)
                acc[mi][ni] = __builtin_amdgcn_mfma_f32_16x16x32_bf16(
                    a[mi], b[ni], acc[mi][ni], 0, 0, 0);
        __syncthreads();
    }

    const int r0 = lk * 4;
#pragma unroll
    for (int mi = 0; mi < 4; ++mi)
#pragma unroll
        for (int ni = 0; ni < 4; ++ni) {
            size_t base = (size_t)(bm + wm + mi * 16 + r0) * N + bn + wn + ni * 16 + lr;
            if (OBF) {
                unsigned short* cp = (unsigned short*)Cv + base;
#pragma unroll
                for (int r = 0; r < 4; ++r)
                    cp[(size_t)r * N] = f2bf(acc[mi][ni][r]);
            } else {
                float* cp = (float*)Cv + base;
#pragma unroll
                for (int r = 0; r < 4; ++r)
                    cp[(size_t)r * N] = acc[mi][ni][r];
            }
        }
}

// ------- beta/g projection, split-K partials (fp32): 128 Mtiles x 8 Kslices -------
#define PJS 129   // padded fp32 LDS stride
__global__ __launch_bounds__(256)
void proj_bg_partial(const float* __restrict__ x, const float* __restrict__ Wb,
                     const float* __restrict__ Wa, float* __restrict__ partial) {
    const int m0 = (blockIdx.x >> 3) * 32;   // M-tile
    const int ks = blockIdx.x & 7;           // K-slice
    const int k0 = ks * 128;
    const int tid = threadIdx.x;
    __shared__ float xs[32 * PJS];
    __shared__ float wsh[32 * PJS];
    const int sr = tid >> 3;                 // 0..31
    const int sc = (tid & 7) << 4;           // 0,16,...,112
    const int mi2 = tid >> 3;
    const int n02 = (tid & 7) << 2;          // 0,4,...,28

    {
        const float* xrow = x + (size_t)(m0 + sr) * D_ + k0 + sc;
        const float* wrow = ((sr < 16) ? (Wb + (size_t)sr * D_) : (Wa + (size_t)(sr - 16) * D_)) + k0 + sc;
#pragma unroll
        for (int j = 0; j < 16; j += 4) {
            float4 a = *(const float4*)(xrow + j);
            float4 b = *(const float4*)(wrow + j);
            xs[sr * PJS + sc + j + 0] = a.x; xs[sr * PJS + sc + j + 1] = a.y;
            xs[sr * PJS + sc + j + 2] = a.z; xs[sr * PJS + sc + j + 3] = a.w;
            wsh[sr * PJS + sc + j + 0] = b.x; wsh[sr * PJS + sc + j + 1] = b.y;
            wsh[sr * PJS + sc + j + 2] = b.z; wsh[sr * PJS + sc + j + 3] = b.w;
        }
    }
    __syncthreads();

    float acc[4] = {0.f, 0.f, 0.f, 0.f};
#pragma unroll 8
    for (int kk = 0; kk < 128; ++kk) {
        float av = xs[mi2 * PJS + kk];
#pragma unroll
        for (int j = 0; j < 4; ++j)
            acc[j] = fmaf(av, wsh[(n02 + j) * PJS + kk], acc[j]);
    }
    float* op = partial + (size_t)ks * (4096 * 32) + (size_t)(m0 + mi2) * 32 + n02;
    *(float4*)op = make_float4(acc[0], acc[1], acc[2], acc[3]);
}

__global__ __launch_bounds__(256)
void proj_bg_reduce(const float* __restrict__ partial, const float* __restrict__ dt_bias,
                    const float* __restrict__ A_log,
                    float* __restrict__ beta, float* __restrict__ g) {
    const int gid = blockIdx.x * 256 + threadIdx.x;   // [0, 4096*32)
    const int m = gid >> 5;
    const int n = gid & 31;
    float s = 0.f;
#pragma unroll
    for (int ks = 0; ks < 8; ++ks)
        s += partial[(size_t)ks * (4096 * 32) + gid];
    if (n < 16) {
        beta[(size_t)m * H_ + n] = 1.f / (1.f + expf(-s));
    } else {
        int h = n - 16;
        float spin = s + dt_bias[h];
        float sp = (spin > 20.f) ? spin : log1pf(expf(spin));
        g[(size_t)m * H_ + h] = -expf(A_log[h]) * sp;
    }
}

// ---- causal depthwise conv (K=4) + SiLU: bf16 in, time-tiled x8, bf16 out ----
__global__ __launch_bounds__(256)
void conv_silu_tt(const unsigned short* __restrict__ mixedb,
                  const float* __restrict__ conv_w,
                  unsigned short* __restrict__ qkvb) {
    int idx = blockIdx.x * 256 + threadIdx.x;   // over B*(T/TT)*(CD/4)
    const int cq = idx % (CD_ / 4);
    const int bt8 = idx / (CD_ / 4);
    const int t0 = (bt8 % (T_ / TT)) * TT;
    const int b = bt8 / (T_ / TT);
    const int c0 = cq << 2;
    const unsigned short* base = mixedb + (size_t)(b * T_ + t0) * CD_ + c0;

    float vals[TT + 3][4];
#pragma unroll
    for (int i = 0; i < TT + 3; ++i) {
        int t = t0 + i - 3;
        if (t >= 0) {
            u16x4 m = *(const u16x4*)(base + (ptrdiff_t)(i - 3) * CD_);
            vals[i][0] = bf2f(m.x); vals[i][1] = bf2f(m.y);
            vals[i][2] = bf2f(m.z); vals[i][3] = bf2f(m.w);
        } else {
            vals[i][0] = vals[i][1] = vals[i][2] = vals[i][3] = 0.f;
        }
    }
    const float4* wp = (const float4*)(conv_w + (size_t)c0 * 4);
    float4 w[4] = {wp[0], wp[1], wp[2], wp[3]};   // w[j].x oldest .. w[j].w current

    unsigned short* outp = qkvb + (size_t)(b * T_ + t0) * CD_ + c0;
#pragma unroll
    for (int tt = 0; tt < TT; ++tt) {
        u16x4 r;
        float s0 = vals[tt + 3][0] * w[0].w + vals[tt + 2][0] * w[0].z
                 + vals[tt + 1][0] * w[0].y + vals[tt + 0][0] * w[0].x;
        float s1 = vals[tt + 3][1] * w[1].w + vals[tt + 2][1] * w[1].z
                 + vals[tt + 1][1] * w[1].y + vals[tt + 0][1] * w[1].x;
        float s2 = vals[tt + 3][2] * w[2].w + vals[tt + 2][2] * w[2].z
                 + vals[tt + 1][2] * w[2].y + vals[tt + 0][2] * w[2].x;
        float s3 = vals[tt + 3][3] * w[3].w + vals[tt + 2][3] * w[3].z
                 + vals[tt + 1][3] * w[3].y + vals[tt + 0][3] * w[3].x;
        r.x = f2bf(s0 / (1.f + expf(-s0)));
        r.y = f2bf(s1 / (1.f + expf(-s1)));
        r.z = f2bf(s2 / (1.f + expf(-s2)));
        r.w = f2bf(s3 / (1.f + expf(-s3)));
        *(u16x4*)(outp + (size_t)tt * CD_) = r;
    }
}

// ---------------- l2norm on q and k head-vectors (in place, bf16) ------------
__global__ __launch_bounds__(256)
void l2norm_qk(unsigned short* __restrict__ qkvb) {
    const int vec = blockIdx.x * 4 + (threadIdx.x >> 6);  // [0, 2*B*T*H)
    const int lane = threadIdx.x & 63;
    const int part = vec >> 16;          // B*T*H = 65536: 0 = q, 1 = k
    const int r = vec & 65535;
    const int h = r & 15;
    const size_t bt = (size_t)(r >> 4);
    unsigned short* p = qkvb + bt * CD_ + (size_t)part * D_ + h * HD_ + lane;
    float v = bf2f(*p);
    float s = v * v;
#pragma unroll
    for (int off = 32; off > 0; off >>= 1) s += __shfl_xor(s, off, 64);
    float scale = rsqrtf(s + 1e-6f);
    if (part == 0) scale *= 0.125f;      // HD^-0.5
    *p = f2bf(v * scale);
}

// ------------ phase 1 (MFMA): per-chunk dS^T[v][d], cum, a_c ------------
__global__ __launch_bounds__(256)
void chunk_phase1(const unsigned short* __restrict__ qkvb,
                  const float* __restrict__ beta, const float* __restrict__ gg,
                  float* __restrict__ dST, float* __restrict__ cum,
                  float* __restrict__ ac) {
    const int cid = blockIdx.x;           // (b*H+h)*NC + c
    const int c = cid & (NC_ - 1);
    const int bh = cid >> 5;
    const int b = bh >> 4, h = bh & 15;
    const int tid = threadIdx.x;
    const int wave = tid >> 6, lane = tid & 63;
    const int t0 = c * L_;

    __shared__ __align__(16) short kT[64 * TS];   // [d][s]
    __shared__ __align__(16) short vT[64 * TS];   // [v][s], weighted
    __shared__ float cumS[64], wS[64];

    const unsigned short* rowp = qkvb + (size_t)(b * T_ + t0 + lane) * CD_ + h * HD_ + wave * 16;
    bf16x8 k0 = *(const bf16x8*)(rowp + D_);
    bf16x8 k1 = *(const bf16x8*)(rowp + D_ + 8);
    bf16x8 v0 = *(const bf16x8*)(rowp + 2 * D_);
    bf16x8 v1 = *(const bf16x8*)(rowp + 2 * D_ + 8);

    if (wave == 0) {   // parallel inclusive scan of g over the 64 timesteps
        float s = gg[(size_t)(b * T_ + t0 + lane) * H_ + h];
#pragma unroll
        for (int off = 1; off < 64; off <<= 1) {
            float up = __shfl_up(s, off, 64);
            if (lane >= off) s += up;
        }
        cumS[lane] = s;
        float cend = __shfl(s, 63, 64);
        wS[lane] = expf(cend - s) * beta[(size_t)(b * T_ + t0 + lane) * H_ + h];
        cum[(size_t)bh * T_ + t0 + lane] = s;
        if (lane == 63) ac[cid] = expf(cend);
    }
    __syncthreads();
    const float w = wS[lane];
#pragma unroll
    for (int j = 0; j < 8; ++j) {
        kT[(wave * 16 + j) * TS + lane] = k0[j];
        kT[(wave * 16 + 8 + j) * TS + lane] = k1[j];
        vT[(wave * 16 + j) * TS + lane] = f2bf(bf2f((unsigned short)v0[j]) * w);
        vT[(wave * 16 + 8 + j) * TS + lane] = f2bf(bf2f((unsigned short)v1[j]) * w);
    }
    __syncthreads();

    const int lr = lane & 15, lk = lane >> 4;
    f32x4 acc[4] = {};
    const short* pA = vT + (wave * 16 + lr) * TS + lk * 8;
#pragma unroll
    for (int kk = 0; kk < 2; ++kk) {
        bf16x8 a = *(const bf16x8*)(pA + kk * 32);
#pragma unroll
        for (int n = 0; n < 4; ++n) {
            bf16x8 bfr = *(const bf16x8*)(kT + (n * 16 + lr) * TS + lk * 8 + kk * 32);
            acc[n] = __builtin_amdgcn_mfma_f32_16x16x32_bf16(a, bfr, acc[n], 0, 0, 0);
        }
    }
#pragma unroll
    for (int n = 0; n < 4; ++n) {
        float* op = dST + (size_t)cid * 4096 + (wave * 16 + lk * 4) * 64 + n * 16 + lr;
#pragma unroll
        for (int r = 0; r < 4; ++r)
            op[r * 64] = acc[n][r];
    }
}

// ---------------- phase 2: scan over chunks, IN PLACE (dST -> states) --------
__global__ __launch_bounds__(256)
void chunk_phase2(float* __restrict__ dST, const float* __restrict__ ac) {
    const int gid = blockIdx.x * 256 + threadIdx.x;  // B*H*4096 = 131072
    const int bh = gid >> 12;
    const int e = gid & 4095;
    float s = 0.f;
    for (int c = 0; c < NC_; ++c) {
        size_t off = (size_t)(bh * NC_ + c) * 4096 + e;
        float tmp = dST[off];
        dST[off] = s;                 // state ENTERING chunk c (transposed layout)
        s = fmaf(ac[bh * NC_ + c], s, tmp);
    }
}

// ------------ phase 3 (MFMA): O = exp(ct)*Q*S_in + (decayed P)*V ------------
__global__ __launch_bounds__(256)
void chunk_phase3(const unsigned short* __restrict__ qkvb,
                  const float* __restrict__ beta, const float* __restrict__ cum,
                  const float* __restrict__ states,   // dST layout [cid][v][d] fp32
                  float* __restrict__ o) {
    const int cid = blockIdx.x;
    const int c = cid & (NC_ - 1);
    const int bh = cid >> 5;
    const int b = bh >> 4, h = bh & 15;
    const int tid = threadIdx.x;
    const int wave = tid >> 6, lane = tid & 63;
    const int t0 = c * L_;

    __shared__ __align__(16) short vT[64 * TS];   // [v][s]
    __shared__ __align__(16) short sT[64 * TS];   // S_in^T bf16 [v][d]
    __shared__ __align__(16) short pS[64 * TS];   // P [t][s] bf16
    __shared__ float cumS[64], betaS[64];

    {
        const unsigned short* rowp = qkvb + (size_t)(b * T_ + t0 + lane) * CD_ + 2 * D_ + h * HD_ + wave * 16;
        bf16x8 v0 = *(const bf16x8*)rowp;
        bf16x8 v1 = *(const bf16x8*)(rowp + 8);
#pragma unroll
        for (int j = 0; j < 8; ++j) {
            vT[(wave * 16 + j) * TS + lane] = v0[j];
            vT[(wave * 16 + 8 + j) * TS + lane] = v1[j];
        }
    }
    {
        const float* sp = states + (size_t)cid * 4096 + (tid >> 2) * 64 + (tid & 3) * 16;
        short* dp = sT + (tid >> 2) * TS + (tid & 3) * 16;
#pragma unroll
        for (int j = 0; j < 16; j += 4) {
            float4 f = *(const float4*)(sp + j);
            dp[j] = f2bf(f.x); dp[j + 1] = f2bf(f.y);
            dp[j + 2] = f2bf(f.z); dp[j + 3] = f2bf(f.w);
        }
    }
    if (tid < 64) {
        cumS[tid] = cum[(size_t)bh * T_ + t0 + tid];
        betaS[tid] = beta[(size_t)(b * T_ + t0 + tid) * H_ + h];
    }
    __syncthreads();

    const int lr = lane & 15, lk = lane >> 4;
    const unsigned short* qrow = qkvb + (size_t)(b * T_ + t0 + wave * 16 + lr) * CD_ + h * HD_;
    bf16x8 qf0 = *(const bf16x8*)(qrow + lk * 8);
    bf16x8 qf1 = *(const bf16x8*)(qrow + 32 + lk * 8);

    f32x4 pacc[4] = {};
#pragma unroll
    for (int n = 0; n < 4; ++n) {
        const unsigned short* krow = qkvb + (size_t)(b * T_ + t0 + n * 16 + lr) * CD_ + D_ + h * HD_;
        bf16x8 b0 = *(const bf16x8*)(krow + lk * 8);
        bf16x8 b1 = *(const bf16x8*)(krow + 32 + lk * 8);
        pacc[n] = __builtin_amdgcn_mfma_f32_16x16x32_bf16(qf0, b0, pacc[n], 0, 0, 0);
        pacc[n] = __builtin_amdgcn_mfma_f32_16x16x32_bf16(qf1, b1, pacc[n], 0, 0, 0);
    }
#pragma unroll
    for (int n = 0; n < 4; ++n) {
        int s = n * 16 + lr;
        float cs = cumS[s], bs = betaS[s];
#pragma unroll
        for (int r = 0; r < 4; ++r) {
            int t = wave * 16 + lk * 4 + r;
            float pv = (s <= t) ? expf(cumS[t] - cs) * bs * pacc[n][r] : 0.f;
            pS[t * TS + s] = f2bf(pv);
        }
    }
    __syncthreads();

    f32x4 oacc[4] = {};
#pragma unroll
    for (int n = 0; n < 4; ++n) {
        const short* srow = sT + (n * 16 + lr) * TS + lk * 8;
        bf16x8 b0 = *(const bf16x8*)srow;
        bf16x8 b1 = *(const bf16x8*)(srow + 32);
        oacc[n] = __builtin_amdgcn_mfma_f32_16x16x32_bf16(qf0, b0, oacc[n], 0, 0, 0);
        oacc[n] = __builtin_amdgcn_mfma_f32_16x16x32_bf16(qf1, b1, oacc[n], 0, 0, 0);
    }
    float ect[4];
#pragma unroll
    for (int r = 0; r < 4; ++r) ect[r] = expf(cumS[wave * 16 + lk * 4 + r]);
#pragma unroll
    for (int n = 0; n < 4; ++n)
#pragma unroll
        for (int r = 0; r < 4; ++r) oacc[n][r] *= ect[r];
    const short* prow = pS + (wave * 16 + lr) * TS + lk * 8;
    bf16x8 pf0 = *(const bf16x8*)prow;
    bf16x8 pf1 = *(const bf16x8*)(prow + 32);
#pragma unroll
    for (int n = 0; n < 4; ++n) {
        const short* vrow = vT + (n * 16 + lr) * TS + lk * 8;
        bf16x8 b0 = *(const bf16x8*)vrow;
        bf16x8 b1 = *(const bf16x8*)(vrow + 32);
        oacc[n] = __builtin_amdgcn_mfma_f32_16x16x32_bf16(pf0, b0, oacc[n], 0, 0, 0);
        oacc[n] = __builtin_amdgcn_mfma_f32_16x16x32_bf16(pf1, b1, oacc[n], 0, 0, 0);
    }
#pragma unroll
    for (int n = 0; n < 4; ++n) {
        float* op = o + (size_t)(b * T_ + t0 + wave * 16 + lk * 4) * D_ + h * HD_ + n * 16 + lr;
#pragma unroll
        for (int r = 0; r < 4; ++r)
            op[(size_t)r * D_] = oacc[n][r];
    }
}

// ---------------- gated RMSNorm over head dim, bf16 output ----------------
__global__ __launch_bounds__(256)
void rmsnorm_gate(const float* __restrict__ o, const float* __restrict__ z,
                  unsigned short* __restrict__ normed) {
    const int vec = blockIdx.x * 4 + (threadIdx.x >> 6);  // [0, B*T*H)
    const int lane = threadIdx.x & 63;
    const size_t bt = (size_t)(vec >> 4);
    const int h = vec & 15;
    const size_t off = bt * D_ + h * HD_ + lane;
    float ov = o[off];
    float s = ov * ov;
#pragma unroll
    for (int w = 32; w > 0; w >>= 1) s += __shfl_xor(s, w, 64);
    float inv = rsqrtf(s * (1.f / 64.f) + 1e-6f);
    float zv = z[off];
    float sz = zv / (1.f + expf(-zv));   // silu(z)
    normed[off] = f2bf(ov * inv * sz);
}

extern "C" void kernel_launch(void* const* d_in, const int* in_sizes, int n_in,
                              void* d_out, int out_size, void* d_ws, size_t ws_size,
                              hipStream_t stream) {
    const float* x       = (const float*)d_in[0];
    const float* W_qkv   = (const float*)d_in[1];
    const float* conv_w  = (const float*)d_in[2];
    const float* W_z     = (const float*)d_in[3];
    const float* W_b     = (const float*)d_in[4];
    const float* W_a     = (const float*)d_in[5];
    const float* dt_bias = (const float*)d_in[6];
    const float* A_log   = (const float*)d_in[7];
    const float* W_out   = (const float*)d_in[8];
    float* out = (float*)d_out;

    float* ws = (float*)d_ws;
    // Region A [0, 12582912 floats): mixedb (bf16, 6.29M floats) until conv; then:
    unsigned short* mixedb = (unsigned short*)ws;              // 12.6M bf16 (25 MB)
    float* dST    = ws;                        // 4M floats (ph1 -> ph2 in-place -> ph3)
    float* o      = ws + 4194304;              // 4M floats (ph3 -> rmsnorm)
    float* betab  = ws + 8388608;              // 65,536
    float* gb     = ws + 8454144;              // 65,536
    float* cum    = ws + 8519680;              // 65,536
    float* ac     = ws + 8585216;              // 1,024
    unsigned short* Woutb = (unsigned short*)(ws + 8586240);   // 1M bf16
    // Region B [12582912, 18874368): xb/Wqkvb/Wzb pre-conv; qkvb after; normb last
    unsigned short* xb    = (unsigned short*)(ws + 12582912);  // 4M bf16
    unsigned short* Wqkvb = (unsigned short*)(ws + 14680064);  // 3M bf16
    unsigned short* Wzb   = (unsigned short*)(ws + 16252928);  // 1M bf16
    unsigned short* qkvb  = (unsigned short*)(ws + 12582912);  // 12.6M bf16
    unsigned short* normb = (unsigned short*)(ws + 12582912);  // 4M bf16 (after ph3)
    // Region C
    float* z      = ws + 18874368;             // 4M floats
    float* bgpart = ws + 23068672;             // 8*4096*32 = 1,048,576 floats (4 MB)

    const int M = B_ * T_;                     // 4096
    dim3 blk(256);

    cvt_bf16<<<dim3(4096), blk, 0, stream>>>(x, xb, 1048576);
    cvt_bf16<<<dim3(3072), blk, 0, stream>>>(W_qkv, Wqkvb, 786432);
    cvt_bf16<<<dim3(1024), blk, 0, stream>>>(W_z, Wzb, 262144);

    gemm_bt_bf16<1><<<dim3(CD_ / 128, M / 128), blk, 0, stream>>>(xb, Wqkvb, mixedb, M, CD_, D_);
    gemm_bt_bf16<0><<<dim3(D_ / 128, M / 128), blk, 0, stream>>>(xb, Wzb, z, M, D_, D_);

    conv_silu_tt<<<dim3(B_ * (T_ / TT) * (CD_ / 4) / 256), blk, 0, stream>>>(mixedb, conv_w, qkvb);

    cvt_bf16<<<dim3(1024), blk, 0, stream>>>(W_out, Woutb, 262144);
    proj_bg_partial<<<dim3(1024), blk, 0, stream>>>(x, W_b, W_a, bgpart);
    proj_bg_reduce<<<dim3(512), blk, 0, stream>>>(bgpart, dt_bias, A_log, betab, gb);
    l2norm_qk<<<dim3(2 * M * H_ / 4), blk, 0, stream>>>(qkvb);

    chunk_phase1<<<dim3(B_ * H_ * NC_), blk, 0, stream>>>(qkvb, betab, gb, dST, cum, ac);
    chunk_phase2<<<dim3(B_ * H_ * 4096 / 256), blk, 0, stream>>>(dST, ac);
    chunk_phase3<<<dim3(B_ * H_ * NC_), blk, 0, stream>>>(qkvb, betab, cum, dST, o);

    rmsnorm_gate<<<dim3(M * H_ / 4), blk, 0, stream>>>(o, z, normb);
    gemm_bt_bf16<0><<<dim3(D_ / 128, M / 128), blk, 0, stream>>>(normb, Woutb, out, M, D_, D_);
}

// Round 8
// 170.974 us; speedup vs baseline: 10.2313x; 1.2095x over previous
//
#include <hip/hip_runtime.h>
#include <math.h>

#define B_  2
#define T_  2048
#define D_  1024
#define H_  16
#define HD_ 64
#define CD_ 3072   // 3*D
#define L_  64     // chunk length
#define NC_ 32     // T/L chunks
#define TS  72     // padded LDS stride in shorts (144 B, 16B-aligned rows)
#define TT  8      // conv time-tile

typedef __attribute__((ext_vector_type(8))) short bf16x8;
typedef __attribute__((ext_vector_type(4))) float f32x4;
typedef __attribute__((ext_vector_type(4))) unsigned short u16x4;

__device__ __forceinline__ unsigned short f2bf(float f) {
    unsigned int u = __float_as_uint(f);
    unsigned int r = (u + 0x7fffu + ((u >> 16) & 1u)) >> 16;
    return (unsigned short)r;
}
__device__ __forceinline__ float bf2f(unsigned short u) {
    return __uint_as_float(((unsigned int)u) << 16);
}

// ---------------- fp32 -> bf16 conversion (x4 vectorized) ----------------
__global__ __launch_bounds__(256)
void cvt_bf16(const float* __restrict__ in, unsigned short* __restrict__ out, int n4) {
    int i = blockIdx.x * 256 + threadIdx.x;
    if (i >= n4) return;
    float4 a = ((const float4*)in)[i];
    u16x4 o;
    o.x = f2bf(a.x); o.y = f2bf(a.y); o.z = f2bf(a.z); o.w = f2bf(a.w);
    ((u16x4*)out)[i] = o;
}

// ------- merged qkv+z GEMM: A[4096,1024] x Wcat[4096,1024]^T -------
// cols 0..3071 -> mixedb (bf16, stride 3072); cols 3072..4095 -> z (fp32, stride 1024)
__global__ __launch_bounds__(256)
void gemm_qkvz(const unsigned short* __restrict__ A,
               const unsigned short* __restrict__ Bw,
               unsigned short* __restrict__ mixedb, float* __restrict__ z) {
    const int K = 1024;
    __shared__ short As[128 * 32];
    __shared__ short Bs[128 * 32];
    const int tid = threadIdx.x;
    const int bm = blockIdx.y * 128;
    const int bn = blockIdx.x * 128;
    const int wave = tid >> 6;
    const int lane = tid & 63;
    const int wm = (wave >> 1) * 64;
    const int wn = (wave & 1) * 64;
    const int lr = lane & 15;
    const int lk = lane >> 4;

    f32x4 acc[4][4] = {};

    const int srow = tid >> 2;
    const int scol = (tid & 3) << 3;
    const unsigned short* Ag = A + (size_t)(bm + srow) * K + scol;
    const unsigned short* Bg = Bw + (size_t)(bn + srow) * K + scol;

    short* AsP = As + tid * 8;
    short* BsP = Bs + tid * 8;

    const short* pA = As + (wm + lr) * 32 + lk * 8;
    const short* pB = Bs + (wn + lr) * 32 + lk * 8;

    for (int k0 = 0; k0 < K; k0 += 32) {
        __builtin_amdgcn_global_load_lds(
            (const __attribute__((address_space(1))) void*)(Ag + k0),
            (__attribute__((address_space(3))) void*)AsP, 16, 0, 0);
        __builtin_amdgcn_global_load_lds(
            (const __attribute__((address_space(1))) void*)(Ag + (size_t)64 * K + k0),
            (__attribute__((address_space(3))) void*)(AsP + 2048), 16, 0, 0);
        __builtin_amdgcn_global_load_lds(
            (const __attribute__((address_space(1))) void*)(Bg + k0),
            (__attribute__((address_space(3))) void*)BsP, 16, 0, 0);
        __builtin_amdgcn_global_load_lds(
            (const __attribute__((address_space(1))) void*)(Bg + (size_t)64 * K + k0),
            (__attribute__((address_space(3))) void*)(BsP + 2048), 16, 0, 0);
        __syncthreads();

        bf16x8 a[4], b[4];
#pragma unroll
        for (int mi = 0; mi < 4; ++mi) a[mi] = *(const bf16x8*)(pA + mi * 16 * 32);
#pragma unroll
        for (int ni = 0; ni < 4; ++ni) b[ni] = *(const bf16x8*)(pB + ni * 16 * 32);
#pragma unroll
        for (int mi = 0; mi < 4; ++mi)
#pragma unroll
            for (int ni = 0; ni < 4; ++ni)
                acc[mi][ni] = __builtin_amdgcn_mfma_f32_16x16x32_bf16(
                    a[mi], b[ni], acc[mi][ni], 0, 0, 0);
        __syncthreads();
    }

    const int r0 = lk * 4;
#pragma unroll
    for (int mi = 0; mi < 4; ++mi)
#pragma unroll
        for (int ni = 0; ni < 4; ++ni) {
            int row = bm + wm + mi * 16 + r0;
            int ncol = bn + wn + ni * 16 + lr;
            if (ncol < 3072) {
                unsigned short* cp = mixedb + (size_t)row * 3072 + ncol;
#pragma unroll
                for (int r = 0; r < 4; ++r)
                    cp[(size_t)r * 3072] = f2bf(acc[mi][ni][r]);
            } else {
                float* cp = z + (size_t)row * 1024 + (ncol - 3072);
#pragma unroll
                for (int r = 0; r < 4; ++r)
                    cp[(size_t)r * 1024] = acc[mi][ni][r];
            }
        }
}

// ---------------- bf16 MFMA GEMM NT (fp32 C): final out projection ----------------
__global__ __launch_bounds__(256)
void gemm_bt_bf16(const unsigned short* __restrict__ A,
                  const unsigned short* __restrict__ Bw,
                  float* __restrict__ C, int M, int N, int K) {
    __shared__ short As[128 * 32];
    __shared__ short Bs[128 * 32];
    const int tid = threadIdx.x;
    const int bm = blockIdx.y * 128;
    const int bn = blockIdx.x * 128;
    const int wave = tid >> 6;
    const int lane = tid & 63;
    const int wm = (wave >> 1) * 64;
    const int wn = (wave & 1) * 64;
    const int lr = lane & 15;
    const int lk = lane >> 4;

    f32x4 acc[4][4] = {};

    const int srow = tid >> 2;
    const int scol = (tid & 3) << 3;
    const unsigned short* Ag = A + (size_t)(bm + srow) * K + scol;
    const unsigned short* Bg = Bw + (size_t)(bn + srow) * K + scol;

    short* AsP = As + tid * 8;
    short* BsP = Bs + tid * 8;

    const short* pA = As + (wm + lr) * 32 + lk * 8;
    const short* pB = Bs + (wn + lr) * 32 + lk * 8;

    for (int k0 = 0; k0 < K; k0 += 32) {
        __builtin_amdgcn_global_load_lds(
            (const __attribute__((address_space(1))) void*)(Ag + k0),
            (__attribute__((address_space(3))) void*)AsP, 16, 0, 0);
        __builtin_amdgcn_global_load_lds(
            (const __attribute__((address_space(1))) void*)(Ag + (size_t)64 * K + k0),
            (__attribute__((address_space(3))) void*)(AsP + 2048), 16, 0, 0);
        __builtin_amdgcn_global_load_lds(
            (const __attribute__((address_space(1))) void*)(Bg + k0),
            (__attribute__((address_space(3))) void*)BsP, 16, 0, 0);
        __builtin_amdgcn_global_load_lds(
            (const __attribute__((address_space(1))) void*)(Bg + (size_t)64 * K + k0),
            (__attribute__((address_space(3))) void*)(BsP + 2048), 16, 0, 0);
        __syncthreads();

        bf16x8 a[4], b[4];
#pragma unroll
        for (int mi = 0; mi < 4; ++mi) a[mi] = *(const bf16x8*)(pA + mi * 16 * 32);
#pragma unroll
        for (int ni = 0; ni < 4; ++ni) b[ni] = *(const bf16x8*)(pB + ni * 16 * 32);
#pragma unroll
        for (int mi = 0; mi < 4; ++mi)
#pragma unroll
            for (int ni = 0; ni < 4; ++ni)
                acc[mi][ni] = __builtin_amdgcn_mfma_f32_16x16x32_bf16(
                    a[mi], b[ni], acc[mi][ni], 0, 0, 0);
        __syncthreads();
    }

    const int r0 = lk * 4;
#pragma unroll
    for (int mi = 0; mi < 4; ++mi)
#pragma unroll
        for (int ni = 0; ni < 4; ++ni) {
            float* cp = C + (size_t)(bm + wm + mi * 16 + r0) * N + bn + wn + ni * 16 + lr;
#pragma unroll
            for (int r = 0; r < 4; ++r)
                cp[(size_t)r * N] = acc[mi][ni][r];
        }
}

// ------- beta/g projection, split-K partials (fp32): 128 Mtiles x 8 Kslices -------
#define PJS 129   // padded fp32 LDS stride
__global__ __launch_bounds__(256)
void proj_bg_partial(const float* __restrict__ x, const float* __restrict__ Wb,
                     const float* __restrict__ Wa, float* __restrict__ partial) {
    const int m0 = (blockIdx.x >> 3) * 32;   // M-tile
    const int ks = blockIdx.x & 7;           // K-slice
    const int k0 = ks * 128;
    const int tid = threadIdx.x;
    __shared__ float xs[32 * PJS];
    __shared__ float wsh[32 * PJS];
    const int sr = tid >> 3;                 // 0..31
    const int sc = (tid & 7) << 4;           // 0,16,...,112
    const int mi2 = tid >> 3;
    const int n02 = (tid & 7) << 2;          // 0,4,...,28

    {
        const float* xrow = x + (size_t)(m0 + sr) * D_ + k0 + sc;
        const float* wrow = ((sr < 16) ? (Wb + (size_t)sr * D_) : (Wa + (size_t)(sr - 16) * D_)) + k0 + sc;
#pragma unroll
        for (int j = 0; j < 16; j += 4) {
            float4 a = *(const float4*)(xrow + j);
            float4 b = *(const float4*)(wrow + j);
            xs[sr * PJS + sc + j + 0] = a.x; xs[sr * PJS + sc + j + 1] = a.y;
            xs[sr * PJS + sc + j + 2] = a.z; xs[sr * PJS + sc + j + 3] = a.w;
            wsh[sr * PJS + sc + j + 0] = b.x; wsh[sr * PJS + sc + j + 1] = b.y;
            wsh[sr * PJS + sc + j + 2] = b.z; wsh[sr * PJS + sc + j + 3] = b.w;
        }
    }
    __syncthreads();

    float acc[4] = {0.f, 0.f, 0.f, 0.f};
#pragma unroll 8
    for (int kk = 0; kk < 128; ++kk) {
        float av = xs[mi2 * PJS + kk];
#pragma unroll
        for (int j = 0; j < 4; ++j)
            acc[j] = fmaf(av, wsh[(n02 + j) * PJS + kk], acc[j]);
    }
    float* op = partial + (size_t)ks * (4096 * 32) + (size_t)(m0 + mi2) * 32 + n02;
    *(float4*)op = make_float4(acc[0], acc[1], acc[2], acc[3]);
}

__global__ __launch_bounds__(256)
void proj_bg_reduce(const float* __restrict__ partial, const float* __restrict__ dt_bias,
                    const float* __restrict__ A_log,
                    float* __restrict__ beta, float* __restrict__ g) {
    const int gid = blockIdx.x * 256 + threadIdx.x;   // [0, 4096*32)
    const int m = gid >> 5;
    const int n = gid & 31;
    float s = 0.f;
#pragma unroll
    for (int ks = 0; ks < 8; ++ks)
        s += partial[(size_t)ks * (4096 * 32) + gid];
    if (n < 16) {
        beta[(size_t)m * H_ + n] = 1.f / (1.f + expf(-s));
    } else {
        int h = n - 16;
        float spin = s + dt_bias[h];
        float sp = (spin > 20.f) ? spin : log1pf(expf(spin));
        g[(size_t)m * H_ + h] = -expf(A_log[h]) * sp;
    }
}

// ---- causal depthwise conv (K=4) + SiLU: bf16 in, time-tiled x8, bf16 out ----
__global__ __launch_bounds__(256)
void conv_silu_tt(const unsigned short* __restrict__ mixedb,
                  const float* __restrict__ conv_w,
                  unsigned short* __restrict__ qkvb) {
    int idx = blockIdx.x * 256 + threadIdx.x;   // over B*(T/TT)*(CD/4)
    const int cq = idx % (CD_ / 4);
    const int bt8 = idx / (CD_ / 4);
    const int t0 = (bt8 % (T_ / TT)) * TT;
    const int b = bt8 / (T_ / TT);
    const int c0 = cq << 2;
    const unsigned short* base = mixedb + (size_t)(b * T_ + t0) * CD_ + c0;

    float vals[TT + 3][4];
#pragma unroll
    for (int i = 0; i < TT + 3; ++i) {
        int t = t0 + i - 3;
        if (t >= 0) {
            u16x4 m = *(const u16x4*)(base + (ptrdiff_t)(i - 3) * CD_);
            vals[i][0] = bf2f(m.x); vals[i][1] = bf2f(m.y);
            vals[i][2] = bf2f(m.z); vals[i][3] = bf2f(m.w);
        } else {
            vals[i][0] = vals[i][1] = vals[i][2] = vals[i][3] = 0.f;
        }
    }
    const float4* wp = (const float4*)(conv_w + (size_t)c0 * 4);
    float4 w[4] = {wp[0], wp[1], wp[2], wp[3]};

    unsigned short* outp = qkvb + (size_t)(b * T_ + t0) * CD_ + c0;
#pragma unroll
    for (int tt = 0; tt < TT; ++tt) {
        u16x4 r;
        float s0 = vals[tt + 3][0] * w[0].w + vals[tt + 2][0] * w[0].z
                 + vals[tt + 1][0] * w[0].y + vals[tt + 0][0] * w[0].x;
        float s1 = vals[tt + 3][1] * w[1].w + vals[tt + 2][1] * w[1].z
                 + vals[tt + 1][1] * w[1].y + vals[tt + 0][1] * w[1].x;
        float s2 = vals[tt + 3][2] * w[2].w + vals[tt + 2][2] * w[2].z
                 + vals[tt + 1][2] * w[2].y + vals[tt + 0][2] * w[2].x;
        float s3 = vals[tt + 3][3] * w[3].w + vals[tt + 2][3] * w[3].z
                 + vals[tt + 1][3] * w[3].y + vals[tt + 0][3] * w[3].x;
        r.x = f2bf(s0 / (1.f + expf(-s0)));
        r.y = f2bf(s1 / (1.f + expf(-s1)));
        r.z = f2bf(s2 / (1.f + expf(-s2)));
        r.w = f2bf(s3 / (1.f + expf(-s3)));
        *(u16x4*)(outp + (size_t)tt * CD_) = r;
    }
}

// ------------ phase 1 (MFMA): per-chunk dS^T[v][d], cum, a_c; k-l2norm fused --
__global__ __launch_bounds__(256)
void chunk_phase1(const unsigned short* __restrict__ qkvb,
                  const float* __restrict__ beta, const float* __restrict__ gg,
                  float* __restrict__ dST, float* __restrict__ cum,
                  float* __restrict__ ac) {
    const int cid = blockIdx.x;           // (b*H+h)*NC + c
    const int c = cid & (NC_ - 1);
    const int bh = cid >> 5;
    const int b = bh >> 4, h = bh & 15;
    const int tid = threadIdx.x;
    const int wave = tid >> 6, lane = tid & 63;
    const int t0 = c * L_;

    __shared__ __align__(16) short kT[64 * TS];   // [d][s], RAW k
    __shared__ __align__(16) short vT[64 * TS];   // [v][s], weighted (beta*decay/||k||)
    __shared__ float cumS[64], wS[64];
    __shared__ float ksumP[4][64];                // per-wave k sumsq partials

    const unsigned short* rowp = qkvb + (size_t)(b * T_ + t0 + lane) * CD_ + h * HD_ + wave * 16;
    bf16x8 k0 = *(const bf16x8*)(rowp + D_);
    bf16x8 k1 = *(const bf16x8*)(rowp + D_ + 8);
    bf16x8 v0 = *(const bf16x8*)(rowp + 2 * D_);
    bf16x8 v1 = *(const bf16x8*)(rowp + 2 * D_ + 8);

    {   // partial sum of squares of this wave's 16 k-columns for timestep s=lane
        float ks = 0.f;
#pragma unroll
        for (int j = 0; j < 8; ++j) {
            float a = bf2f((unsigned short)k0[j]); ks = fmaf(a, a, ks);
            float bq = bf2f((unsigned short)k1[j]); ks = fmaf(bq, bq, ks);
        }
        ksumP[wave][lane] = ks;
    }

    if (wave == 0) {   // parallel inclusive scan of g over the 64 timesteps
        float s = gg[(size_t)(b * T_ + t0 + lane) * H_ + h];
#pragma unroll
        for (int off = 1; off < 64; off <<= 1) {
            float up = __shfl_up(s, off, 64);
            if (lane >= off) s += up;
        }
        cumS[lane] = s;
        float cend = __shfl(s, 63, 64);
        wS[lane] = expf(cend - s) * beta[(size_t)(b * T_ + t0 + lane) * H_ + h];
        cum[(size_t)bh * T_ + t0 + lane] = s;
        if (lane == 63) ac[cid] = expf(cend);
    }
    __syncthreads();
    const float kn = rsqrtf(ksumP[0][lane] + ksumP[1][lane] + ksumP[2][lane]
                            + ksumP[3][lane] + 1e-6f);
    const float w = wS[lane] * kn;     // fold 1/||k|| into the v-weight
#pragma unroll
    for (int j = 0; j < 8; ++j) {
        kT[(wave * 16 + j) * TS + lane] = k0[j];
        kT[(wave * 16 + 8 + j) * TS + lane] = k1[j];
        vT[(wave * 16 + j) * TS + lane] = f2bf(bf2f((unsigned short)v0[j]) * w);
        vT[(wave * 16 + 8 + j) * TS + lane] = f2bf(bf2f((unsigned short)v1[j]) * w);
    }
    __syncthreads();

    const int lr = lane & 15, lk = lane >> 4;
    f32x4 acc[4] = {};
    const short* pA = vT + (wave * 16 + lr) * TS + lk * 8;
#pragma unroll
    for (int kk = 0; kk < 2; ++kk) {
        bf16x8 a = *(const bf16x8*)(pA + kk * 32);
#pragma unroll
        for (int n = 0; n < 4; ++n) {
            bf16x8 bfr = *(const bf16x8*)(kT + (n * 16 + lr) * TS + lk * 8 + kk * 32);
            acc[n] = __builtin_amdgcn_mfma_f32_16x16x32_bf16(a, bfr, acc[n], 0, 0, 0);
        }
    }
#pragma unroll
    for (int n = 0; n < 4; ++n) {
        float* op = dST + (size_t)cid * 4096 + (wave * 16 + lk * 4) * 64 + n * 16 + lr;
#pragma unroll
        for (int r = 0; r < 4; ++r)
            op[r * 64] = acc[n][r];
    }
}

// ---------------- phase 2: scan over chunks, IN PLACE (dST -> states) --------
__global__ __launch_bounds__(256)
void chunk_phase2(float* __restrict__ dST, const float* __restrict__ ac) {
    const int gid = blockIdx.x * 256 + threadIdx.x;  // B*H*4096 = 131072
    const int bh = gid >> 12;
    const int e = gid & 4095;
    float s = 0.f;
    for (int c = 0; c < NC_; ++c) {
        size_t off = (size_t)(bh * NC_ + c) * 4096 + e;
        float tmp = dST[off];
        dST[off] = s;
        s = fmaf(ac[bh * NC_ + c], s, tmp);
    }
}

// -- phase 3 (MFMA): O = exp(ct)*Q*S_in + P*V; q/k-l2norm + gated-RMSNorm fused --
__global__ __launch_bounds__(256)
void chunk_phase3(const unsigned short* __restrict__ qkvb,
                  const float* __restrict__ beta, const float* __restrict__ cum,
                  const float* __restrict__ states,   // dST layout [cid][v][d] fp32
                  const float* __restrict__ z,
                  unsigned short* __restrict__ normb) {
    const int cid = blockIdx.x;
    const int c = cid & (NC_ - 1);
    const int bh = cid >> 5;
    const int b = bh >> 4, h = bh & 15;
    const int tid = threadIdx.x;
    const int wave = tid >> 6, lane = tid & 63;
    const int t0 = c * L_;

    __shared__ __align__(16) short vT[64 * TS];   // [v][s]
    __shared__ __align__(16) short sT[64 * TS];   // S_in^T bf16 [v][d]
    __shared__ __align__(16) short pS[64 * TS];   // P [t][s] bf16
    __shared__ float cumS[64], betaS[64];
    __shared__ float invq[64], invk[64];

    {   // stage vT (transpose)
        const unsigned short* rowp = qkvb + (size_t)(b * T_ + t0 + lane) * CD_ + 2 * D_ + h * HD_ + wave * 16;
        bf16x8 v0 = *(const bf16x8*)rowp;
        bf16x8 v1 = *(const bf16x8*)(rowp + 8);
#pragma unroll
        for (int j = 0; j < 8; ++j) {
            vT[(wave * 16 + j) * TS + lane] = v0[j];
            vT[(wave * 16 + 8 + j) * TS + lane] = v1[j];
        }
    }
    {   // stage sT (fp32 -> bf16)
        const float* sp = states + (size_t)cid * 4096 + (tid >> 2) * 64 + (tid & 3) * 16;
        short* dp = sT + (tid >> 2) * TS + (tid & 3) * 16;
#pragma unroll
        for (int j = 0; j < 16; j += 4) {
            float4 f = *(const float4*)(sp + j);
            dp[j] = f2bf(f.x); dp[j + 1] = f2bf(f.y);
            dp[j + 2] = f2bf(f.z); dp[j + 3] = f2bf(f.w);
        }
    }
    {   // per-row l2norm factors for q and k (4 threads per row)
        int row = tid >> 2;
        int seg = (tid & 3) << 4;   // 0,16,32,48
        const unsigned short* qr = qkvb + (size_t)(b * T_ + t0 + row) * CD_ + h * HD_ + seg;
        bf16x8 a0 = *(const bf16x8*)qr;
        bf16x8 a1 = *(const bf16x8*)(qr + 8);
        float sq = 0.f;
#pragma unroll
        for (int j = 0; j < 8; ++j) {
            float v = bf2f((unsigned short)a0[j]); sq = fmaf(v, v, sq);
            v = bf2f((unsigned short)a1[j]); sq = fmaf(v, v, sq);
        }
        sq += __shfl_xor(sq, 1, 64);
        sq += __shfl_xor(sq, 2, 64);
        const unsigned short* kr = qr + D_;
        bf16x8 b0 = *(const bf16x8*)kr;
        bf16x8 b1 = *(const bf16x8*)(kr + 8);
        float sk = 0.f;
#pragma unroll
        for (int j = 0; j < 8; ++j) {
            float v = bf2f((unsigned short)b0[j]); sk = fmaf(v, v, sk);
            v = bf2f((unsigned short)b1[j]); sk = fmaf(v, v, sk);
        }
        sk += __shfl_xor(sk, 1, 64);
        sk += __shfl_xor(sk, 2, 64);
        if ((tid & 3) == 0) {
            invq[row] = 0.125f * rsqrtf(sq + 1e-6f);   // includes HD^-0.5
            invk[row] = rsqrtf(sk + 1e-6f);
        }
    }
    if (tid < 64) {
        cumS[tid] = cum[(size_t)bh * T_ + t0 + tid];
        betaS[tid] = beta[(size_t)(b * T_ + t0 + tid) * H_ + h];
    }
    __syncthreads();

    const int lr = lane & 15, lk = lane >> 4;
    const unsigned short* qrow = qkvb + (size_t)(b * T_ + t0 + wave * 16 + lr) * CD_ + h * HD_;
    bf16x8 qf0 = *(const bf16x8*)(qrow + lk * 8);
    bf16x8 qf1 = *(const bf16x8*)(qrow + 32 + lk * 8);

    // QK^T on RAW q,k
    f32x4 pacc[4] = {};
#pragma unroll
    for (int n = 0; n < 4; ++n) {
        const unsigned short* krow = qkvb + (size_t)(b * T_ + t0 + n * 16 + lr) * CD_ + D_ + h * HD_;
        bf16x8 b0 = *(const bf16x8*)(krow + lk * 8);
        bf16x8 b1 = *(const bf16x8*)(krow + 32 + lk * 8);
        pacc[n] = __builtin_amdgcn_mfma_f32_16x16x32_bf16(qf0, b0, pacc[n], 0, 0, 0);
        pacc[n] = __builtin_amdgcn_mfma_f32_16x16x32_bf16(qf1, b1, pacc[n], 0, 0, 0);
    }
    // decay + mask + beta + norms -> pS (bf16)
#pragma unroll
    for (int n = 0; n < 4; ++n) {
        int s = n * 16 + lr;
        float cs = cumS[s], bsk = betaS[s] * invk[s];
#pragma unroll
        for (int r = 0; r < 4; ++r) {
            int t = wave * 16 + lk * 4 + r;
            float pv = (s <= t) ? expf(cumS[t] - cs) * bsk * pacc[n][r] * invq[t] : 0.f;
            pS[t * TS + s] = f2bf(pv);
        }
    }
    __syncthreads();

    // O = Q * S_in^T-frags (raw q, scaled after)
    f32x4 oacc[4] = {};
#pragma unroll
    for (int n = 0; n < 4; ++n) {
        const short* srow = sT + (n * 16 + lr) * TS + lk * 8;
        bf16x8 b0 = *(const bf16x8*)srow;
        bf16x8 b1 = *(const bf16x8*)(srow + 32);
        oacc[n] = __builtin_amdgcn_mfma_f32_16x16x32_bf16(qf0, b0, oacc[n], 0, 0, 0);
        oacc[n] = __builtin_amdgcn_mfma_f32_16x16x32_bf16(qf1, b1, oacc[n], 0, 0, 0);
    }
    float qsc[4];
#pragma unroll
    for (int r = 0; r < 4; ++r) {
        int t = wave * 16 + lk * 4 + r;
        qsc[r] = expf(cumS[t]) * invq[t];
    }
#pragma unroll
    for (int n = 0; n < 4; ++n)
#pragma unroll
        for (int r = 0; r < 4; ++r) oacc[n][r] *= qsc[r];
    // + P * V
    const short* prow = pS + (wave * 16 + lr) * TS + lk * 8;
    bf16x8 pf0 = *(const bf16x8*)prow;
    bf16x8 pf1 = *(const bf16x8*)(prow + 32);
#pragma unroll
    for (int n = 0; n < 4; ++n) {
        const short* vrow = vT + (n * 16 + lr) * TS + lk * 8;
        bf16x8 b0 = *(const bf16x8*)vrow;
        bf16x8 b1 = *(const bf16x8*)(vrow + 32);
        oacc[n] = __builtin_amdgcn_mfma_f32_16x16x32_bf16(pf0, b0, oacc[n], 0, 0, 0);
        oacc[n] = __builtin_amdgcn_mfma_f32_16x16x32_bf16(pf1, b1, oacc[n], 0, 0, 0);
    }

    // fused gated RMSNorm over head dim + bf16 store
#pragma unroll
    for (int r = 0; r < 4; ++r) {
        int t = wave * 16 + lk * 4 + r;
        float ss = 0.f;
#pragma unroll
        for (int n = 0; n < 4; ++n) ss = fmaf(oacc[n][r], oacc[n][r], ss);
        ss += __shfl_xor(ss, 1, 64);
        ss += __shfl_xor(ss, 2, 64);
        ss += __shfl_xor(ss, 4, 64);
        ss += __shfl_xor(ss, 8, 64);
        float inv = rsqrtf(ss * (1.f / 64.f) + 1e-6f);
        size_t rowoff = (size_t)(b * T_ + t0 + t) * D_ + h * HD_;
#pragma unroll
        for (int n = 0; n < 4; ++n) {
            float zv = z[rowoff + n * 16 + lr];
            float sz = zv / (1.f + expf(-zv));
            normb[rowoff + n * 16 + lr] = f2bf(oacc[n][r] * inv * sz);
        }
    }
}

extern "C" void kernel_launch(void* const* d_in, const int* in_sizes, int n_in,
                              void* d_out, int out_size, void* d_ws, size_t ws_size,
                              hipStream_t stream) {
    const float* x       = (const float*)d_in[0];
    const float* W_qkv   = (const float*)d_in[1];
    const float* conv_w  = (const float*)d_in[2];
    const float* W_z     = (const float*)d_in[3];
    const float* W_b     = (const float*)d_in[4];
    const float* W_a     = (const float*)d_in[5];
    const float* dt_bias = (const float*)d_in[6];
    const float* A_log   = (const float*)d_in[7];
    const float* W_out   = (const float*)d_in[8];
    float* out = (float*)d_out;

    float* ws = (float*)d_ws;
    // Region A [0, 6291456 floats): mixedb (bf16) until conv; overlays after:
    unsigned short* mixedb = (unsigned short*)ws;              // 12.6M bf16 (25 MB)
    float* dST    = ws;                        // 4M floats (ph1 -> ph2 in-place -> ph3)
    unsigned short* normb = (unsigned short*)(ws + 4194304);   // 4.2M bf16 (ph3 output)
    float* betab  = ws + 8388608;              // 65,536
    float* gb     = ws + 8454144;              // 65,536
    float* cum    = ws + 8519680;              // 65,536
    float* ac     = ws + 8585216;              // 1,024
    unsigned short* Woutb = (unsigned short*)(ws + 8586240);   // 1M bf16
    // Region B [12582912, 18874368): xb/Wqkvb/Wzb pre-conv; qkvb after
    unsigned short* xb    = (unsigned short*)(ws + 12582912);  // 4M bf16
    unsigned short* Wqkvb = (unsigned short*)(ws + 14680064);  // 3M bf16 (cat head)
    unsigned short* Wzb   = (unsigned short*)(ws + 16252928);  // 1M bf16 (cat tail)
    unsigned short* qkvb  = (unsigned short*)(ws + 12582912);  // 12.6M bf16
    // Region C
    float* z      = ws + 18874368;             // 4M floats
    float* bgpart = ws + 23068672;             // 1M floats (4 MB)

    const int M = B_ * T_;                     // 4096
    dim3 blk(256);

    cvt_bf16<<<dim3(4096), blk, 0, stream>>>(x, xb, 1048576);
    cvt_bf16<<<dim3(3072), blk, 0, stream>>>(W_qkv, Wqkvb, 786432);
    cvt_bf16<<<dim3(1024), blk, 0, stream>>>(W_z, Wzb, 262144);   // contiguous after Wqkvb

    gemm_qkvz<<<dim3(32, 32), blk, 0, stream>>>(xb, Wqkvb, mixedb, z);

    conv_silu_tt<<<dim3(B_ * (T_ / TT) * (CD_ / 4) / 256), blk, 0, stream>>>(mixedb, conv_w, qkvb);

    cvt_bf16<<<dim3(1024), blk, 0, stream>>>(W_out, Woutb, 262144);
    proj_bg_partial<<<dim3(1024), blk, 0, stream>>>(x, W_b, W_a, bgpart);
    proj_bg_reduce<<<dim3(512), blk, 0, stream>>>(bgpart, dt_bias, A_log, betab, gb);

    chunk_phase1<<<dim3(B_ * H_ * NC_), blk, 0, stream>>>(qkvb, betab, gb, dST, cum, ac);
    chunk_phase2<<<dim3(B_ * H_ * 4096 / 256), blk, 0, stream>>>(dST, ac);
    chunk_phase3<<<dim3(B_ * H_ * NC_), blk, 0, stream>>>(qkvb, betab, cum, dST, z, normb);

    gemm_bt_bf16<<<dim3(D_ / 128, M / 128), blk, 0, stream>>>(normb, Woutb, out, M, D_, D_);
}

// Round 10
// 165.812 us; speedup vs baseline: 10.5498x; 1.0311x over previous
//
#include <hip/hip_runtime.h>
#include <math.h>

#define B_  2
#define T_  2048
#define D_  1024
#define H_  16
#define HD_ 64
#define CD_ 3072   // 3*D
#define L_  64     // chunk length
#define NC_ 32     // T/L chunks
#define TS  72     // padded LDS stride in shorts (144 B, 16B-aligned rows)
#define TT  8      // conv time-tile

typedef __attribute__((ext_vector_type(8))) short bf16x8;
typedef __attribute__((ext_vector_type(4))) float f32x4;
typedef __attribute__((ext_vector_type(4))) unsigned short u16x4;

__device__ __forceinline__ unsigned short f2bf(float f) {
    unsigned int u = __float_as_uint(f);
    unsigned int r = (u + 0x7fffu + ((u >> 16) & 1u)) >> 16;
    return (unsigned short)r;
}
__device__ __forceinline__ float bf2f(unsigned short u) {
    return __uint_as_float(((unsigned int)u) << 16);
}

// ------- one-shot fp32 -> bf16 conversion of x, W_qkv, W_z, W_out -------
// float4 ranges: x 1048576 | W_qkv 786432 | W_z 262144 | W_out 262144 -> 2359296
__global__ __launch_bounds__(256)
void cvt_all(const float* __restrict__ x, const float* __restrict__ Wqkv,
             const float* __restrict__ Wz, const float* __restrict__ Wout,
             unsigned short* __restrict__ xb, unsigned short* __restrict__ Wqkvb,
             unsigned short* __restrict__ Wzb, unsigned short* __restrict__ Woutb) {
    int i = blockIdx.x * 256 + threadIdx.x;   // [0, 2359296)
    const float* src; unsigned short* dst; int li;
    if (i < 1048576)      { src = x;    dst = xb;    li = i; }
    else if (i < 1835008) { src = Wqkv; dst = Wqkvb; li = i - 1048576; }
    else if (i < 2097152) { src = Wz;   dst = Wzb;   li = i - 1835008; }
    else                  { src = Wout; dst = Woutb; li = i - 2097152; }
    float4 a = ((const float4*)src)[li];
    u16x4 o;
    o.x = f2bf(a.x); o.y = f2bf(a.y); o.z = f2bf(a.z); o.w = f2bf(a.w);
    ((u16x4*)dst)[li] = o;
}

// ------- merged qkv+z GEMM: A[4096,1024] x Wcat[4096,1024]^T -------
// 1D grid 1024, XCD-swizzled; LDS double-buffered (stage k+1 before compute k).
// cols 0..3071 -> mixedb (bf16, stride 3072); cols 3072..4095 -> z (fp32, stride 1024)
__global__ __launch_bounds__(256)
void gemm_qkvz(const unsigned short* __restrict__ A,
               const unsigned short* __restrict__ Bw,
               unsigned short* __restrict__ mixedb, float* __restrict__ z) {
    const int K = 1024;
    __shared__ short As[2][128 * 32];
    __shared__ short Bs[2][128 * 32];
    const int tid = threadIdx.x;
    // bijective XCD swizzle: 1024 blocks, 8 XCDs, 128 contiguous wgids per XCD
    const int wgid = (blockIdx.x & 7) * 128 + (blockIdx.x >> 3);
    const int bm = (wgid >> 5) * 128;
    const int bn = (wgid & 31) * 128;
    const int wave = tid >> 6;
    const int lane = tid & 63;
    const int wm = (wave >> 1) * 64;
    const int wn = (wave & 1) * 64;
    const int lr = lane & 15;
    const int lk = lane >> 4;

    f32x4 acc[4][4] = {};

    const int srow = tid >> 2;
    const int scol = (tid & 3) << 3;
    const unsigned short* Ag = A + (size_t)(bm + srow) * K + scol;
    const unsigned short* Bg = Bw + (size_t)(bn + srow) * K + scol;

#define STAGE_Q(buf, k0)                                                          \
    do {                                                                          \
        __builtin_amdgcn_global_load_lds(                                         \
            (const __attribute__((address_space(1))) void*)(Ag + (k0)),           \
            (__attribute__((address_space(3))) void*)(&As[buf][tid * 8]), 16, 0, 0); \
        __builtin_amdgcn_global_load_lds(                                         \
            (const __attribute__((address_space(1))) void*)(Ag + (size_t)64 * K + (k0)), \
            (__attribute__((address_space(3))) void*)(&As[buf][tid * 8 + 2048]), 16, 0, 0); \
        __builtin_amdgcn_global_load_lds(                                         \
            (const __attribute__((address_space(1))) void*)(Bg + (k0)),           \
            (__attribute__((address_space(3))) void*)(&Bs[buf][tid * 8]), 16, 0, 0); \
        __builtin_amdgcn_global_load_lds(                                         \
            (const __attribute__((address_space(1))) void*)(Bg + (size_t)64 * K + (k0)), \
            (__attribute__((address_space(3))) void*)(&Bs[buf][tid * 8 + 2048]), 16, 0, 0); \
    } while (0)

#define COMPUTE_Q(buf)                                                            \
    do {                                                                          \
        const short* pA = &As[buf][(wm + lr) * 32 + lk * 8];                      \
        const short* pB = &Bs[buf][(wn + lr) * 32 + lk * 8];                      \
        bf16x8 a[4], b[4];                                                        \
        _Pragma("unroll")                                                         \
        for (int mi = 0; mi < 4; ++mi) a[mi] = *(const bf16x8*)(pA + mi * 16 * 32); \
        _Pragma("unroll")                                                         \
        for (int ni = 0; ni < 4; ++ni) b[ni] = *(const bf16x8*)(pB + ni * 16 * 32); \
        _Pragma("unroll")                                                         \
        for (int mi = 0; mi < 4; ++mi)                                            \
            _Pragma("unroll")                                                     \
            for (int ni = 0; ni < 4; ++ni)                                        \
                acc[mi][ni] = __builtin_amdgcn_mfma_f32_16x16x32_bf16(            \
                    a[mi], b[ni], acc[mi][ni], 0, 0, 0);                          \
    } while (0)

    STAGE_Q(0, 0);
    __syncthreads();
    int cur = 0;
    for (int it = 0; it < 31; ++it) {
        STAGE_Q(cur ^ 1, (it + 1) * 32);   // issue next tile's loads
        COMPUTE_Q(cur);                    // compute under the loads' latency
        __syncthreads();                   // drains vmcnt + lds; both bufs settled
        cur ^= 1;
    }
    COMPUTE_Q(cur);

    const int r0 = lk * 4;
#pragma unroll
    for (int mi = 0; mi < 4; ++mi)
#pragma unroll
        for (int ni = 0; ni < 4; ++ni) {
            int row = bm + wm + mi * 16 + r0;
            int ncol = bn + wn + ni * 16 + lr;
            if (ncol < 3072) {
                unsigned short* cp = mixedb + (size_t)row * 3072 + ncol;
#pragma unroll
                for (int r = 0; r < 4; ++r)
                    cp[(size_t)r * 3072] = f2bf(acc[mi][ni][r]);
            } else {
                float* cp = z + (size_t)row * 1024 + (ncol - 3072);
#pragma unroll
                for (int r = 0; r < 4; ++r)
                    cp[(size_t)r * 1024] = acc[mi][ni][r];
            }
        }
}

// ------- final out-projection GEMM: [4096,1024]x[1024,1024]^T, fp32 C -------
// 1D grid 256, XCD-swizzled, double-buffered.
__global__ __launch_bounds__(256)
void gemm_out(const unsigned short* __restrict__ A,
              const unsigned short* __restrict__ Bw,
              float* __restrict__ C) {
    const int K = 1024, N = 1024;
    __shared__ short As[2][128 * 32];
    __shared__ short Bs[2][128 * 32];
    const int tid = threadIdx.x;
    // 256 blocks, 32 contiguous wgids per XCD
    const int wgid = (blockIdx.x & 7) * 32 + (blockIdx.x >> 3);
    const int bm = (wgid >> 3) * 128;
    const int bn = (wgid & 7) * 128;
    const int wave = tid >> 6;
    const int lane = tid & 63;
    const int wm = (wave >> 1) * 64;
    const int wn = (wave & 1) * 64;
    const int lr = lane & 15;
    const int lk = lane >> 4;

    f32x4 acc[4][4] = {};

    const int srow = tid >> 2;
    const int scol = (tid & 3) << 3;
    const unsigned short* Ag = A + (size_t)(bm + srow) * K + scol;
    const unsigned short* Bg = Bw + (size_t)(bn + srow) * K + scol;

    STAGE_Q(0, 0);
    __syncthreads();
    int cur = 0;
    for (int it = 0; it < 31; ++it) {
        STAGE_Q(cur ^ 1, (it + 1) * 32);
        COMPUTE_Q(cur);
        __syncthreads();
        cur ^= 1;
    }
    COMPUTE_Q(cur);

    const int r0 = lk * 4;
#pragma unroll
    for (int mi = 0; mi < 4; ++mi)
#pragma unroll
        for (int ni = 0; ni < 4; ++ni) {
            float* cp = C + (size_t)(bm + wm + mi * 16 + r0) * N + bn + wn + ni * 16 + lr;
#pragma unroll
            for (int r = 0; r < 4; ++r)
                cp[(size_t)r * N] = acc[mi][ni][r];
        }
}

// ------- beta/g projection, split-K partials (fp32): 128 Mtiles x 8 Kslices -------
#define PJS 129   // padded fp32 LDS stride
__global__ __launch_bounds__(256)
void proj_bg_partial(const float* __restrict__ x, const float* __restrict__ Wb,
                     const float* __restrict__ Wa, float* __restrict__ partial) {
    const int m0 = (blockIdx.x >> 3) * 32;   // M-tile
    const int ks = blockIdx.x & 7;           // K-slice
    const int k0 = ks * 128;
    const int tid = threadIdx.x;
    __shared__ float xs[32 * PJS];
    __shared__ float wsh[32 * PJS];
    const int sr = tid >> 3;                 // 0..31
    const int sc = (tid & 7) << 4;           // 0,16,...,112
    const int mi2 = tid >> 3;
    const int n02 = (tid & 7) << 2;          // 0,4,...,28

    {
        const float* xrow = x + (size_t)(m0 + sr) * D_ + k0 + sc;
        const float* wrow = ((sr < 16) ? (Wb + (size_t)sr * D_) : (Wa + (size_t)(sr - 16) * D_)) + k0 + sc;
#pragma unroll
        for (int j = 0; j < 16; j += 4) {
            float4 a = *(const float4*)(xrow + j);
            float4 b = *(const float4*)(wrow + j);
            xs[sr * PJS + sc + j + 0] = a.x; xs[sr * PJS + sc + j + 1] = a.y;
            xs[sr * PJS + sc + j + 2] = a.z; xs[sr * PJS + sc + j + 3] = a.w;
            wsh[sr * PJS + sc + j + 0] = b.x; wsh[sr * PJS + sc + j + 1] = b.y;
            wsh[sr * PJS + sc + j + 2] = b.z; wsh[sr * PJS + sc + j + 3] = b.w;
        }
    }
    __syncthreads();

    float acc[4] = {0.f, 0.f, 0.f, 0.f};
#pragma unroll 8
    for (int kk = 0; kk < 128; ++kk) {
        float av = xs[mi2 * PJS + kk];
#pragma unroll
        for (int j = 0; j < 4; ++j)
            acc[j] = fmaf(av, wsh[(n02 + j) * PJS + kk], acc[j]);
    }
    float* op = partial + (size_t)ks * (4096 * 32) + (size_t)(m0 + mi2) * 32 + n02;
    *(float4*)op = make_float4(acc[0], acc[1], acc[2], acc[3]);
}

__global__ __launch_bounds__(256)
void proj_bg_reduce(const float* __restrict__ partial, const float* __restrict__ dt_bias,
                    const float* __restrict__ A_log,
                    float* __restrict__ beta, float* __restrict__ g) {
    const int gid = blockIdx.x * 256 + threadIdx.x;   // [0, 4096*32)
    const int m = gid >> 5;
    const int n = gid & 31;
    float s = 0.f;
#pragma unroll
    for (int ks = 0; ks < 8; ++ks)
        s += partial[(size_t)ks * (4096 * 32) + gid];
    if (n < 16) {
        beta[(size_t)m * H_ + n] = 1.f / (1.f + expf(-s));
    } else {
        int h = n - 16;
        float spin = s + dt_bias[h];
        float sp = (spin > 20.f) ? spin : log1pf(expf(spin));
        g[(size_t)m * H_ + h] = -expf(A_log[h]) * sp;
    }
}

// ---- causal depthwise conv (K=4) + SiLU: bf16 in, time-tiled x8, bf16 out ----
__global__ __launch_bounds__(256)
void conv_silu_tt(const unsigned short* __restrict__ mixedb,
                  const float* __restrict__ conv_w,
                  unsigned short* __restrict__ qkvb) {
    int idx = blockIdx.x * 256 + threadIdx.x;   // over B*(T/TT)*(CD/4)
    const int cq = idx % (CD_ / 4);
    const int bt8 = idx / (CD_ / 4);
    const int t0 = (bt8 % (T_ / TT)) * TT;
    const int b = bt8 / (T_ / TT);
    const int c0 = cq << 2;
    const unsigned short* base = mixedb + (size_t)(b * T_ + t0) * CD_ + c0;

    float vals[TT + 3][4];
#pragma unroll
    for (int i = 0; i < TT + 3; ++i) {
        int t = t0 + i - 3;
        if (t >= 0) {
            u16x4 m = *(const u16x4*)(base + (ptrdiff_t)(i - 3) * CD_);
            vals[i][0] = bf2f(m.x); vals[i][1] = bf2f(m.y);
            vals[i][2] = bf2f(m.z); vals[i][3] = bf2f(m.w);
        } else {
            vals[i][0] = vals[i][1] = vals[i][2] = vals[i][3] = 0.f;
        }
    }
    const float4* wp = (const float4*)(conv_w + (size_t)c0 * 4);
    float4 w[4] = {wp[0], wp[1], wp[2], wp[3]};

    unsigned short* outp = qkvb + (size_t)(b * T_ + t0) * CD_ + c0;
#pragma unroll
    for (int tt = 0; tt < TT; ++tt) {
        u16x4 r;
        float s0 = vals[tt + 3][0] * w[0].w + vals[tt + 2][0] * w[0].z
                 + vals[tt + 1][0] * w[0].y + vals[tt + 0][0] * w[0].x;
        float s1 = vals[tt + 3][1] * w[1].w + vals[tt + 2][1] * w[1].z
                 + vals[tt + 1][1] * w[1].y + vals[tt + 0][1] * w[1].x;
        float s2 = vals[tt + 3][2] * w[2].w + vals[tt + 2][2] * w[2].z
                 + vals[tt + 1][2] * w[2].y + vals[tt + 0][2] * w[2].x;
        float s3 = vals[tt + 3][3] * w[3].w + vals[tt + 2][3] * w[3].z
                 + vals[tt + 1][3] * w[3].y + vals[tt + 0][3] * w[3].x;
        r.x = f2bf(s0 / (1.f + expf(-s0)));
        r.y = f2bf(s1 / (1.f + expf(-s1)));
        r.z = f2bf(s2 / (1.f + expf(-s2)));
        r.w = f2bf(s3 / (1.f + expf(-s3)));
        *(u16x4*)(outp + (size_t)tt * CD_) = r;
    }
}

// ------------ phase 1 (MFMA): per-chunk dS^T[v][d], cum, a_c; k-l2norm fused --
__global__ __launch_bounds__(256)
void chunk_phase1(const unsigned short* __restrict__ qkvb,
                  const float* __restrict__ beta, const float* __restrict__ gg,
                  float* __restrict__ dST, float* __restrict__ cum,
                  float* __restrict__ ac) {
    const int cid = blockIdx.x;           // (b*H+h)*NC + c
    const int c = cid & (NC_ - 1);
    const int bh = cid >> 5;
    const int b = bh >> 4, h = bh & 15;
    const int tid = threadIdx.x;
    const int wave = tid >> 6, lane = tid & 63;
    const int t0 = c * L_;

    __shared__ __align__(16) short kT[64 * TS];   // [d][s], RAW k
    __shared__ __align__(16) short vT[64 * TS];   // [v][s], weighted (beta*decay/||k||)
    __shared__ float cumS[64], wS[64];
    __shared__ float ksumP[4][64];                // per-wave k sumsq partials

    const unsigned short* rowp = qkvb + (size_t)(b * T_ + t0 + lane) * CD_ + h * HD_ + wave * 16;
    bf16x8 k0 = *(const bf16x8*)(rowp + D_);
    bf16x8 k1 = *(const bf16x8*)(rowp + D_ + 8);
    bf16x8 v0 = *(const bf16x8*)(rowp + 2 * D_);
    bf16x8 v1 = *(const bf16x8*)(rowp + 2 * D_ + 8);

    {   // partial sum of squares of this wave's 16 k-columns for timestep s=lane
        float ks = 0.f;
#pragma unroll
        for (int j = 0; j < 8; ++j) {
            float a = bf2f((unsigned short)k0[j]); ks = fmaf(a, a, ks);
            float bq = bf2f((unsigned short)k1[j]); ks = fmaf(bq, bq, ks);
        }
        ksumP[wave][lane] = ks;
    }

    if (wave == 0) {   // parallel inclusive scan of g over the 64 timesteps
        float s = gg[(size_t)(b * T_ + t0 + lane) * H_ + h];
#pragma unroll
        for (int off = 1; off < 64; off <<= 1) {
            float up = __shfl_up(s, off, 64);
            if (lane >= off) s += up;
        }
        cumS[lane] = s;
        float cend = __shfl(s, 63, 64);
        wS[lane] = expf(cend - s) * beta[(size_t)(b * T_ + t0 + lane) * H_ + h];
        cum[(size_t)bh * T_ + t0 + lane] = s;
        if (lane == 63) ac[cid] = expf(cend);
    }
    __syncthreads();
    const float kn = rsqrtf(ksumP[0][lane] + ksumP[1][lane] + ksumP[2][lane]
                            + ksumP[3][lane] + 1e-6f);
    const float w = wS[lane] * kn;     // fold 1/||k|| into the v-weight
#pragma unroll
    for (int j = 0; j < 8; ++j) {
        kT[(wave * 16 + j) * TS + lane] = k0[j];
        kT[(wave * 16 + 8 + j) * TS + lane] = k1[j];
        vT[(wave * 16 + j) * TS + lane] = f2bf(bf2f((unsigned short)v0[j]) * w);
        vT[(wave * 16 + 8 + j) * TS + lane] = f2bf(bf2f((unsigned short)v1[j]) * w);
    }
    __syncthreads();

    const int lr = lane & 15, lk = lane >> 4;
    f32x4 acc[4] = {};
    const short* pA = vT + (wave * 16 + lr) * TS + lk * 8;
#pragma unroll
    for (int kk = 0; kk < 2; ++kk) {
        bf16x8 a = *(const bf16x8*)(pA + kk * 32);
#pragma unroll
        for (int n = 0; n < 4; ++n) {
            bf16x8 bfr = *(const bf16x8*)(kT + (n * 16 + lr) * TS + lk * 8 + kk * 32);
            acc[n] = __builtin_amdgcn_mfma_f32_16x16x32_bf16(a, bfr, acc[n], 0, 0, 0);
        }
    }
#pragma unroll
    for (int n = 0; n < 4; ++n) {
        float* op = dST + (size_t)cid * 4096 + (wave * 16 + lk * 4) * 64 + n * 16 + lr;
#pragma unroll
        for (int r = 0; r < 4; ++r)
            op[r * 64] = acc[n][r];
    }
}

// ---------------- phase 2: scan over chunks, IN PLACE (dST -> states) --------
__global__ __launch_bounds__(256)
void chunk_phase2(float* __restrict__ dST, const float* __restrict__ ac) {
    const int gid = blockIdx.x * 256 + threadIdx.x;  // B*H*4096 = 131072
    const int bh = gid >> 12;
    const int e = gid & 4095;
    float s = 0.f;
    for (int c = 0; c < NC_; ++c) {
        size_t off = (size_t)(bh * NC_ + c) * 4096 + e;
        float tmp = dST[off];
        dST[off] = s;
        s = fmaf(ac[bh * NC_ + c], s, tmp);
    }
}

// -- phase 3 (MFMA): O = exp(ct)*Q*S_in + P*V; q/k-l2norm + gated-RMSNorm fused --
__global__ __launch_bounds__(256)
void chunk_phase3(const unsigned short* __restrict__ qkvb,
                  const float* __restrict__ beta, const float* __restrict__ cum,
                  const float* __restrict__ states,   // dST layout [cid][v][d] fp32
                  const float* __restrict__ z,
                  unsigned short* __restrict__ normb) {
    const int cid = blockIdx.x;
    const int c = cid & (NC_ - 1);
    const int bh = cid >> 5;
    const int b = bh >> 4, h = bh & 15;
    const int tid = threadIdx.x;
    const int wave = tid >> 6, lane = tid & 63;
    const int t0 = c * L_;

    __shared__ __align__(16) short vT[64 * TS];   // [v][s]
    __shared__ __align__(16) short sT[64 * TS];   // S_in^T bf16 [v][d]
    __shared__ __align__(16) short pS[64 * TS];   // P [t][s] bf16
    __shared__ float cumS[64], betaS[64];
    __shared__ float invq[64], invk[64];

    {   // stage vT (transpose)
        const unsigned short* rowp = qkvb + (size_t)(b * T_ + t0 + lane) * CD_ + 2 * D_ + h * HD_ + wave * 16;
        bf16x8 v0 = *(const bf16x8*)rowp;
        bf16x8 v1 = *(const bf16x8*)(rowp + 8);
#pragma unroll
        for (int j = 0; j < 8; ++j) {
            vT[(wave * 16 + j) * TS + lane] = v0[j];
            vT[(wave * 16 + 8 + j) * TS + lane] = v1[j];
        }
    }
    {   // stage sT (fp32 -> bf16)
        const float* sp = states + (size_t)cid * 4096 + (tid >> 2) * 64 + (tid & 3) * 16;
        short* dp = sT + (tid >> 2) * TS + (tid & 3) * 16;
#pragma unroll
        for (int j = 0; j < 16; j += 4) {
            float4 f = *(const float4*)(sp + j);
            dp[j] = f2bf(f.x); dp[j + 1] = f2bf(f.y);
            dp[j + 2] = f2bf(f.z); dp[j + 3] = f2bf(f.w);
        }
    }
    {   // per-row l2norm factors for q and k (4 threads per row)
        int row = tid >> 2;
        int seg = (tid & 3) << 4;   // 0,16,32,48
        const unsigned short* qr = qkvb + (size_t)(b * T_ + t0 + row) * CD_ + h * HD_ + seg;
        bf16x8 a0 = *(const bf16x8*)qr;
        bf16x8 a1 = *(const bf16x8*)(qr + 8);
        float sq = 0.f;
#pragma unroll
        for (int j = 0; j < 8; ++j) {
            float v = bf2f((unsigned short)a0[j]); sq = fmaf(v, v, sq);
            v = bf2f((unsigned short)a1[j]); sq = fmaf(v, v, sq);
        }
        sq += __shfl_xor(sq, 1, 64);
        sq += __shfl_xor(sq, 2, 64);
        const unsigned short* kr = qr + D_;
        bf16x8 b0 = *(const bf16x8*)kr;
        bf16x8 b1 = *(const bf16x8*)(kr + 8);
        float sk = 0.f;
#pragma unroll
        for (int j = 0; j < 8; ++j) {
            float v = bf2f((unsigned short)b0[j]); sk = fmaf(v, v, sk);
            v = bf2f((unsigned short)b1[j]); sk = fmaf(v, v, sk);
        }
        sk += __shfl_xor(sk, 1, 64);
        sk += __shfl_xor(sk, 2, 64);
        if ((tid & 3) == 0) {
            invq[row] = 0.125f * rsqrtf(sq + 1e-6f);   // includes HD^-0.5
            invk[row] = rsqrtf(sk + 1e-6f);
        }
    }
    if (tid < 64) {
        cumS[tid] = cum[(size_t)bh * T_ + t0 + tid];
        betaS[tid] = beta[(size_t)(b * T_ + t0 + tid) * H_ + h];
    }
    __syncthreads();

    const int lr = lane & 15, lk = lane >> 4;
    const unsigned short* qrow = qkvb + (size_t)(b * T_ + t0 + wave * 16 + lr) * CD_ + h * HD_;
    bf16x8 qf0 = *(const bf16x8*)(qrow + lk * 8);
    bf16x8 qf1 = *(const bf16x8*)(qrow + 32 + lk * 8);

    // QK^T on RAW q,k
    f32x4 pacc[4] = {};
#pragma unroll
    for (int n = 0; n < 4; ++n) {
        const unsigned short* krow = qkvb + (size_t)(b * T_ + t0 + n * 16 + lr) * CD_ + D_ + h * HD_;
        bf16x8 b0 = *(const bf16x8*)(krow + lk * 8);
        bf16x8 b1 = *(const bf16x8*)(krow + 32 + lk * 8);
        pacc[n] = __builtin_amdgcn_mfma_f32_16x16x32_bf16(qf0, b0, pacc[n], 0, 0, 0);
        pacc[n] = __builtin_amdgcn_mfma_f32_16x16x32_bf16(qf1, b1, pacc[n], 0, 0, 0);
    }
    // decay + mask + beta + norms -> pS (bf16)
#pragma unroll
    for (int n = 0; n < 4; ++n) {
        int s = n * 16 + lr;
        float cs = cumS[s], bsk = betaS[s] * invk[s];
#pragma unroll
        for (int r = 0; r < 4; ++r) {
            int t = wave * 16 + lk * 4 + r;
            float pv = (s <= t) ? expf(cumS[t] - cs) * bsk * pacc[n][r] * invq[t] : 0.f;
            pS[t * TS + s] = f2bf(pv);
        }
    }
    __syncthreads();

    // O = Q * S_in^T-frags (raw q, scaled after)
    f32x4 oacc[4] = {};
#pragma unroll
    for (int n = 0; n < 4; ++n) {
        const short* srow = sT + (n * 16 + lr) * TS + lk * 8;
        bf16x8 b0 = *(const bf16x8*)srow;
        bf16x8 b1 = *(const bf16x8*)(srow + 32);
        oacc[n] = __builtin_amdgcn_mfma_f32_16x16x32_bf16(qf0, b0, oacc[n], 0, 0, 0);
        oacc[n] = __builtin_amdgcn_mfma_f32_16x16x32_bf16(qf1, b1, oacc[n], 0, 0, 0);
    }
    float qsc[4];
#pragma unroll
    for (int r = 0; r < 4; ++r) {
        int t = wave * 16 + lk * 4 + r;
        qsc[r] = expf(cumS[t]) * invq[t];
    }
#pragma unroll
    for (int n = 0; n < 4; ++n)
#pragma unroll
        for (int r = 0; r < 4; ++r) oacc[n][r] *= qsc[r];
    // + P * V
    const short* prow = pS + (wave * 16 + lr) * TS + lk * 8;
    bf16x8 pf0 = *(const bf16x8*)prow;
    bf16x8 pf1 = *(const bf16x8*)(prow + 32);
#pragma unroll
    for (int n = 0; n < 4; ++n) {
        const short* vrow = vT + (n * 16 + lr) * TS + lk * 8;
        bf16x8 b0 = *(const bf16x8*)vrow;
        bf16x8 b1 = *(const bf16x8*)(vrow + 32);
        oacc[n] = __builtin_amdgcn_mfma_f32_16x16x32_bf16(pf0, b0, oacc[n], 0, 0, 0);
        oacc[n] = __builtin_amdgcn_mfma_f32_16x16x32_bf16(pf1, b1, oacc[n], 0, 0, 0);
    }

    // fused gated RMSNorm over head dim + bf16 store
#pragma unroll
    for (int r = 0; r < 4; ++r) {
        int t = wave * 16 + lk * 4 + r;
        float ss = 0.f;
#pragma unroll
        for (int n = 0; n < 4; ++n) ss = fmaf(oacc[n][r], oacc[n][r], ss);
        ss += __shfl_xor(ss, 1, 64);
        ss += __shfl_xor(ss, 2, 64);
        ss += __shfl_xor(ss, 4, 64);
        ss += __shfl_xor(ss, 8, 64);
        float inv = rsqrtf(ss * (1.f / 64.f) + 1e-6f);
        size_t rowoff = (size_t)(b * T_ + t0 + t) * D_ + h * HD_;
#pragma unroll
        for (int n = 0; n < 4; ++n) {
            float zv = z[rowoff + n * 16 + lr];
            float sz = zv / (1.f + expf(-zv));
            normb[rowoff + n * 16 + lr] = f2bf(oacc[n][r] * inv * sz);
        }
    }
}

extern "C" void kernel_launch(void* const* d_in, const int* in_sizes, int n_in,
                              void* d_out, int out_size, void* d_ws, size_t ws_size,
                              hipStream_t stream) {
    const float* x       = (const float*)d_in[0];
    const float* W_qkv   = (const float*)d_in[1];
    const float* conv_w  = (const float*)d_in[2];
    const float* W_z     = (const float*)d_in[3];
    const float* W_b     = (const float*)d_in[4];
    const float* W_a     = (const float*)d_in[5];
    const float* dt_bias = (const float*)d_in[6];
    const float* A_log   = (const float*)d_in[7];
    const float* W_out   = (const float*)d_in[8];
    float* out = (float*)d_out;

    float* ws = (float*)d_ws;
    // Region A: mixedb (bf16) until conv; overlays after:
    unsigned short* mixedb = (unsigned short*)ws;              // 12.6M bf16 (25 MB)
    float* dST    = ws;                        // 4M floats (ph1 -> ph2 in-place -> ph3)
    unsigned short* normb = (unsigned short*)(ws + 4194304);   // 4.2M bf16 (ph3 output)
    float* betab  = ws + 8388608;              // 65,536
    float* gb     = ws + 8454144;              // 65,536
    float* cum    = ws + 8519680;              // 65,536
    float* ac     = ws + 8585216;              // 1,024
    unsigned short* Woutb = (unsigned short*)(ws + 8586240);   // 1M bf16
    // Region B: xb/Wqkvb/Wzb pre-conv; qkvb after
    unsigned short* xb    = (unsigned short*)(ws + 12582912);  // 4M bf16
    unsigned short* Wqkvb = (unsigned short*)(ws + 14680064);  // 3M bf16 (cat head)
    unsigned short* Wzb   = (unsigned short*)(ws + 16252928);  // 1M bf16 (cat tail)
    unsigned short* qkvb  = (unsigned short*)(ws + 12582912);  // 12.6M bf16
    // Region C
    float* z      = ws + 18874368;             // 4M floats
    float* bgpart = ws + 23068672;             // 1M floats (4 MB)

    const int M = B_ * T_;                     // 4096
    dim3 blk(256);

    cvt_all<<<dim3(9216), blk, 0, stream>>>(x, W_qkv, W_z, W_out, xb, Wqkvb, Wzb, Woutb);

    gemm_qkvz<<<dim3(1024), blk, 0, stream>>>(xb, Wqkvb, mixedb, z);

    conv_silu_tt<<<dim3(B_ * (T_ / TT) * (CD_ / 4) / 256), blk, 0, stream>>>(mixedb, conv_w, qkvb);

    proj_bg_partial<<<dim3(1024), blk, 0, stream>>>(x, W_b, W_a, bgpart);
    proj_bg_reduce<<<dim3(512), blk, 0, stream>>>(bgpart, dt_bias, A_log, betab, gb);

    chunk_phase1<<<dim3(B_ * H_ * NC_), blk, 0, stream>>>(qkvb, betab, gb, dST, cum, ac);
    chunk_phase2<<<dim3(B_ * H_ * 4096 / 256), blk, 0, stream>>>(dST, ac);
    chunk_phase3<<<dim3(B_ * H_ * NC_), blk, 0, stream>>>(qkvb, betab, cum, dST, z, normb);

    gemm_out<<<dim3(256), blk, 0, stream>>>(normb, Woutb, out);
}

// Round 11
// 164.626 us; speedup vs baseline: 10.6259x; 1.0072x over previous
//
#include <hip/hip_runtime.h>
#include <math.h>

#define B_  2
#define T_  2048
#define D_  1024
#define H_  16
#define HD_ 64
#define CD_ 3072   // 3*D
#define L_  64     // chunk length
#define NC_ 32     // T/L chunks
#define TS  72     // padded LDS stride in shorts (144 B, 16B-aligned rows)
#define TT  8      // conv time-tile

typedef __attribute__((ext_vector_type(8))) short bf16x8;
typedef __attribute__((ext_vector_type(4))) float f32x4;
typedef __attribute__((ext_vector_type(4))) unsigned short u16x4;

__device__ __forceinline__ unsigned short f2bf(float f) {
    unsigned int u = __float_as_uint(f);
    unsigned int r = (u + 0x7fffu + ((u >> 16) & 1u)) >> 16;
    return (unsigned short)r;
}
__device__ __forceinline__ float bf2f(unsigned short u) {
    return __uint_as_float(((unsigned int)u) << 16);
}

// ------- one-shot fp32 -> bf16 conversion of x, W_qkv, W_z, W_out -------
// float4 ranges: x 1048576 | W_qkv 786432 | W_z 262144 | W_out 262144 -> 2359296
__global__ __launch_bounds__(256)
void cvt_all(const float* __restrict__ x, const float* __restrict__ Wqkv,
             const float* __restrict__ Wz, const float* __restrict__ Wout,
             unsigned short* __restrict__ xb, unsigned short* __restrict__ Wqkvb,
             unsigned short* __restrict__ Wzb, unsigned short* __restrict__ Woutb) {
    int i = blockIdx.x * 256 + threadIdx.x;   // [0, 2359296)
    const float* src; unsigned short* dst; int li;
    if (i < 1048576)      { src = x;    dst = xb;    li = i; }
    else if (i < 1835008) { src = Wqkv; dst = Wqkvb; li = i - 1048576; }
    else if (i < 2097152) { src = Wz;   dst = Wzb;   li = i - 1835008; }
    else                  { src = Wout; dst = Woutb; li = i - 2097152; }
    float4 a = ((const float4*)src)[li];
    u16x4 o;
    o.x = f2bf(a.x); o.y = f2bf(a.y); o.z = f2bf(a.z); o.w = f2bf(a.w);
    ((u16x4*)dst)[li] = o;
}

// ------- merged qkv+z GEMM: A[4096,1024] x Wcat[4096,1024]^T -------
// 1D grid 1024, LINEAR mapping (consecutive blocks share M-panel);
// LDS double-buffered (stage k+1 issued before compute k).
// cols 0..3071 -> mixedb (bf16, stride 3072); cols 3072..4095 -> zb (bf16, stride 1024)
__global__ __launch_bounds__(256)
void gemm_qkvz(const unsigned short* __restrict__ A,
               const unsigned short* __restrict__ Bw,
               unsigned short* __restrict__ mixedb, unsigned short* __restrict__ zb) {
    const int K = 1024;
    __shared__ short As[2][128 * 32];
    __shared__ short Bs[2][128 * 32];
    const int tid = threadIdx.x;
    const int wgid = blockIdx.x;              // linear: bn-major within an M-panel
    const int bm = (wgid >> 5) * 128;
    const int bn = (wgid & 31) * 128;
    const int wave = tid >> 6;
    const int lane = tid & 63;
    const int wm = (wave >> 1) * 64;
    const int wn = (wave & 1) * 64;
    const int lr = lane & 15;
    const int lk = lane >> 4;

    f32x4 acc[4][4] = {};

    const int srow = tid >> 2;
    const int scol = (tid & 3) << 3;
    const unsigned short* Ag = A + (size_t)(bm + srow) * K + scol;
    const unsigned short* Bg = Bw + (size_t)(bn + srow) * K + scol;

#define STAGE_Q(buf, k0)                                                          \
    do {                                                                          \
        __builtin_amdgcn_global_load_lds(                                         \
            (const __attribute__((address_space(1))) void*)(Ag + (k0)),           \
            (__attribute__((address_space(3))) void*)(&As[buf][tid * 8]), 16, 0, 0); \
        __builtin_amdgcn_global_load_lds(                                         \
            (const __attribute__((address_space(1))) void*)(Ag + (size_t)64 * K + (k0)), \
            (__attribute__((address_space(3))) void*)(&As[buf][tid * 8 + 2048]), 16, 0, 0); \
        __builtin_amdgcn_global_load_lds(                                         \
            (const __attribute__((address_space(1))) void*)(Bg + (k0)),           \
            (__attribute__((address_space(3))) void*)(&Bs[buf][tid * 8]), 16, 0, 0); \
        __builtin_amdgcn_global_load_lds(                                         \
            (const __attribute__((address_space(1))) void*)(Bg + (size_t)64 * K + (k0)), \
            (__attribute__((address_space(3))) void*)(&Bs[buf][tid * 8 + 2048]), 16, 0, 0); \
    } while (0)

#define COMPUTE_Q(buf)                                                            \
    do {                                                                          \
        const short* pA = &As[buf][(wm + lr) * 32 + lk * 8];                      \
        const short* pB = &Bs[buf][(wn + lr) * 32 + lk * 8];                      \
        bf16x8 a[4], b[4];                                                        \
        _Pragma("unroll")                                                         \
        for (int mi = 0; mi < 4; ++mi) a[mi] = *(const bf16x8*)(pA + mi * 16 * 32); \
        _Pragma("unroll")                                                         \
        for (int ni = 0; ni < 4; ++ni) b[ni] = *(const bf16x8*)(pB + ni * 16 * 32); \
        _Pragma("unroll")                                                         \
        for (int mi = 0; mi < 4; ++mi)                                            \
            _Pragma("unroll")                                                     \
            for (int ni = 0; ni < 4; ++ni)                                        \
                acc[mi][ni] = __builtin_amdgcn_mfma_f32_16x16x32_bf16(            \
                    a[mi], b[ni], acc[mi][ni], 0, 0, 0);                          \
    } while (0)

    STAGE_Q(0, 0);
    __syncthreads();
    int cur = 0;
    for (int it = 0; it < 31; ++it) {
        STAGE_Q(cur ^ 1, (it + 1) * 32);   // issue next tile's loads
        COMPUTE_Q(cur);                    // compute under the loads' latency
        __syncthreads();
        cur ^= 1;
    }
    COMPUTE_Q(cur);

    const int r0 = lk * 4;
#pragma unroll
    for (int mi = 0; mi < 4; ++mi)
#pragma unroll
        for (int ni = 0; ni < 4; ++ni) {
            int row = bm + wm + mi * 16 + r0;
            int ncol = bn + wn + ni * 16 + lr;
            if (ncol < 3072) {
                unsigned short* cp = mixedb + (size_t)row * 3072 + ncol;
#pragma unroll
                for (int r = 0; r < 4; ++r)
                    cp[(size_t)r * 3072] = f2bf(acc[mi][ni][r]);
            } else {
                unsigned short* cp = zb + (size_t)row * 1024 + (ncol - 3072);
#pragma unroll
                for (int r = 0; r < 4; ++r)
                    cp[(size_t)r * 1024] = f2bf(acc[mi][ni][r]);
            }
        }
}

// ------- final out-projection GEMM: [4096,1024]x[1024,1024]^T, fp32 C -------
// 1D grid 256, linear mapping, double-buffered.
__global__ __launch_bounds__(256)
void gemm_out(const unsigned short* __restrict__ A,
              const unsigned short* __restrict__ Bw,
              float* __restrict__ C) {
    const int K = 1024, N = 1024;
    __shared__ short As[2][128 * 32];
    __shared__ short Bs[2][128 * 32];
    const int tid = threadIdx.x;
    const int wgid = blockIdx.x;
    const int bm = (wgid >> 3) * 128;
    const int bn = (wgid & 7) * 128;
    const int wave = tid >> 6;
    const int lane = tid & 63;
    const int wm = (wave >> 1) * 64;
    const int wn = (wave & 1) * 64;
    const int lr = lane & 15;
    const int lk = lane >> 4;

    f32x4 acc[4][4] = {};

    const int srow = tid >> 2;
    const int scol = (tid & 3) << 3;
    const unsigned short* Ag = A + (size_t)(bm + srow) * K + scol;
    const unsigned short* Bg = Bw + (size_t)(bn + srow) * K + scol;

    STAGE_Q(0, 0);
    __syncthreads();
    int cur = 0;
    for (int it = 0; it < 31; ++it) {
        STAGE_Q(cur ^ 1, (it + 1) * 32);
        COMPUTE_Q(cur);
        __syncthreads();
        cur ^= 1;
    }
    COMPUTE_Q(cur);

    const int r0 = lk * 4;
#pragma unroll
    for (int mi = 0; mi < 4; ++mi)
#pragma unroll
        for (int ni = 0; ni < 4; ++ni) {
            float* cp = C + (size_t)(bm + wm + mi * 16 + r0) * N + bn + wn + ni * 16 + lr;
#pragma unroll
            for (int r = 0; r < 4; ++r)
                cp[(size_t)r * N] = acc[mi][ni][r];
        }
}

// ------- beta/g projection, split-K partials (fp32): 128 Mtiles x 8 Kslices -------
#define PJS 129   // padded fp32 LDS stride
__global__ __launch_bounds__(256)
void proj_bg_partial(const float* __restrict__ x, const float* __restrict__ Wb,
                     const float* __restrict__ Wa, float* __restrict__ partial) {
    const int m0 = (blockIdx.x >> 3) * 32;   // M-tile
    const int ks = blockIdx.x & 7;           // K-slice
    const int k0 = ks * 128;
    const int tid = threadIdx.x;
    __shared__ float xs[32 * PJS];
    __shared__ float wsh[32 * PJS];
    const int sr = tid >> 3;                 // 0..31
    const int sc = (tid & 7) << 4;           // 0,16,...,112
    const int mi2 = tid >> 3;
    const int n02 = (tid & 7) << 2;          // 0,4,...,28

    {
        const float* xrow = x + (size_t)(m0 + sr) * D_ + k0 + sc;
        const float* wrow = ((sr < 16) ? (Wb + (size_t)sr * D_) : (Wa + (size_t)(sr - 16) * D_)) + k0 + sc;
#pragma unroll
        for (int j = 0; j < 16; j += 4) {
            float4 a = *(const float4*)(xrow + j);
            float4 b = *(const float4*)(wrow + j);
            xs[sr * PJS + sc + j + 0] = a.x; xs[sr * PJS + sc + j + 1] = a.y;
            xs[sr * PJS + sc + j + 2] = a.z; xs[sr * PJS + sc + j + 3] = a.w;
            wsh[sr * PJS + sc + j + 0] = b.x; wsh[sr * PJS + sc + j + 1] = b.y;
            wsh[sr * PJS + sc + j + 2] = b.z; wsh[sr * PJS + sc + j + 3] = b.w;
        }
    }
    __syncthreads();

    float acc[4] = {0.f, 0.f, 0.f, 0.f};
#pragma unroll 8
    for (int kk = 0; kk < 128; ++kk) {
        float av = xs[mi2 * PJS + kk];
#pragma unroll
        for (int j = 0; j < 4; ++j)
            acc[j] = fmaf(av, wsh[(n02 + j) * PJS + kk], acc[j]);
    }
    float* op = partial + (size_t)ks * (4096 * 32) + (size_t)(m0 + mi2) * 32 + n02;
    *(float4*)op = make_float4(acc[0], acc[1], acc[2], acc[3]);
}

__global__ __launch_bounds__(256)
void proj_bg_reduce(const float* __restrict__ partial, const float* __restrict__ dt_bias,
                    const float* __restrict__ A_log,
                    float* __restrict__ beta, float* __restrict__ g) {
    const int gid = blockIdx.x * 256 + threadIdx.x;   // [0, 4096*32)
    const int m = gid >> 5;
    const int n = gid & 31;
    float s = 0.f;
#pragma unroll
    for (int ks = 0; ks < 8; ++ks)
        s += partial[(size_t)ks * (4096 * 32) + gid];
    if (n < 16) {
        beta[(size_t)m * H_ + n] = 1.f / (1.f + expf(-s));
    } else {
        int h = n - 16;
        float spin = s + dt_bias[h];
        float sp = (spin > 20.f) ? spin : log1pf(expf(spin));
        g[(size_t)m * H_ + h] = -expf(A_log[h]) * sp;
    }
}

// ---- causal depthwise conv (K=4) + SiLU: bf16 in, time-tiled x8, bf16 out ----
__global__ __launch_bounds__(256)
void conv_silu_tt(const unsigned short* __restrict__ mixedb,
                  const float* __restrict__ conv_w,
                  unsigned short* __restrict__ qkvb) {
    int idx = blockIdx.x * 256 + threadIdx.x;   // over B*(T/TT)*(CD/4)
    const int cq = idx % (CD_ / 4);
    const int bt8 = idx / (CD_ / 4);
    const int t0 = (bt8 % (T_ / TT)) * TT;
    const int b = bt8 / (T_ / TT);
    const int c0 = cq << 2;
    const unsigned short* base = mixedb + (size_t)(b * T_ + t0) * CD_ + c0;

    float vals[TT + 3][4];
#pragma unroll
    for (int i = 0; i < TT + 3; ++i) {
        int t = t0 + i - 3;
        if (t >= 0) {
            u16x4 m = *(const u16x4*)(base + (ptrdiff_t)(i - 3) * CD_);
            vals[i][0] = bf2f(m.x); vals[i][1] = bf2f(m.y);
            vals[i][2] = bf2f(m.z); vals[i][3] = bf2f(m.w);
        } else {
            vals[i][0] = vals[i][1] = vals[i][2] = vals[i][3] = 0.f;
        }
    }
    const float4* wp = (const float4*)(conv_w + (size_t)c0 * 4);
    float4 w[4] = {wp[0], wp[1], wp[2], wp[3]};

    unsigned short* outp = qkvb + (size_t)(b * T_ + t0) * CD_ + c0;
#pragma unroll
    for (int tt = 0; tt < TT; ++tt) {
        u16x4 r;
        float s0 = vals[tt + 3][0] * w[0].w + vals[tt + 2][0] * w[0].z
                 + vals[tt + 1][0] * w[0].y + vals[tt + 0][0] * w[0].x;
        float s1 = vals[tt + 3][1] * w[1].w + vals[tt + 2][1] * w[1].z
                 + vals[tt + 1][1] * w[1].y + vals[tt + 0][1] * w[1].x;
        float s2 = vals[tt + 3][2] * w[2].w + vals[tt + 2][2] * w[2].z
                 + vals[tt + 1][2] * w[2].y + vals[tt + 0][2] * w[2].x;
        float s3 = vals[tt + 3][3] * w[3].w + vals[tt + 2][3] * w[3].z
                 + vals[tt + 1][3] * w[3].y + vals[tt + 0][3] * w[3].x;
        r.x = f2bf(s0 / (1.f + expf(-s0)));
        r.y = f2bf(s1 / (1.f + expf(-s1)));
        r.z = f2bf(s2 / (1.f + expf(-s2)));
        r.w = f2bf(s3 / (1.f + expf(-s3)));
        *(u16x4*)(outp + (size_t)tt * CD_) = r;
    }
}

// ------------ phase 1 (MFMA): per-chunk dS^T[v][d], cum, a_c; k-l2norm fused --
__global__ __launch_bounds__(256)
void chunk_phase1(const unsigned short* __restrict__ qkvb,
                  const float* __restrict__ beta, const float* __restrict__ gg,
                  float* __restrict__ dST, float* __restrict__ cum,
                  float* __restrict__ ac) {
    const int cid = blockIdx.x;           // (b*H+h)*NC + c
    const int c = cid & (NC_ - 1);
    const int bh = cid >> 5;
    const int b = bh >> 4, h = bh & 15;
    const int tid = threadIdx.x;
    const int wave = tid >> 6, lane = tid & 63;
    const int t0 = c * L_;

    __shared__ __align__(16) short kT[64 * TS];   // [d][s], RAW k
    __shared__ __align__(16) short vT[64 * TS];   // [v][s], weighted (beta*decay/||k||)
    __shared__ float cumS[64], wS[64];
    __shared__ float ksumP[4][64];                // per-wave k sumsq partials

    const unsigned short* rowp = qkvb + (size_t)(b * T_ + t0 + lane) * CD_ + h * HD_ + wave * 16;
    bf16x8 k0 = *(const bf16x8*)(rowp + D_);
    bf16x8 k1 = *(const bf16x8*)(rowp + D_ + 8);
    bf16x8 v0 = *(const bf16x8*)(rowp + 2 * D_);
    bf16x8 v1 = *(const bf16x8*)(rowp + 2 * D_ + 8);

    {   // partial sum of squares of this wave's 16 k-columns for timestep s=lane
        float ks = 0.f;
#pragma unroll
        for (int j = 0; j < 8; ++j) {
            float a = bf2f((unsigned short)k0[j]); ks = fmaf(a, a, ks);
            float bq = bf2f((unsigned short)k1[j]); ks = fmaf(bq, bq, ks);
        }
        ksumP[wave][lane] = ks;
    }

    if (wave == 0) {   // parallel inclusive scan of g over the 64 timesteps
        float s = gg[(size_t)(b * T_ + t0 + lane) * H_ + h];
#pragma unroll
        for (int off = 1; off < 64; off <<= 1) {
            float up = __shfl_up(s, off, 64);
            if (lane >= off) s += up;
        }
        cumS[lane] = s;
        float cend = __shfl(s, 63, 64);
        wS[lane] = expf(cend - s) * beta[(size_t)(b * T_ + t0 + lane) * H_ + h];
        cum[(size_t)bh * T_ + t0 + lane] = s;
        if (lane == 63) ac[cid] = expf(cend);
    }
    __syncthreads();
    const float kn = rsqrtf(ksumP[0][lane] + ksumP[1][lane] + ksumP[2][lane]
                            + ksumP[3][lane] + 1e-6f);
    const float w = wS[lane] * kn;     // fold 1/||k|| into the v-weight
#pragma unroll
    for (int j = 0; j < 8; ++j) {
        kT[(wave * 16 + j) * TS + lane] = k0[j];
        kT[(wave * 16 + 8 + j) * TS + lane] = k1[j];
        vT[(wave * 16 + j) * TS + lane] = f2bf(bf2f((unsigned short)v0[j]) * w);
        vT[(wave * 16 + 8 + j) * TS + lane] = f2bf(bf2f((unsigned short)v1[j]) * w);
    }
    __syncthreads();

    const int lr = lane & 15, lk = lane >> 4;
    f32x4 acc[4] = {};
    const short* pA = vT + (wave * 16 + lr) * TS + lk * 8;
#pragma unroll
    for (int kk = 0; kk < 2; ++kk) {
        bf16x8 a = *(const bf16x8*)(pA + kk * 32);
#pragma unroll
        for (int n = 0; n < 4; ++n) {
            bf16x8 bfr = *(const bf16x8*)(kT + (n * 16 + lr) * TS + lk * 8 + kk * 32);
            acc[n] = __builtin_amdgcn_mfma_f32_16x16x32_bf16(a, bfr, acc[n], 0, 0, 0);
        }
    }
#pragma unroll
    for (int n = 0; n < 4; ++n) {
        float* op = dST + (size_t)cid * 4096 + (wave * 16 + lk * 4) * 64 + n * 16 + lr;
#pragma unroll
        for (int r = 0; r < 4; ++r)
            op[r * 64] = acc[n][r];
    }
}

// ---------------- phase 2: scan over chunks, IN PLACE (dST -> states) --------
__global__ __launch_bounds__(256)
void chunk_phase2(float* __restrict__ dST, const float* __restrict__ ac) {
    const int gid = blockIdx.x * 256 + threadIdx.x;  // B*H*4096 = 131072
    const int bh = gid >> 12;
    const int e = gid & 4095;
    float s = 0.f;
    for (int c = 0; c < NC_; ++c) {
        size_t off = (size_t)(bh * NC_ + c) * 4096 + e;
        float tmp = dST[off];
        dST[off] = s;
        s = fmaf(ac[bh * NC_ + c], s, tmp);
    }
}

// -- phase 3 (MFMA): O = exp(ct)*Q*S_in + P*V; q/k-l2norm + gated-RMSNorm fused --
__global__ __launch_bounds__(256)
void chunk_phase3(const unsigned short* __restrict__ qkvb,
                  const float* __restrict__ beta, const float* __restrict__ cum,
                  const float* __restrict__ states,   // dST layout [cid][v][d] fp32
                  const unsigned short* __restrict__ zb,
                  unsigned short* __restrict__ normb) {
    const int cid = blockIdx.x;
    const int c = cid & (NC_ - 1);
    const int bh = cid >> 5;
    const int b = bh >> 4, h = bh & 15;
    const int tid = threadIdx.x;
    const int wave = tid >> 6, lane = tid & 63;
    const int t0 = c * L_;

    __shared__ __align__(16) short vT[64 * TS];   // [v][s]
    __shared__ __align__(16) short sT[64 * TS];   // S_in^T bf16 [v][d]
    __shared__ __align__(16) short pS[64 * TS];   // P [t][s] bf16
    __shared__ float cumS[64], betaS[64];
    __shared__ float invq[64], invk[64];

    {   // stage vT (transpose)
        const unsigned short* rowp = qkvb + (size_t)(b * T_ + t0 + lane) * CD_ + 2 * D_ + h * HD_ + wave * 16;
        bf16x8 v0 = *(const bf16x8*)rowp;
        bf16x8 v1 = *(const bf16x8*)(rowp + 8);
#pragma unroll
        for (int j = 0; j < 8; ++j) {
            vT[(wave * 16 + j) * TS + lane] = v0[j];
            vT[(wave * 16 + 8 + j) * TS + lane] = v1[j];
        }
    }
    {   // stage sT (fp32 -> bf16)
        const float* sp = states + (size_t)cid * 4096 + (tid >> 2) * 64 + (tid & 3) * 16;
        short* dp = sT + (tid >> 2) * TS + (tid & 3) * 16;
#pragma unroll
        for (int j = 0; j < 16; j += 4) {
            float4 f = *(const float4*)(sp + j);
            dp[j] = f2bf(f.x); dp[j + 1] = f2bf(f.y);
            dp[j + 2] = f2bf(f.z); dp[j + 3] = f2bf(f.w);
        }
    }
    {   // per-row l2norm factors for q and k (4 threads per row)
        int row = tid >> 2;
        int seg = (tid & 3) << 4;   // 0,16,32,48
        const unsigned short* qr = qkvb + (size_t)(b * T_ + t0 + row) * CD_ + h * HD_ + seg;
        bf16x8 a0 = *(const bf16x8*)qr;
        bf16x8 a1 = *(const bf16x8*)(qr + 8);
        float sq = 0.f;
#pragma unroll
        for (int j = 0; j < 8; ++j) {
            float v = bf2f((unsigned short)a0[j]); sq = fmaf(v, v, sq);
            v = bf2f((unsigned short)a1[j]); sq = fmaf(v, v, sq);
        }
        sq += __shfl_xor(sq, 1, 64);
        sq += __shfl_xor(sq, 2, 64);
        const unsigned short* kr = qr + D_;
        bf16x8 b0 = *(const bf16x8*)kr;
        bf16x8 b1 = *(const bf16x8*)(kr + 8);
        float sk = 0.f;
#pragma unroll
        for (int j = 0; j < 8; ++j) {
            float v = bf2f((unsigned short)b0[j]); sk = fmaf(v, v, sk);
            v = bf2f((unsigned short)b1[j]); sk = fmaf(v, v, sk);
        }
        sk += __shfl_xor(sk, 1, 64);
        sk += __shfl_xor(sk, 2, 64);
        if ((tid & 3) == 0) {
            invq[row] = 0.125f * rsqrtf(sq + 1e-6f);   // includes HD^-0.5
            invk[row] = rsqrtf(sk + 1e-6f);
        }
    }
    if (tid < 64) {
        cumS[tid] = cum[(size_t)bh * T_ + t0 + tid];
        betaS[tid] = beta[(size_t)(b * T_ + t0 + tid) * H_ + h];
    }
    __syncthreads();

    const int lr = lane & 15, lk = lane >> 4;
    const unsigned short* qrow = qkvb + (size_t)(b * T_ + t0 + wave * 16 + lr) * CD_ + h * HD_;
    bf16x8 qf0 = *(const bf16x8*)(qrow + lk * 8);
    bf16x8 qf1 = *(const bf16x8*)(qrow + 32 + lk * 8);

    // QK^T on RAW q,k
    f32x4 pacc[4] = {};
#pragma unroll
    for (int n = 0; n < 4; ++n) {
        const unsigned short* krow = qkvb + (size_t)(b * T_ + t0 + n * 16 + lr) * CD_ + D_ + h * HD_;
        bf16x8 b0 = *(const bf16x8*)(krow + lk * 8);
        bf16x8 b1 = *(const bf16x8*)(krow + 32 + lk * 8);
        pacc[n] = __builtin_amdgcn_mfma_f32_16x16x32_bf16(qf0, b0, pacc[n], 0, 0, 0);
        pacc[n] = __builtin_amdgcn_mfma_f32_16x16x32_bf16(qf1, b1, pacc[n], 0, 0, 0);
    }
    // decay + mask + beta + norms -> pS (bf16)
#pragma unroll
    for (int n = 0; n < 4; ++n) {
        int s = n * 16 + lr;
        float cs = cumS[s], bsk = betaS[s] * invk[s];
#pragma unroll
        for (int r = 0; r < 4; ++r) {
            int t = wave * 16 + lk * 4 + r;
            float pv = (s <= t) ? expf(cumS[t] - cs) * bsk * pacc[n][r] * invq[t] : 0.f;
            pS[t * TS + s] = f2bf(pv);
        }
    }
    __syncthreads();

    // O = Q * S_in^T-frags (raw q, scaled after)
    f32x4 oacc[4] = {};
#pragma unroll
    for (int n = 0; n < 4; ++n) {
        const short* srow = sT + (n * 16 + lr) * TS + lk * 8;
        bf16x8 b0 = *(const bf16x8*)srow;
        bf16x8 b1 = *(const bf16x8*)(srow + 32);
        oacc[n] = __builtin_amdgcn_mfma_f32_16x16x32_bf16(qf0, b0, oacc[n], 0, 0, 0);
        oacc[n] = __builtin_amdgcn_mfma_f32_16x16x32_bf16(qf1, b1, oacc[n], 0, 0, 0);
    }
    float qsc[4];
#pragma unroll
    for (int r = 0; r < 4; ++r) {
        int t = wave * 16 + lk * 4 + r;
        qsc[r] = expf(cumS[t]) * invq[t];
    }
#pragma unroll
    for (int n = 0; n < 4; ++n)
#pragma unroll
        for (int r = 0; r < 4; ++r) oacc[n][r] *= qsc[r];
    // + P * V
    const short* prow = pS + (wave * 16 + lr) * TS + lk * 8;
    bf16x8 pf0 = *(const bf16x8*)prow;
    bf16x8 pf1 = *(const bf16x8*)(prow + 32);
#pragma unroll
    for (int n = 0; n < 4; ++n) {
        const short* vrow = vT + (n * 16 + lr) * TS + lk * 8;
        bf16x8 b0 = *(const bf16x8*)vrow;
        bf16x8 b1 = *(const bf16x8*)(vrow + 32);
        oacc[n] = __builtin_amdgcn_mfma_f32_16x16x32_bf16(pf0, b0, oacc[n], 0, 0, 0);
        oacc[n] = __builtin_amdgcn_mfma_f32_16x16x32_bf16(pf1, b1, oacc[n], 0, 0, 0);
    }

    // fused gated RMSNorm over head dim + bf16 store
#pragma unroll
    for (int r = 0; r < 4; ++r) {
        int t = wave * 16 + lk * 4 + r;
        float ss = 0.f;
#pragma unroll
        for (int n = 0; n < 4; ++n) ss = fmaf(oacc[n][r], oacc[n][r], ss);
        ss += __shfl_xor(ss, 1, 64);
        ss += __shfl_xor(ss, 2, 64);
        ss += __shfl_xor(ss, 4, 64);
        ss += __shfl_xor(ss, 8, 64);
        float inv = rsqrtf(ss * (1.f / 64.f) + 1e-6f);
        size_t rowoff = (size_t)(b * T_ + t0 + t) * D_ + h * HD_;
#pragma unroll
        for (int n = 0; n < 4; ++n) {
            float zv = bf2f(zb[rowoff + n * 16 + lr]);
            float sz = zv / (1.f + expf(-zv));
            normb[rowoff + n * 16 + lr] = f2bf(oacc[n][r] * inv * sz);
        }
    }
}

extern "C" void kernel_launch(void* const* d_in, const int* in_sizes, int n_in,
                              void* d_out, int out_size, void* d_ws, size_t ws_size,
                              hipStream_t stream) {
    const float* x       = (const float*)d_in[0];
    const float* W_qkv   = (const float*)d_in[1];
    const float* conv_w  = (const float*)d_in[2];
    const float* W_z     = (const float*)d_in[3];
    const float* W_b     = (const float*)d_in[4];
    const float* W_a     = (const float*)d_in[5];
    const float* dt_bias = (const float*)d_in[6];
    const float* A_log   = (const float*)d_in[7];
    const float* W_out   = (const float*)d_in[8];
    float* out = (float*)d_out;

    float* ws = (float*)d_ws;
    // Region A: mixedb (bf16) until conv; overlays after:
    unsigned short* mixedb = (unsigned short*)ws;              // 12.6M bf16 (25 MB)
    float* dST    = ws;                        // 4M floats (ph1 -> ph2 in-place -> ph3)
    unsigned short* normb = (unsigned short*)(ws + 4194304);   // 4.2M bf16 (ph3 output)
    float* betab  = ws + 8388608;              // 65,536
    float* gb     = ws + 8454144;              // 65,536
    float* cum    = ws + 8519680;              // 65,536
    float* ac     = ws + 8585216;              // 1,024
    unsigned short* Woutb = (unsigned short*)(ws + 8586240);   // 1M bf16
    // Region B: xb/Wqkvb/Wzb pre-conv; qkvb after
    unsigned short* xb    = (unsigned short*)(ws + 12582912);  // 4M bf16
    unsigned short* Wqkvb = (unsigned short*)(ws + 14680064);  // 3M bf16 (cat head)
    unsigned short* Wzb   = (unsigned short*)(ws + 16252928);  // 1M bf16 (cat tail)
    unsigned short* qkvb  = (unsigned short*)(ws + 12582912);  // 12.6M bf16
    // Region C
    unsigned short* zb    = (unsigned short*)(ws + 18874368);  // 4.2M bf16 (2 MB... 4M shorts)
    float* bgpart = ws + 23068672;             // 1M floats (4 MB)

    const int M = B_ * T_;                     // 4096
    dim3 blk(256);

    cvt_all<<<dim3(9216), blk, 0, stream>>>(x, W_qkv, W_z, W_out, xb, Wqkvb, Wzb, Woutb);

    gemm_qkvz<<<dim3(1024), blk, 0, stream>>>(xb, Wqkvb, mixedb, zb);

    conv_silu_tt<<<dim3(B_ * (T_ / TT) * (CD_ / 4) / 256), blk, 0, stream>>>(mixedb, conv_w, qkvb);

    proj_bg_partial<<<dim3(1024), blk, 0, stream>>>(x, W_b, W_a, bgpart);
    proj_bg_reduce<<<dim3(512), blk, 0, stream>>>(bgpart, dt_bias, A_log, betab, gb);

    chunk_phase1<<<dim3(B_ * H_ * NC_), blk, 0, stream>>>(qkvb, betab, gb, dST, cum, ac);
    chunk_phase2<<<dim3(B_ * H_ * 4096 / 256), blk, 0, stream>>>(dST, ac);
    chunk_phase3<<<dim3(B_ * H_ * NC_), blk, 0, stream>>>(qkvb, betab, cum, dST, zb, normb);

    gemm_out<<<dim3(256), blk, 0, stream>>>(normb, Woutb, out);
}

// Round 12
// 144.858 us; speedup vs baseline: 12.0760x; 1.1365x over previous
//
#include <hip/hip_runtime.h>
#include <math.h>

#define B_  2
#define T_  2048
#define D_  1024
#define H_  16
#define HD_ 64
#define CD_ 3072   // 3*D
#define L_  64     // chunk length
#define NC_ 32     // T/L chunks
#define TS  72     // padded LDS stride in shorts (144 B, 16B-aligned rows)
#define TT  8      // conv time-tile

typedef __attribute__((ext_vector_type(8))) short bf16x8;
typedef __attribute__((ext_vector_type(4))) float f32x4;
typedef __attribute__((ext_vector_type(4))) unsigned short u16x4;

__device__ __forceinline__ unsigned short f2bf(float f) {
    unsigned int u = __float_as_uint(f);
    unsigned int r = (u + 0x7fffu + ((u >> 16) & 1u)) >> 16;
    return (unsigned short)r;
}
__device__ __forceinline__ float bf2f(unsigned short u) {
    return __uint_as_float(((unsigned int)u) << 16);
}

// ------- one-shot fp32 -> bf16 conversion of x, W_qkv, W_z, W_out -------
__global__ __launch_bounds__(256)
void cvt_all(const float* __restrict__ x, const float* __restrict__ Wqkv,
             const float* __restrict__ Wz, const float* __restrict__ Wout,
             unsigned short* __restrict__ xb, unsigned short* __restrict__ Wqkvb,
             unsigned short* __restrict__ Wzb, unsigned short* __restrict__ Woutb) {
    int i = blockIdx.x * 256 + threadIdx.x;   // [0, 2359296)
    const float* src; unsigned short* dst; int li;
    if (i < 1048576)      { src = x;    dst = xb;    li = i; }
    else if (i < 1835008) { src = Wqkv; dst = Wqkvb; li = i - 1048576; }
    else if (i < 2097152) { src = Wz;   dst = Wzb;   li = i - 1835008; }
    else                  { src = Wout; dst = Woutb; li = i - 2097152; }
    float4 a = ((const float4*)src)[li];
    u16x4 o;
    o.x = f2bf(a.x); o.y = f2bf(a.y); o.z = f2bf(a.z); o.w = f2bf(a.w);
    ((u16x4*)dst)[li] = o;
}

// ================= 256x256-tile merged qkv+z GEMM (8 waves) =================
// A[4096,1024] x Wcat[4096,1024]^T. Grid 256 x 512 threads, 128 KiB dyn LDS.
// 2 LDS buffers, BK=64, chunk-XOR swizzle (linear gload_lds dest, pre-swizzled
// global source, swizzled ds_read). cols<3072 -> mixedb bf16; else zb bf16.
__global__ __launch_bounds__(512, 2)
void gemm_qkvz256(const unsigned short* __restrict__ A,
                  const unsigned short* __restrict__ Bw,
                  unsigned short* __restrict__ mixedb, unsigned short* __restrict__ zb) {
    const int K = 1024;
    extern __shared__ short lds[];      // [buf:2][A:16384 | B:16384] shorts
    const int tid = threadIdx.x;
    const int bm = (blockIdx.x >> 4) * 256;
    const int bn = (blockIdx.x & 15) * 256;
    const int wid = tid >> 6;
    const int lane = tid & 63;
    const int wm = (wid >> 2) * 128;    // 2 M-wave rows
    const int wn = (wid & 3) * 64;      // 4 N-wave cols
    const int lr = lane & 15;
    const int lk = lane >> 4;

    f32x4 acc[8][4] = {};

    // staging: thread t covers row srow (+j*64), physical 16B chunk sphys;
    // source column chunk is XOR-swizzled so a linear LDS write yields a
    // swizzled layout (readable conflict-free below).
    const int srow = tid >> 3;                       // 0..63
    const int sphys = tid & 7;
    const int sgcol = ((sphys ^ (srow & 7)) << 3);   // shorts
    const unsigned short* Ag = A + (size_t)(bm + srow) * K + sgcol;
    const unsigned short* Bg = Bw + (size_t)(bn + srow) * K + sgcol;
    short* ldsAd = lds + srow * 64 + sphys * 8;      // + bsel*32768 + j*4096
    short* ldsBd = ldsAd + 16384;

#define STG256(bsel, kt)                                                         \
    do {                                                                         \
        _Pragma("unroll")                                                        \
        for (int j = 0; j < 4; ++j) {                                            \
            __builtin_amdgcn_global_load_lds(                                    \
                (const __attribute__((address_space(1))) void*)(Ag + (size_t)(j * 64) * K + (kt) * 64), \
                (__attribute__((address_space(3))) void*)(ldsAd + (bsel) * 32768 + j * 4096), 16, 0, 0); \
            __builtin_amdgcn_global_load_lds(                                    \
                (const __attribute__((address_space(1))) void*)(Bg + (size_t)(j * 64) * K + (kt) * 64), \
                (__attribute__((address_space(3))) void*)(ldsBd + (bsel) * 32768 + j * 4096), 16, 0, 0); \
        }                                                                        \
    } while (0)

#define CMP256(bsel)                                                             \
    do {                                                                         \
        const short* LA = lds + (bsel) * 32768 + (wm + lr) * 64;                 \
        const short* LB = lds + (bsel) * 32768 + 16384 + (wn + lr) * 64;         \
        _Pragma("unroll")                                                        \
        for (int ks = 0; ks < 2; ++ks) {                                         \
            const int ch = ((ks * 4 + lk) ^ (lr & 7)) * 8;                       \
            bf16x8 bf[4], af[4];                                                 \
            _Pragma("unroll")                                                    \
            for (int ni = 0; ni < 4; ++ni) bf[ni] = *(const bf16x8*)(LB + ni * 1024 + ch); \
            _Pragma("unroll")                                                    \
            for (int mi = 0; mi < 4; ++mi) af[mi] = *(const bf16x8*)(LA + mi * 1024 + ch); \
            __builtin_amdgcn_s_setprio(1);                                       \
            _Pragma("unroll")                                                    \
            for (int mi = 0; mi < 4; ++mi)                                       \
                _Pragma("unroll")                                                \
                for (int ni = 0; ni < 4; ++ni)                                   \
                    acc[mi][ni] = __builtin_amdgcn_mfma_f32_16x16x32_bf16(       \
                        af[mi], bf[ni], acc[mi][ni], 0, 0, 0);                   \
            __builtin_amdgcn_s_setprio(0);                                       \
            _Pragma("unroll")                                                    \
            for (int mi = 0; mi < 4; ++mi) af[mi] = *(const bf16x8*)(LA + (mi + 4) * 1024 + ch); \
            __builtin_amdgcn_s_setprio(1);                                       \
            _Pragma("unroll")                                                    \
            for (int mi = 0; mi < 4; ++mi)                                       \
                _Pragma("unroll")                                                \
                for (int ni = 0; ni < 4; ++ni)                                   \
                    acc[mi + 4][ni] = __builtin_amdgcn_mfma_f32_16x16x32_bf16(   \
                        af[mi], bf[ni], acc[mi + 4][ni], 0, 0, 0);               \
            __builtin_amdgcn_s_setprio(0);                                       \
        }                                                                        \
    } while (0)

    STG256(0, 0);
    __syncthreads();
    for (int kt = 0; kt < 15; ++kt) {
        STG256((kt + 1) & 1, kt + 1);   // issue next K-tile's loads first
        CMP256(kt & 1);                 // 64 MFMA/wave under the load latency
        __syncthreads();                // drains vmcnt; both buffers settled
    }
    CMP256(1);                          // kt = 15

    const int r0 = lk * 4;
#pragma unroll
    for (int mi = 0; mi < 8; ++mi)
#pragma unroll
        for (int ni = 0; ni < 4; ++ni) {
            int row = bm + wm + mi * 16 + r0;
            int col = bn + wn + ni * 16 + lr;
            if (bn < 3072) {
                unsigned short* cp = mixedb + (size_t)row * 3072 + col;
#pragma unroll
                for (int r = 0; r < 4; ++r) cp[(size_t)r * 3072] = f2bf(acc[mi][ni][r]);
            } else {
                unsigned short* cp = zb + (size_t)row * 1024 + (col - 3072);
#pragma unroll
                for (int r = 0; r < 4; ++r) cp[(size_t)r * 1024] = f2bf(acc[mi][ni][r]);
            }
        }
}

// ------- final out-projection GEMM: [4096,1024]x[1024,1024]^T, fp32 C -------
// 128^2 tile, 256 blocks, double-buffered (unchanged this round).
__global__ __launch_bounds__(256)
void gemm_out(const unsigned short* __restrict__ A,
              const unsigned short* __restrict__ Bw,
              float* __restrict__ C) {
    const int K = 1024, N = 1024;
    __shared__ short As[2][128 * 32];
    __shared__ short Bs[2][128 * 32];
    const int tid = threadIdx.x;
    const int wgid = blockIdx.x;
    const int bm = (wgid >> 3) * 128;
    const int bn = (wgid & 7) * 128;
    const int wave = tid >> 6;
    const int lane = tid & 63;
    const int wm = (wave >> 1) * 64;
    const int wn = (wave & 1) * 64;
    const int lr = lane & 15;
    const int lk = lane >> 4;

    f32x4 acc[4][4] = {};

    const int srow = tid >> 2;
    const int scol = (tid & 3) << 3;
    const unsigned short* Ag = A + (size_t)(bm + srow) * K + scol;
    const unsigned short* Bg = Bw + (size_t)(bn + srow) * K + scol;

#define STAGE_Q(buf, k0)                                                          \
    do {                                                                          \
        __builtin_amdgcn_global_load_lds(                                         \
            (const __attribute__((address_space(1))) void*)(Ag + (k0)),           \
            (__attribute__((address_space(3))) void*)(&As[buf][tid * 8]), 16, 0, 0); \
        __builtin_amdgcn_global_load_lds(                                         \
            (const __attribute__((address_space(1))) void*)(Ag + (size_t)64 * K + (k0)), \
            (__attribute__((address_space(3))) void*)(&As[buf][tid * 8 + 2048]), 16, 0, 0); \
        __builtin_amdgcn_global_load_lds(                                         \
            (const __attribute__((address_space(1))) void*)(Bg + (k0)),           \
            (__attribute__((address_space(3))) void*)(&Bs[buf][tid * 8]), 16, 0, 0); \
        __builtin_amdgcn_global_load_lds(                                         \
            (const __attribute__((address_space(1))) void*)(Bg + (size_t)64 * K + (k0)), \
            (__attribute__((address_space(3))) void*)(&Bs[buf][tid * 8 + 2048]), 16, 0, 0); \
    } while (0)

#define COMPUTE_Q(buf)                                                            \
    do {                                                                          \
        const short* pA = &As[buf][(wm + lr) * 32 + lk * 8];                      \
        const short* pB = &Bs[buf][(wn + lr) * 32 + lk * 8];                      \
        bf16x8 a[4], b[4];                                                        \
        _Pragma("unroll")                                                         \
        for (int mi = 0; mi < 4; ++mi) a[mi] = *(const bf16x8*)(pA + mi * 16 * 32); \
        _Pragma("unroll")                                                         \
        for (int ni = 0; ni < 4; ++ni) b[ni] = *(const bf16x8*)(pB + ni * 16 * 32); \
        _Pragma("unroll")                                                         \
        for (int mi = 0; mi < 4; ++mi)                                            \
            _Pragma("unroll")                                                     \
            for (int ni = 0; ni < 4; ++ni)                                        \
                acc[mi][ni] = __builtin_amdgcn_mfma_f32_16x16x32_bf16(            \
                    a[mi], b[ni], acc[mi][ni], 0, 0, 0);                          \
    } while (0)

    STAGE_Q(0, 0);
    __syncthreads();
    int cur = 0;
    for (int it = 0; it < 31; ++it) {
        STAGE_Q(cur ^ 1, (it + 1) * 32);
        COMPUTE_Q(cur);
        __syncthreads();
        cur ^= 1;
    }
    COMPUTE_Q(cur);

    const int r0 = lk * 4;
#pragma unroll
    for (int mi = 0; mi < 4; ++mi)
#pragma unroll
        for (int ni = 0; ni < 4; ++ni) {
            float* cp = C + (size_t)(bm + wm + mi * 16 + r0) * N + bn + wn + ni * 16 + lr;
#pragma unroll
            for (int r = 0; r < 4; ++r)
                cp[(size_t)r * N] = acc[mi][ni][r];
        }
}

// ------- beta/g projection, split-K partials (fp32): 128 Mtiles x 8 Kslices -------
#define PJS 129   // padded fp32 LDS stride
__global__ __launch_bounds__(256)
void proj_bg_partial(const float* __restrict__ x, const float* __restrict__ Wb,
                     const float* __restrict__ Wa, float* __restrict__ partial) {
    const int m0 = (blockIdx.x >> 3) * 32;   // M-tile
    const int ks = blockIdx.x & 7;           // K-slice
    const int k0 = ks * 128;
    const int tid = threadIdx.x;
    __shared__ float xs[32 * PJS];
    __shared__ float wsh[32 * PJS];
    const int sr = tid >> 3;                 // 0..31
    const int sc = (tid & 7) << 4;           // 0,16,...,112
    const int mi2 = tid >> 3;
    const int n02 = (tid & 7) << 2;          // 0,4,...,28

    {
        const float* xrow = x + (size_t)(m0 + sr) * D_ + k0 + sc;
        const float* wrow = ((sr < 16) ? (Wb + (size_t)sr * D_) : (Wa + (size_t)(sr - 16) * D_)) + k0 + sc;
#pragma unroll
        for (int j = 0; j < 16; j += 4) {
            float4 a = *(const float4*)(xrow + j);
            float4 b = *(const float4*)(wrow + j);
            xs[sr * PJS + sc + j + 0] = a.x; xs[sr * PJS + sc + j + 1] = a.y;
            xs[sr * PJS + sc + j + 2] = a.z; xs[sr * PJS + sc + j + 3] = a.w;
            wsh[sr * PJS + sc + j + 0] = b.x; wsh[sr * PJS + sc + j + 1] = b.y;
            wsh[sr * PJS + sc + j + 2] = b.z; wsh[sr * PJS + sc + j + 3] = b.w;
        }
    }
    __syncthreads();

    float acc[4] = {0.f, 0.f, 0.f, 0.f};
#pragma unroll 8
    for (int kk = 0; kk < 128; ++kk) {
        float av = xs[mi2 * PJS + kk];
#pragma unroll
        for (int j = 0; j < 4; ++j)
            acc[j] = fmaf(av, wsh[(n02 + j) * PJS + kk], acc[j]);
    }
    float* op = partial + (size_t)ks * (4096 * 32) + (size_t)(m0 + mi2) * 32 + n02;
    *(float4*)op = make_float4(acc[0], acc[1], acc[2], acc[3]);
}

__global__ __launch_bounds__(256)
void proj_bg_reduce(const float* __restrict__ partial, const float* __restrict__ dt_bias,
                    const float* __restrict__ A_log,
                    float* __restrict__ beta, float* __restrict__ g) {
    const int gid = blockIdx.x * 256 + threadIdx.x;   // [0, 4096*32)
    const int m = gid >> 5;
    const int n = gid & 31;
    float s = 0.f;
#pragma unroll
    for (int ks = 0; ks < 8; ++ks)
        s += partial[(size_t)ks * (4096 * 32) + gid];
    if (n < 16) {
        beta[(size_t)m * H_ + n] = 1.f / (1.f + expf(-s));
    } else {
        int h = n - 16;
        float spin = s + dt_bias[h];
        float sp = (spin > 20.f) ? spin : log1pf(expf(spin));
        g[(size_t)m * H_ + h] = -expf(A_log[h]) * sp;
    }
}

// ---- causal depthwise conv (K=4) + SiLU: bf16 in, time-tiled x8, bf16 out ----
__global__ __launch_bounds__(256)
void conv_silu_tt(const unsigned short* __restrict__ mixedb,
                  const float* __restrict__ conv_w,
                  unsigned short* __restrict__ qkvb) {
    int idx = blockIdx.x * 256 + threadIdx.x;   // over B*(T/TT)*(CD/4)
    const int cq = idx % (CD_ / 4);
    const int bt8 = idx / (CD_ / 4);
    const int t0 = (bt8 % (T_ / TT)) * TT;
    const int b = bt8 / (T_ / TT);
    const int c0 = cq << 2;
    const unsigned short* base = mixedb + (size_t)(b * T_ + t0) * CD_ + c0;

    float vals[TT + 3][4];
#pragma unroll
    for (int i = 0; i < TT + 3; ++i) {
        int t = t0 + i - 3;
        if (t >= 0) {
            u16x4 m = *(const u16x4*)(base + (ptrdiff_t)(i - 3) * CD_);
            vals[i][0] = bf2f(m.x); vals[i][1] = bf2f(m.y);
            vals[i][2] = bf2f(m.z); vals[i][3] = bf2f(m.w);
        } else {
            vals[i][0] = vals[i][1] = vals[i][2] = vals[i][3] = 0.f;
        }
    }
    const float4* wp = (const float4*)(conv_w + (size_t)c0 * 4);
    float4 w[4] = {wp[0], wp[1], wp[2], wp[3]};

    unsigned short* outp = qkvb + (size_t)(b * T_ + t0) * CD_ + c0;
#pragma unroll
    for (int tt = 0; tt < TT; ++tt) {
        u16x4 r;
        float s0 = vals[tt + 3][0] * w[0].w + vals[tt + 2][0] * w[0].z
                 + vals[tt + 1][0] * w[0].y + vals[tt + 0][0] * w[0].x;
        float s1 = vals[tt + 3][1] * w[1].w + vals[tt + 2][1] * w[1].z
                 + vals[tt + 1][1] * w[1].y + vals[tt + 0][1] * w[1].x;
        float s2 = vals[tt + 3][2] * w[2].w + vals[tt + 2][2] * w[2].z
                 + vals[tt + 1][2] * w[2].y + vals[tt + 0][2] * w[2].x;
        float s3 = vals[tt + 3][3] * w[3].w + vals[tt + 2][3] * w[3].z
                 + vals[tt + 1][3] * w[3].y + vals[tt + 0][3] * w[3].x;
        r.x = f2bf(s0 / (1.f + expf(-s0)));
        r.y = f2bf(s1 / (1.f + expf(-s1)));
        r.z = f2bf(s2 / (1.f + expf(-s2)));
        r.w = f2bf(s3 / (1.f + expf(-s3)));
        *(u16x4*)(outp + (size_t)tt * CD_) = r;
    }
}

// ------------ phase 1 (MFMA): per-chunk dS^T[v][d], cum, a_c; k-l2norm fused --
__global__ __launch_bounds__(256)
void chunk_phase1(const unsigned short* __restrict__ qkvb,
                  const float* __restrict__ beta, const float* __restrict__ gg,
                  float* __restrict__ dST, float* __restrict__ cum,
                  float* __restrict__ ac) {
    const int cid = blockIdx.x;           // (b*H+h)*NC + c
    const int c = cid & (NC_ - 1);
    const int bh = cid >> 5;
    const int b = bh >> 4, h = bh & 15;
    const int tid = threadIdx.x;
    const int wave = tid >> 6, lane = tid & 63;
    const int t0 = c * L_;

    __shared__ __align__(16) short kT[64 * TS];   // [d][s], RAW k
    __shared__ __align__(16) short vT[64 * TS];   // [v][s], weighted (beta*decay/||k||)
    __shared__ float cumS[64], wS[64];
    __shared__ float ksumP[4][64];                // per-wave k sumsq partials

    const unsigned short* rowp = qkvb + (size_t)(b * T_ + t0 + lane) * CD_ + h * HD_ + wave * 16;
    bf16x8 k0 = *(const bf16x8*)(rowp + D_);
    bf16x8 k1 = *(const bf16x8*)(rowp + D_ + 8);
    bf16x8 v0 = *(const bf16x8*)(rowp + 2 * D_);
    bf16x8 v1 = *(const bf16x8*)(rowp + 2 * D_ + 8);

    {   // partial sum of squares of this wave's 16 k-columns for timestep s=lane
        float ks = 0.f;
#pragma unroll
        for (int j = 0; j < 8; ++j) {
            float a = bf2f((unsigned short)k0[j]); ks = fmaf(a, a, ks);
            float bq = bf2f((unsigned short)k1[j]); ks = fmaf(bq, bq, ks);
        }
        ksumP[wave][lane] = ks;
    }

    if (wave == 0) {   // parallel inclusive scan of g over the 64 timesteps
        float s = gg[(size_t)(b * T_ + t0 + lane) * H_ + h];
#pragma unroll
        for (int off = 1; off < 64; off <<= 1) {
            float up = __shfl_up(s, off, 64);
            if (lane >= off) s += up;
        }
        cumS[lane] = s;
        float cend = __shfl(s, 63, 64);
        wS[lane] = expf(cend - s) * beta[(size_t)(b * T_ + t0 + lane) * H_ + h];
        cum[(size_t)bh * T_ + t0 + lane] = s;
        if (lane == 63) ac[cid] = expf(cend);
    }
    __syncthreads();
    const float kn = rsqrtf(ksumP[0][lane] + ksumP[1][lane] + ksumP[2][lane]
                            + ksumP[3][lane] + 1e-6f);
    const float w = wS[lane] * kn;     // fold 1/||k|| into the v-weight
#pragma unroll
    for (int j = 0; j < 8; ++j) {
        kT[(wave * 16 + j) * TS + lane] = k0[j];
        kT[(wave * 16 + 8 + j) * TS + lane] = k1[j];
        vT[(wave * 16 + j) * TS + lane] = f2bf(bf2f((unsigned short)v0[j]) * w);
        vT[(wave * 16 + 8 + j) * TS + lane] = f2bf(bf2f((unsigned short)v1[j]) * w);
    }
    __syncthreads();

    const int lr = lane & 15, lk = lane >> 4;
    f32x4 acc[4] = {};
    const short* pA = vT + (wave * 16 + lr) * TS + lk * 8;
#pragma unroll
    for (int kk = 0; kk < 2; ++kk) {
        bf16x8 a = *(const bf16x8*)(pA + kk * 32);
#pragma unroll
        for (int n = 0; n < 4; ++n) {
            bf16x8 bfr = *(const bf16x8*)(kT + (n * 16 + lr) * TS + lk * 8 + kk * 32);
            acc[n] = __builtin_amdgcn_mfma_f32_16x16x32_bf16(a, bfr, acc[n], 0, 0, 0);
        }
    }
#pragma unroll
    for (int n = 0; n < 4; ++n) {
        float* op = dST + (size_t)cid * 4096 + (wave * 16 + lk * 4) * 64 + n * 16 + lr;
#pragma unroll
        for (int r = 0; r < 4; ++r)
            op[r * 64] = acc[n][r];
    }
}

// ---------------- phase 2: scan over chunks, IN PLACE (dST -> states) --------
__global__ __launch_bounds__(256)
void chunk_phase2(float* __restrict__ dST, const float* __restrict__ ac) {
    const int gid = blockIdx.x * 256 + threadIdx.x;  // B*H*4096 = 131072
    const int bh = gid >> 12;
    const int e = gid & 4095;
    float s = 0.f;
    for (int c = 0; c < NC_; ++c) {
        size_t off = (size_t)(bh * NC_ + c) * 4096 + e;
        float tmp = dST[off];
        dST[off] = s;
        s = fmaf(ac[bh * NC_ + c], s, tmp);
    }
}

// -- phase 3 (MFMA): O = exp(ct)*Q*S_in + P*V; q/k-l2norm + gated-RMSNorm fused --
__global__ __launch_bounds__(256)
void chunk_phase3(const unsigned short* __restrict__ qkvb,
                  const float* __restrict__ beta, const float* __restrict__ cum,
                  const float* __restrict__ states,   // dST layout [cid][v][d] fp32
                  const unsigned short* __restrict__ zb,
                  unsigned short* __restrict__ normb) {
    const int cid = blockIdx.x;
    const int c = cid & (NC_ - 1);
    const int bh = cid >> 5;
    const int b = bh >> 4, h = bh & 15;
    const int tid = threadIdx.x;
    const int wave = tid >> 6, lane = tid & 63;
    const int t0 = c * L_;

    __shared__ __align__(16) short vT[64 * TS];   // [v][s]
    __shared__ __align__(16) short sT[64 * TS];   // S_in^T bf16 [v][d]
    __shared__ __align__(16) short pS[64 * TS];   // P [t][s] bf16
    __shared__ float cumS[64], betaS[64];
    __shared__ float invq[64], invk[64];

    {   // stage vT (transpose)
        const unsigned short* rowp = qkvb + (size_t)(b * T_ + t0 + lane) * CD_ + 2 * D_ + h * HD_ + wave * 16;
        bf16x8 v0 = *(const bf16x8*)rowp;
        bf16x8 v1 = *(const bf16x8*)(rowp + 8);
#pragma unroll
        for (int j = 0; j < 8; ++j) {
            vT[(wave * 16 + j) * TS + lane] = v0[j];
            vT[(wave * 16 + 8 + j) * TS + lane] = v1[j];
        }
    }
    {   // stage sT (fp32 -> bf16)
        const float* sp = states + (size_t)cid * 4096 + (tid >> 2) * 64 + (tid & 3) * 16;
        short* dp = sT + (tid >> 2) * TS + (tid & 3) * 16;
#pragma unroll
        for (int j = 0; j < 16; j += 4) {
            float4 f = *(const float4*)(sp + j);
            dp[j] = f2bf(f.x); dp[j + 1] = f2bf(f.y);
            dp[j + 2] = f2bf(f.z); dp[j + 3] = f2bf(f.w);
        }
    }
    {   // per-row l2norm factors for q and k (4 threads per row)
        int row = tid >> 2;
        int seg = (tid & 3) << 4;   // 0,16,32,48
        const unsigned short* qr = qkvb + (size_t)(b * T_ + t0 + row) * CD_ + h * HD_ + seg;
        bf16x8 a0 = *(const bf16x8*)qr;
        bf16x8 a1 = *(const bf16x8*)(qr + 8);
        float sq = 0.f;
#pragma unroll
        for (int j = 0; j < 8; ++j) {
            float v = bf2f((unsigned short)a0[j]); sq = fmaf(v, v, sq);
            v = bf2f((unsigned short)a1[j]); sq = fmaf(v, v, sq);
        }
        sq += __shfl_xor(sq, 1, 64);
        sq += __shfl_xor(sq, 2, 64);
        const unsigned short* kr = qr + D_;
        bf16x8 b0 = *(const bf16x8*)kr;
        bf16x8 b1 = *(const bf16x8*)(kr + 8);
        float sk = 0.f;
#pragma unroll
        for (int j = 0; j < 8; ++j) {
            float v = bf2f((unsigned short)b0[j]); sk = fmaf(v, v, sk);
            v = bf2f((unsigned short)b1[j]); sk = fmaf(v, v, sk);
        }
        sk += __shfl_xor(sk, 1, 64);
        sk += __shfl_xor(sk, 2, 64);
        if ((tid & 3) == 0) {
            invq[row] = 0.125f * rsqrtf(sq + 1e-6f);   // includes HD^-0.5
            invk[row] = rsqrtf(sk + 1e-6f);
        }
    }
    if (tid < 64) {
        cumS[tid] = cum[(size_t)bh * T_ + t0 + tid];
        betaS[tid] = beta[(size_t)(b * T_ + t0 + tid) * H_ + h];
    }
    __syncthreads();

    const int lr = lane & 15, lk = lane >> 4;
    const unsigned short* qrow = qkvb + (size_t)(b * T_ + t0 + wave * 16 + lr) * CD_ + h * HD_;
    bf16x8 qf0 = *(const bf16x8*)(qrow + lk * 8);
    bf16x8 qf1 = *(const bf16x8*)(qrow + 32 + lk * 8);

    // QK^T on RAW q,k
    f32x4 pacc[4] = {};
#pragma unroll
    for (int n = 0; n < 4; ++n) {
        const unsigned short* krow = qkvb + (size_t)(b * T_ + t0 + n * 16 + lr) * CD_ + D_ + h * HD_;
        bf16x8 b0 = *(const bf16x8*)(krow + lk * 8);
        bf16x8 b1 = *(const bf16x8*)(krow + 32 + lk * 8);
        pacc[n] = __builtin_amdgcn_mfma_f32_16x16x32_bf16(qf0, b0, pacc[n], 0, 0, 0);
        pacc[n] = __builtin_amdgcn_mfma_f32_16x16x32_bf16(qf1, b1, pacc[n], 0, 0, 0);
    }
    // decay + mask + beta + norms -> pS (bf16)
#pragma unroll
    for (int n = 0; n < 4; ++n) {
        int s = n * 16 + lr;
        float cs = cumS[s], bsk = betaS[s] * invk[s];
#pragma unroll
        for (int r = 0; r < 4; ++r) {
            int t = wave * 16 + lk * 4 + r;
            float pv = (s <= t) ? expf(cumS[t] - cs) * bsk * pacc[n][r] * invq[t] : 0.f;
            pS[t * TS + s] = f2bf(pv);
        }
    }
    __syncthreads();

    // O = Q * S_in^T-frags (raw q, scaled after)
    f32x4 oacc[4] = {};
#pragma unroll
    for (int n = 0; n < 4; ++n) {
        const short* srow = sT + (n * 16 + lr) * TS + lk * 8;
        bf16x8 b0 = *(const bf16x8*)srow;
        bf16x8 b1 = *(const bf16x8*)(srow + 32);
        oacc[n] = __builtin_amdgcn_mfma_f32_16x16x32_bf16(qf0, b0, oacc[n], 0, 0, 0);
        oacc[n] = __builtin_amdgcn_mfma_f32_16x16x32_bf16(qf1, b1, oacc[n], 0, 0, 0);
    }
    float qsc[4];
#pragma unroll
    for (int r = 0; r < 4; ++r) {
        int t = wave * 16 + lk * 4 + r;
        qsc[r] = expf(cumS[t]) * invq[t];
    }
#pragma unroll
    for (int n = 0; n < 4; ++n)
#pragma unroll
        for (int r = 0; r < 4; ++r) oacc[n][r] *= qsc[r];
    // + P * V
    const short* prow = pS + (wave * 16 + lr) * TS + lk * 8;
    bf16x8 pf0 = *(const bf16x8*)prow;
    bf16x8 pf1 = *(const bf16x8*)(prow + 32);
#pragma unroll
    for (int n = 0; n < 4; ++n) {
        const short* vrow = vT + (n * 16 + lr) * TS + lk * 8;
        bf16x8 b0 = *(const bf16x8*)vrow;
        bf16x8 b1 = *(const bf16x8*)(vrow + 32);
        oacc[n] = __builtin_amdgcn_mfma_f32_16x16x32_bf16(pf0, b0, oacc[n], 0, 0, 0);
        oacc[n] = __builtin_amdgcn_mfma_f32_16x16x32_bf16(pf1, b1, oacc[n], 0, 0, 0);
    }

    // fused gated RMSNorm over head dim + bf16 store
#pragma unroll
    for (int r = 0; r < 4; ++r) {
        int t = wave * 16 + lk * 4 + r;
        float ss = 0.f;
#pragma unroll
        for (int n = 0; n < 4; ++n) ss = fmaf(oacc[n][r], oacc[n][r], ss);
        ss += __shfl_xor(ss, 1, 64);
        ss += __shfl_xor(ss, 2, 64);
        ss += __shfl_xor(ss, 4, 64);
        ss += __shfl_xor(ss, 8, 64);
        float inv = rsqrtf(ss * (1.f / 64.f) + 1e-6f);
        size_t rowoff = (size_t)(b * T_ + t0 + t) * D_ + h * HD_;
#pragma unroll
        for (int n = 0; n < 4; ++n) {
            float zv = bf2f(zb[rowoff + n * 16 + lr]);
            float sz = zv / (1.f + expf(-zv));
            normb[rowoff + n * 16 + lr] = f2bf(oacc[n][r] * inv * sz);
        }
    }
}

extern "C" void kernel_launch(void* const* d_in, const int* in_sizes, int n_in,
                              void* d_out, int out_size, void* d_ws, size_t ws_size,
                              hipStream_t stream) {
    const float* x       = (const float*)d_in[0];
    const float* W_qkv   = (const float*)d_in[1];
    const float* conv_w  = (const float*)d_in[2];
    const float* W_z     = (const float*)d_in[3];
    const float* W_b     = (const float*)d_in[4];
    const float* W_a     = (const float*)d_in[5];
    const float* dt_bias = (const float*)d_in[6];
    const float* A_log   = (const float*)d_in[7];
    const float* W_out   = (const float*)d_in[8];
    float* out = (float*)d_out;

    float* ws = (float*)d_ws;
    // Region A: mixedb (bf16) until conv; overlays after:
    unsigned short* mixedb = (unsigned short*)ws;              // 12.6M bf16 (25 MB)
    float* dST    = ws;                        // 4M floats (ph1 -> ph2 in-place -> ph3)
    unsigned short* normb = (unsigned short*)(ws + 4194304);   // 4.2M bf16 (ph3 output)
    float* betab  = ws + 8388608;              // 65,536
    float* gb     = ws + 8454144;              // 65,536
    float* cum    = ws + 8519680;              // 65,536
    float* ac     = ws + 8585216;              // 1,024
    unsigned short* Woutb = (unsigned short*)(ws + 8586240);   // 1M bf16
    // Region B: xb/Wqkvb/Wzb pre-conv; qkvb after
    unsigned short* xb    = (unsigned short*)(ws + 12582912);  // 4M bf16
    unsigned short* Wqkvb = (unsigned short*)(ws + 14680064);  // 3M bf16 (cat head)
    unsigned short* Wzb   = (unsigned short*)(ws + 16252928);  // 1M bf16 (cat tail)
    unsigned short* qkvb  = (unsigned short*)(ws + 12582912);  // 12.6M bf16
    // Region C
    unsigned short* zb    = (unsigned short*)(ws + 18874368);  // 4M bf16
    float* bgpart = ws + 23068672;             // 1M floats (4 MB)

    const int M = B_ * T_;                     // 4096
    dim3 blk(256);

    cvt_all<<<dim3(9216), blk, 0, stream>>>(x, W_qkv, W_z, W_out, xb, Wqkvb, Wzb, Woutb);

    gemm_qkvz256<<<dim3(256), dim3(512), 131072, stream>>>(xb, Wqkvb, mixedb, zb);

    conv_silu_tt<<<dim3(B_ * (T_ / TT) * (CD_ / 4) / 256), blk, 0, stream>>>(mixedb, conv_w, qkvb);

    proj_bg_partial<<<dim3(1024), blk, 0, stream>>>(x, W_b, W_a, bgpart);
    proj_bg_reduce<<<dim3(512), blk, 0, stream>>>(bgpart, dt_bias, A_log, betab, gb);

    chunk_phase1<<<dim3(B_ * H_ * NC_), blk, 0, stream>>>(qkvb, betab, gb, dST, cum, ac);
    chunk_phase2<<<dim3(B_ * H_ * 4096 / 256), blk, 0, stream>>>(dST, ac);
    chunk_phase3<<<dim3(B_ * H_ * NC_), blk, 0, stream>>>(qkvb, betab, cum, dST, zb, normb);

    gemm_out<<<dim3(256), blk, 0, stream>>>(normb, Woutb, out);
}

// Round 13
// 133.832 us; speedup vs baseline: 13.0708x; 1.0824x over previous
//
#include <hip/hip_runtime.h>
#include <math.h>

#define B_  2
#define T_  2048
#define D_  1024
#define H_  16
#define HD_ 64
#define CD_ 3072   // 3*D
#define L_  64     // chunk length
#define NC_ 32     // T/L chunks
#define TS  72     // padded LDS stride in shorts (144 B, 16B-aligned rows)
#define TT  8      // conv time-tile

typedef __attribute__((ext_vector_type(8))) short bf16x8;
typedef __attribute__((ext_vector_type(4))) float f32x4;
typedef __attribute__((ext_vector_type(4))) unsigned short u16x4;

__device__ __forceinline__ unsigned short f2bf(float f) {
    unsigned int u = __float_as_uint(f);
    unsigned int r = (u + 0x7fffu + ((u >> 16) & 1u)) >> 16;
    return (unsigned short)r;
}
__device__ __forceinline__ float bf2f(unsigned short u) {
    return __uint_as_float(((unsigned int)u) << 16);
}

// ------- one-shot fp32 -> bf16 conversion of x, W_qkv, W_z, W_out -------
__global__ __launch_bounds__(256)
void cvt_all(const float* __restrict__ x, const float* __restrict__ Wqkv,
             const float* __restrict__ Wz, const float* __restrict__ Wout,
             unsigned short* __restrict__ xb, unsigned short* __restrict__ Wqkvb,
             unsigned short* __restrict__ Wzb, unsigned short* __restrict__ Woutb) {
    int i = blockIdx.x * 256 + threadIdx.x;   // [0, 2359296)
    const float* src; unsigned short* dst; int li;
    if (i < 1048576)      { src = x;    dst = xb;    li = i; }
    else if (i < 1835008) { src = Wqkv; dst = Wqkvb; li = i - 1048576; }
    else if (i < 2097152) { src = Wz;   dst = Wzb;   li = i - 1835008; }
    else                  { src = Wout; dst = Woutb; li = i - 2097152; }
    float4 a = ((const float4*)src)[li];
    u16x4 o;
    o.x = f2bf(a.x); o.y = f2bf(a.y); o.z = f2bf(a.z); o.w = f2bf(a.w);
    ((u16x4*)dst)[li] = o;
}

// ================= 256x256-tile merged qkv+z GEMM (8 waves) =================
// A[4096,1024] x Wcat[4096,1024]^T. Grid 256 x 512 threads, 128 KiB dyn LDS.
// 2 LDS buffers, BK=64, chunk-XOR swizzle (linear gload_lds dest, pre-swizzled
// global source, swizzled ds_read). cols<3072 -> mixedb bf16; else zb bf16.
__global__ __launch_bounds__(512, 2)
void gemm_qkvz256(const unsigned short* __restrict__ A,
                  const unsigned short* __restrict__ Bw,
                  unsigned short* __restrict__ mixedb, unsigned short* __restrict__ zb) {
    const int K = 1024;
    extern __shared__ short lds[];      // [buf:2][A:16384 | B:16384] shorts
    const int tid = threadIdx.x;
    const int bm = (blockIdx.x >> 4) * 256;
    const int bn = (blockIdx.x & 15) * 256;
    const int wid = tid >> 6;
    const int lane = tid & 63;
    const int wm = (wid >> 2) * 128;    // 2 M-wave rows
    const int wn = (wid & 3) * 64;      // 4 N-wave cols
    const int lr = lane & 15;
    const int lk = lane >> 4;

    f32x4 acc[8][4] = {};

    const int srow = tid >> 3;                       // 0..63
    const int sphys = tid & 7;
    const int sgcol = ((sphys ^ (srow & 7)) << 3);   // shorts
    const unsigned short* Ag = A + (size_t)(bm + srow) * K + sgcol;
    const unsigned short* Bg = Bw + (size_t)(bn + srow) * K + sgcol;
    short* ldsAd = lds + srow * 64 + sphys * 8;      // + bsel*32768 + j*4096
    short* ldsBd = ldsAd + 16384;

#define STG256(bsel, kt)                                                         \
    do {                                                                         \
        _Pragma("unroll")                                                        \
        for (int j = 0; j < 4; ++j) {                                            \
            __builtin_amdgcn_global_load_lds(                                    \
                (const __attribute__((address_space(1))) void*)(Ag + (size_t)(j * 64) * K + (kt) * 64), \
                (__attribute__((address_space(3))) void*)(ldsAd + (bsel) * 32768 + j * 4096), 16, 0, 0); \
            __builtin_amdgcn_global_load_lds(                                    \
                (const __attribute__((address_space(1))) void*)(Bg + (size_t)(j * 64) * K + (kt) * 64), \
                (__attribute__((address_space(3))) void*)(ldsBd + (bsel) * 32768 + j * 4096), 16, 0, 0); \
        }                                                                        \
    } while (0)

#define CMP256(bsel)                                                             \
    do {                                                                         \
        const short* LA = lds + (bsel) * 32768 + (wm + lr) * 64;                 \
        const short* LB = lds + (bsel) * 32768 + 16384 + (wn + lr) * 64;         \
        _Pragma("unroll")                                                        \
        for (int ks = 0; ks < 2; ++ks) {                                         \
            const int ch = ((ks * 4 + lk) ^ (lr & 7)) * 8;                       \
            bf16x8 bf[4], af[4];                                                 \
            _Pragma("unroll")                                                    \
            for (int ni = 0; ni < 4; ++ni) bf[ni] = *(const bf16x8*)(LB + ni * 1024 + ch); \
            _Pragma("unroll")                                                    \
            for (int mi = 0; mi < 4; ++mi) af[mi] = *(const bf16x8*)(LA + mi * 1024 + ch); \
            __builtin_amdgcn_s_setprio(1);                                       \
            _Pragma("unroll")                                                    \
            for (int mi = 0; mi < 4; ++mi)                                       \
                _Pragma("unroll")                                                \
                for (int ni = 0; ni < 4; ++ni)                                   \
                    acc[mi][ni] = __builtin_amdgcn_mfma_f32_16x16x32_bf16(       \
                        af[mi], bf[ni], acc[mi][ni], 0, 0, 0);                   \
            __builtin_amdgcn_s_setprio(0);                                       \
            _Pragma("unroll")                                                    \
            for (int mi = 0; mi < 4; ++mi) af[mi] = *(const bf16x8*)(LA + (mi + 4) * 1024 + ch); \
            __builtin_amdgcn_s_setprio(1);                                       \
            _Pragma("unroll")                                                    \
            for (int mi = 0; mi < 4; ++mi)                                       \
                _Pragma("unroll")                                                \
                for (int ni = 0; ni < 4; ++ni)                                   \
                    acc[mi + 4][ni] = __builtin_amdgcn_mfma_f32_16x16x32_bf16(   \
                        af[mi], bf[ni], acc[mi + 4][ni], 0, 0, 0);               \
            __builtin_amdgcn_s_setprio(0);                                       \
        }                                                                        \
    } while (0)

    STG256(0, 0);
    __syncthreads();
    for (int kt = 0; kt < 15; ++kt) {
        STG256((kt + 1) & 1, kt + 1);   // issue next K-tile's loads first
        CMP256(kt & 1);                 // 64 MFMA/wave under the load latency
        __syncthreads();                // drains vmcnt; both buffers settled
    }
    CMP256(1);                          // kt = 15

    const int r0 = lk * 4;
#pragma unroll
    for (int mi = 0; mi < 8; ++mi)
#pragma unroll
        for (int ni = 0; ni < 4; ++ni) {
            int row = bm + wm + mi * 16 + r0;
            int col = bn + wn + ni * 16 + lr;
            if (bn < 3072) {
                unsigned short* cp = mixedb + (size_t)row * 3072 + col;
#pragma unroll
                for (int r = 0; r < 4; ++r) cp[(size_t)r * 3072] = f2bf(acc[mi][ni][r]);
            } else {
                unsigned short* cp = zb + (size_t)row * 1024 + (col - 3072);
#pragma unroll
                for (int r = 0; r < 4; ++r) cp[(size_t)r * 1024] = f2bf(acc[mi][ni][r]);
            }
        }
}

// ------- final out-projection GEMM: [4096,1024]x[1024,1024]^T, fp32 C -------
// 128^2 tile, BK=64, 4 waves, both-sides XOR swizzle, 2 LDS bufs (64 KB,
// 2 blocks/CU), 32 MFMA/wave per barrier.
__global__ __launch_bounds__(256, 2)
void gemm_out(const unsigned short* __restrict__ A,
              const unsigned short* __restrict__ Bw,
              float* __restrict__ C) {
    const int K = 1024, N = 1024;
    __shared__ short Ls[2][16384];      // per buf: A[128][64] | B[128][64]
    const int tid = threadIdx.x;
    const int bm = (blockIdx.x >> 3) * 128;
    const int bn = (blockIdx.x & 7) * 128;
    const int wave = tid >> 6;
    const int lane = tid & 63;
    const int wm = (wave >> 1) * 64;
    const int wn = (wave & 1) * 64;
    const int lr = lane & 15;
    const int lk = lane >> 4;

    f32x4 acc[4][4] = {};

    const int srow = tid >> 3;                       // 0..31
    const int sphys = tid & 7;
    const int sgcol = ((sphys ^ (srow & 7)) << 3);
    const unsigned short* Ag = A + (size_t)(bm + srow) * K + sgcol;
    const unsigned short* Bg = Bw + (size_t)(bn + srow) * K + sgcol;
    short* ldsAd = &Ls[0][0] + srow * 64 + sphys * 8;   // + bsel*16384 + j*2048
    short* ldsBd = ldsAd + 8192;

#define STG_O(bsel, kt)                                                          \
    do {                                                                         \
        _Pragma("unroll")                                                        \
        for (int j = 0; j < 4; ++j) {                                            \
            __builtin_amdgcn_global_load_lds(                                    \
                (const __attribute__((address_space(1))) void*)(Ag + (size_t)(j * 32) * K + (kt) * 64), \
                (__attribute__((address_space(3))) void*)(ldsAd + (bsel) * 16384 + j * 2048), 16, 0, 0); \
            __builtin_amdgcn_global_load_lds(                                    \
                (const __attribute__((address_space(1))) void*)(Bg + (size_t)(j * 32) * K + (kt) * 64), \
                (__attribute__((address_space(3))) void*)(ldsBd + (bsel) * 16384 + j * 2048), 16, 0, 0); \
        }                                                                        \
    } while (0)

#define CMP_O(bsel)                                                              \
    do {                                                                         \
        const short* LA = &Ls[bsel][0] + (wm + lr) * 64;                         \
        const short* LB = &Ls[bsel][8192] + (wn + lr) * 64;                      \
        _Pragma("unroll")                                                        \
        for (int ks = 0; ks < 2; ++ks) {                                         \
            const int ch = ((ks * 4 + lk) ^ (lr & 7)) * 8;                       \
            bf16x8 af[4], bf[4];                                                 \
            _Pragma("unroll")                                                    \
            for (int mi = 0; mi < 4; ++mi) af[mi] = *(const bf16x8*)(LA + mi * 1024 + ch); \
            _Pragma("unroll")                                                    \
            for (int ni = 0; ni < 4; ++ni) bf[ni] = *(const bf16x8*)(LB + ni * 1024 + ch); \
            __builtin_amdgcn_s_setprio(1);                                       \
            _Pragma("unroll")                                                    \
            for (int mi = 0; mi < 4; ++mi)                                       \
                _Pragma("unroll")                                                \
                for (int ni = 0; ni < 4; ++ni)                                   \
                    acc[mi][ni] = __builtin_amdgcn_mfma_f32_16x16x32_bf16(       \
                        af[mi], bf[ni], acc[mi][ni], 0, 0, 0);                   \
            __builtin_amdgcn_s_setprio(0);                                       \
        }                                                                        \
    } while (0)

    STG_O(0, 0);
    __syncthreads();
    for (int kt = 0; kt < 15; ++kt) {
        STG_O((kt + 1) & 1, kt + 1);
        CMP_O(kt & 1);
        __syncthreads();
    }
    CMP_O(1);                           // kt = 15

    const int r0 = lk * 4;
#pragma unroll
    for (int mi = 0; mi < 4; ++mi)
#pragma unroll
        for (int ni = 0; ni < 4; ++ni) {
            float* cp = C + (size_t)(bm + wm + mi * 16 + r0) * N + bn + wn + ni * 16 + lr;
#pragma unroll
            for (int r = 0; r < 4; ++r)
                cp[(size_t)r * N] = acc[mi][ni][r];
        }
}

// ------- beta/g projection, split-K partials (fp32): 128 Mtiles x 8 Kslices -------
#define PJS 129   // padded fp32 LDS stride
__global__ __launch_bounds__(256)
void proj_bg_partial(const float* __restrict__ x, const float* __restrict__ Wb,
                     const float* __restrict__ Wa, float* __restrict__ partial) {
    const int m0 = (blockIdx.x >> 3) * 32;   // M-tile
    const int ks = blockIdx.x & 7;           // K-slice
    const int k0 = ks * 128;
    const int tid = threadIdx.x;
    __shared__ float xs[32 * PJS];
    __shared__ float wsh[32 * PJS];
    const int sr = tid >> 3;                 // 0..31
    const int sc = (tid & 7) << 4;           // 0,16,...,112
    const int mi2 = tid >> 3;
    const int n02 = (tid & 7) << 2;          // 0,4,...,28

    {
        const float* xrow = x + (size_t)(m0 + sr) * D_ + k0 + sc;
        const float* wrow = ((sr < 16) ? (Wb + (size_t)sr * D_) : (Wa + (size_t)(sr - 16) * D_)) + k0 + sc;
#pragma unroll
        for (int j = 0; j < 16; j += 4) {
            float4 a = *(const float4*)(xrow + j);
            float4 b = *(const float4*)(wrow + j);
            xs[sr * PJS + sc + j + 0] = a.x; xs[sr * PJS + sc + j + 1] = a.y;
            xs[sr * PJS + sc + j + 2] = a.z; xs[sr * PJS + sc + j + 3] = a.w;
            wsh[sr * PJS + sc + j + 0] = b.x; wsh[sr * PJS + sc + j + 1] = b.y;
            wsh[sr * PJS + sc + j + 2] = b.z; wsh[sr * PJS + sc + j + 3] = b.w;
        }
    }
    __syncthreads();

    float acc[4] = {0.f, 0.f, 0.f, 0.f};
#pragma unroll 8
    for (int kk = 0; kk < 128; ++kk) {
        float av = xs[mi2 * PJS + kk];
#pragma unroll
        for (int j = 0; j < 4; ++j)
            acc[j] = fmaf(av, wsh[(n02 + j) * PJS + kk], acc[j]);
    }
    float* op = partial + (size_t)ks * (4096 * 32) + (size_t)(m0 + mi2) * 32 + n02;
    *(float4*)op = make_float4(acc[0], acc[1], acc[2], acc[3]);
}

__global__ __launch_bounds__(256)
void proj_bg_reduce(const float* __restrict__ partial, const float* __restrict__ dt_bias,
                    const float* __restrict__ A_log,
                    float* __restrict__ beta, float* __restrict__ g) {
    const int gid = blockIdx.x * 256 + threadIdx.x;   // [0, 4096*32)
    const int m = gid >> 5;
    const int n = gid & 31;
    float s = 0.f;
#pragma unroll
    for (int ks = 0; ks < 8; ++ks)
        s += partial[(size_t)ks * (4096 * 32) + gid];
    if (n < 16) {
        beta[(size_t)m * H_ + n] = 1.f / (1.f + expf(-s));
    } else {
        int h = n - 16;
        float spin = s + dt_bias[h];
        float sp = (spin > 20.f) ? spin : log1pf(expf(spin));
        g[(size_t)m * H_ + h] = -expf(A_log[h]) * sp;
    }
}

// ---- causal depthwise conv (K=4) + SiLU: bf16 in, time-tiled x8, bf16 out ----
__global__ __launch_bounds__(256)
void conv_silu_tt(const unsigned short* __restrict__ mixedb,
                  const float* __restrict__ conv_w,
                  unsigned short* __restrict__ qkvb) {
    int idx = blockIdx.x * 256 + threadIdx.x;   // over B*(T/TT)*(CD/4)
    const int cq = idx % (CD_ / 4);
    const int bt8 = idx / (CD_ / 4);
    const int t0 = (bt8 % (T_ / TT)) * TT;
    const int b = bt8 / (T_ / TT);
    const int c0 = cq << 2;
    const unsigned short* base = mixedb + (size_t)(b * T_ + t0) * CD_ + c0;

    float vals[TT + 3][4];
#pragma unroll
    for (int i = 0; i < TT + 3; ++i) {
        int t = t0 + i - 3;
        if (t >= 0) {
            u16x4 m = *(const u16x4*)(base + (ptrdiff_t)(i - 3) * CD_);
            vals[i][0] = bf2f(m.x); vals[i][1] = bf2f(m.y);
            vals[i][2] = bf2f(m.z); vals[i][3] = bf2f(m.w);
        } else {
            vals[i][0] = vals[i][1] = vals[i][2] = vals[i][3] = 0.f;
        }
    }
    const float4* wp = (const float4*)(conv_w + (size_t)c0 * 4);
    float4 w[4] = {wp[0], wp[1], wp[2], wp[3]};

    unsigned short* outp = qkvb + (size_t)(b * T_ + t0) * CD_ + c0;
#pragma unroll
    for (int tt = 0; tt < TT; ++tt) {
        u16x4 r;
        float s0 = vals[tt + 3][0] * w[0].w + vals[tt + 2][0] * w[0].z
                 + vals[tt + 1][0] * w[0].y + vals[tt + 0][0] * w[0].x;
        float s1 = vals[tt + 3][1] * w[1].w + vals[tt + 2][1] * w[1].z
                 + vals[tt + 1][1] * w[1].y + vals[tt + 0][1] * w[1].x;
        float s2 = vals[tt + 3][2] * w[2].w + vals[tt + 2][2] * w[2].z
                 + vals[tt + 1][2] * w[2].y + vals[tt + 0][2] * w[2].x;
        float s3 = vals[tt + 3][3] * w[3].w + vals[tt + 2][3] * w[3].z
                 + vals[tt + 1][3] * w[3].y + vals[tt + 0][3] * w[3].x;
        r.x = f2bf(s0 / (1.f + expf(-s0)));
        r.y = f2bf(s1 / (1.f + expf(-s1)));
        r.z = f2bf(s2 / (1.f + expf(-s2)));
        r.w = f2bf(s3 / (1.f + expf(-s3)));
        *(u16x4*)(outp + (size_t)tt * CD_) = r;
    }
}

// ------------ phase 1 (MFMA): per-chunk dS^T[v][d], cum, a_c; k-l2norm fused --
__global__ __launch_bounds__(256)
void chunk_phase1(const unsigned short* __restrict__ qkvb,
                  const float* __restrict__ beta, const float* __restrict__ gg,
                  float* __restrict__ dST, float* __restrict__ cum,
                  float* __restrict__ ac) {
    const int cid = blockIdx.x;           // (b*H+h)*NC + c
    const int c = cid & (NC_ - 1);
    const int bh = cid >> 5;
    const int b = bh >> 4, h = bh & 15;
    const int tid = threadIdx.x;
    const int wave = tid >> 6, lane = tid & 63;
    const int t0 = c * L_;

    __shared__ __align__(16) short kT[64 * TS];   // [d][s], RAW k
    __shared__ __align__(16) short vT[64 * TS];   // [v][s], weighted (beta*decay/||k||)
    __shared__ float cumS[64], wS[64];
    __shared__ float ksumP[4][64];                // per-wave k sumsq partials

    const unsigned short* rowp = qkvb + (size_t)(b * T_ + t0 + lane) * CD_ + h * HD_ + wave * 16;
    bf16x8 k0 = *(const bf16x8*)(rowp + D_);
    bf16x8 k1 = *(const bf16x8*)(rowp + D_ + 8);
    bf16x8 v0 = *(const bf16x8*)(rowp + 2 * D_);
    bf16x8 v1 = *(const bf16x8*)(rowp + 2 * D_ + 8);

    {   // partial sum of squares of this wave's 16 k-columns for timestep s=lane
        float ks = 0.f;
#pragma unroll
        for (int j = 0; j < 8; ++j) {
            float a = bf2f((unsigned short)k0[j]); ks = fmaf(a, a, ks);
            float bq = bf2f((unsigned short)k1[j]); ks = fmaf(bq, bq, ks);
        }
        ksumP[wave][lane] = ks;
    }

    if (wave == 0) {   // parallel inclusive scan of g over the 64 timesteps
        float s = gg[(size_t)(b * T_ + t0 + lane) * H_ + h];
#pragma unroll
        for (int off = 1; off < 64; off <<= 1) {
            float up = __shfl_up(s, off, 64);
            if (lane >= off) s += up;
        }
        cumS[lane] = s;
        float cend = __shfl(s, 63, 64);
        wS[lane] = expf(cend - s) * beta[(size_t)(b * T_ + t0 + lane) * H_ + h];
        cum[(size_t)bh * T_ + t0 + lane] = s;
        if (lane == 63) ac[cid] = expf(cend);
    }
    __syncthreads();
    const float kn = rsqrtf(ksumP[0][lane] + ksumP[1][lane] + ksumP[2][lane]
                            + ksumP[3][lane] + 1e-6f);
    const float w = wS[lane] * kn;     // fold 1/||k|| into the v-weight
#pragma unroll
    for (int j = 0; j < 8; ++j) {
        kT[(wave * 16 + j) * TS + lane] = k0[j];
        kT[(wave * 16 + 8 + j) * TS + lane] = k1[j];
        vT[(wave * 16 + j) * TS + lane] = f2bf(bf2f((unsigned short)v0[j]) * w);
        vT[(wave * 16 + 8 + j) * TS + lane] = f2bf(bf2f((unsigned short)v1[j]) * w);
    }
    __syncthreads();

    const int lr = lane & 15, lk = lane >> 4;
    f32x4 acc[4] = {};
    const short* pA = vT + (wave * 16 + lr) * TS + lk * 8;
#pragma unroll
    for (int kk = 0; kk < 2; ++kk) {
        bf16x8 a = *(const bf16x8*)(pA + kk * 32);
#pragma unroll
        for (int n = 0; n < 4; ++n) {
            bf16x8 bfr = *(const bf16x8*)(kT + (n * 16 + lr) * TS + lk * 8 + kk * 32);
            acc[n] = __builtin_amdgcn_mfma_f32_16x16x32_bf16(a, bfr, acc[n], 0, 0, 0);
        }
    }
#pragma unroll
    for (int n = 0; n < 4; ++n) {
        float* op = dST + (size_t)cid * 4096 + (wave * 16 + lk * 4) * 64 + n * 16 + lr;
#pragma unroll
        for (int r = 0; r < 4; ++r)
            op[r * 64] = acc[n][r];
    }
}

// ---------------- phase 2: scan over chunks, IN PLACE (dST -> states) --------
__global__ __launch_bounds__(256)
void chunk_phase2(float* __restrict__ dST, const float* __restrict__ ac) {
    const int gid = blockIdx.x * 256 + threadIdx.x;  // B*H*4096 = 131072
    const int bh = gid >> 12;
    const int e = gid & 4095;
    float s = 0.f;
    for (int c = 0; c < NC_; ++c) {
        size_t off = (size_t)(bh * NC_ + c) * 4096 + e;
        float tmp = dST[off];
        dST[off] = s;
        s = fmaf(ac[bh * NC_ + c], s, tmp);
    }
}

// -- phase 3 (MFMA): O = exp(ct)*Q*S_in + P*V; q/k-l2norm + gated-RMSNorm fused --
__global__ __launch_bounds__(256)
void chunk_phase3(const unsigned short* __restrict__ qkvb,
                  const float* __restrict__ beta, const float* __restrict__ cum,
                  const float* __restrict__ states,   // dST layout [cid][v][d] fp32
                  const unsigned short* __restrict__ zb,
                  unsigned short* __restrict__ normb) {
    const int cid = blockIdx.x;
    const int c = cid & (NC_ - 1);
    const int bh = cid >> 5;
    const int b = bh >> 4, h = bh & 15;
    const int tid = threadIdx.x;
    const int wave = tid >> 6, lane = tid & 63;
    const int t0 = c * L_;

    __shared__ __align__(16) short vT[64 * TS];   // [v][s]
    __shared__ __align__(16) short sT[64 * TS];   // S_in^T bf16 [v][d]
    __shared__ __align__(16) short pS[64 * TS];   // P [t][s] bf16
    __shared__ float cumS[64], betaS[64];
    __shared__ float invq[64], invk[64];

    {   // stage vT (transpose)
        const unsigned short* rowp = qkvb + (size_t)(b * T_ + t0 + lane) * CD_ + 2 * D_ + h * HD_ + wave * 16;
        bf16x8 v0 = *(const bf16x8*)rowp;
        bf16x8 v1 = *(const bf16x8*)(rowp + 8);
#pragma unroll
        for (int j = 0; j < 8; ++j) {
            vT[(wave * 16 + j) * TS + lane] = v0[j];
            vT[(wave * 16 + 8 + j) * TS + lane] = v1[j];
        }
    }
    {   // stage sT (fp32 -> bf16)
        const float* sp = states + (size_t)cid * 4096 + (tid >> 2) * 64 + (tid & 3) * 16;
        short* dp = sT + (tid >> 2) * TS + (tid & 3) * 16;
#pragma unroll
        for (int j = 0; j < 16; j += 4) {
            float4 f = *(const float4*)(sp + j);
            dp[j] = f2bf(f.x); dp[j + 1] = f2bf(f.y);
            dp[j + 2] = f2bf(f.z); dp[j + 3] = f2bf(f.w);
        }
    }
    {   // per-row l2norm factors for q and k (4 threads per row)
        int row = tid >> 2;
        int seg = (tid & 3) << 4;   // 0,16,32,48
        const unsigned short* qr = qkvb + (size_t)(b * T_ + t0 + row) * CD_ + h * HD_ + seg;
        bf16x8 a0 = *(const bf16x8*)qr;
        bf16x8 a1 = *(const bf16x8*)(qr + 8);
        float sq = 0.f;
#pragma unroll
        for (int j = 0; j < 8; ++j) {
            float v = bf2f((unsigned short)a0[j]); sq = fmaf(v, v, sq);
            v = bf2f((unsigned short)a1[j]); sq = fmaf(v, v, sq);
        }
        sq += __shfl_xor(sq, 1, 64);
        sq += __shfl_xor(sq, 2, 64);
        const unsigned short* kr = qr + D_;
        bf16x8 b0 = *(const bf16x8*)kr;
        bf16x8 b1 = *(const bf16x8*)(kr + 8);
        float sk = 0.f;
#pragma unroll
        for (int j = 0; j < 8; ++j) {
            float v = bf2f((unsigned short)b0[j]); sk = fmaf(v, v, sk);
            v = bf2f((unsigned short)b1[j]); sk = fmaf(v, v, sk);
        }
        sk += __shfl_xor(sk, 1, 64);
        sk += __shfl_xor(sk, 2, 64);
        if ((tid & 3) == 0) {
            invq[row] = 0.125f * rsqrtf(sq + 1e-6f);   // includes HD^-0.5
            invk[row] = rsqrtf(sk + 1e-6f);
        }
    }
    if (tid < 64) {
        cumS[tid] = cum[(size_t)bh * T_ + t0 + tid];
        betaS[tid] = beta[(size_t)(b * T_ + t0 + tid) * H_ + h];
    }
    __syncthreads();

    const int lr = lane & 15, lk = lane >> 4;
    const unsigned short* qrow = qkvb + (size_t)(b * T_ + t0 + wave * 16 + lr) * CD_ + h * HD_;
    bf16x8 qf0 = *(const bf16x8*)(qrow + lk * 8);
    bf16x8 qf1 = *(const bf16x8*)(qrow + 32 + lk * 8);

    // QK^T on RAW q,k
    f32x4 pacc[4] = {};
#pragma unroll
    for (int n = 0; n < 4; ++n) {
        const unsigned short* krow = qkvb + (size_t)(b * T_ + t0 + n * 16 + lr) * CD_ + D_ + h * HD_;
        bf16x8 b0 = *(const bf16x8*)(krow + lk * 8);
        bf16x8 b1 = *(const bf16x8*)(krow + 32 + lk * 8);
        pacc[n] = __builtin_amdgcn_mfma_f32_16x16x32_bf16(qf0, b0, pacc[n], 0, 0, 0);
        pacc[n] = __builtin_amdgcn_mfma_f32_16x16x32_bf16(qf1, b1, pacc[n], 0, 0, 0);
    }
    // decay + mask + beta + norms -> pS (bf16)
#pragma unroll
    for (int n = 0; n < 4; ++n) {
        int s = n * 16 + lr;
        float cs = cumS[s], bsk = betaS[s] * invk[s];
#pragma unroll
        for (int r = 0; r < 4; ++r) {
            int t = wave * 16 + lk * 4 + r;
            float pv = (s <= t) ? expf(cumS[t] - cs) * bsk * pacc[n][r] * invq[t] : 0.f;
            pS[t * TS + s] = f2bf(pv);
        }
    }
    __syncthreads();

    // O = Q * S_in^T-frags (raw q, scaled after)
    f32x4 oacc[4] = {};
#pragma unroll
    for (int n = 0; n < 4; ++n) {
        const short* srow = sT + (n * 16 + lr) * TS + lk * 8;
        bf16x8 b0 = *(const bf16x8*)srow;
        bf16x8 b1 = *(const bf16x8*)(srow + 32);
        oacc[n] = __builtin_amdgcn_mfma_f32_16x16x32_bf16(qf0, b0, oacc[n], 0, 0, 0);
        oacc[n] = __builtin_amdgcn_mfma_f32_16x16x32_bf16(qf1, b1, oacc[n], 0, 0, 0);
    }
    float qsc[4];
#pragma unroll
    for (int r = 0; r < 4; ++r) {
        int t = wave * 16 + lk * 4 + r;
        qsc[r] = expf(cumS[t]) * invq[t];
    }
#pragma unroll
    for (int n = 0; n < 4; ++n)
#pragma unroll
        for (int r = 0; r < 4; ++r) oacc[n][r] *= qsc[r];
    // + P * V
    const short* prow = pS + (wave * 16 + lr) * TS + lk * 8;
    bf16x8 pf0 = *(const bf16x8*)prow;
    bf16x8 pf1 = *(const bf16x8*)(prow + 32);
#pragma unroll
    for (int n = 0; n < 4; ++n) {
        const short* vrow = vT + (n * 16 + lr) * TS + lk * 8;
        bf16x8 b0 = *(const bf16x8*)vrow;
        bf16x8 b1 = *(const bf16x8*)(vrow + 32);
        oacc[n] = __builtin_amdgcn_mfma_f32_16x16x32_bf16(pf0, b0, oacc[n], 0, 0, 0);
        oacc[n] = __builtin_amdgcn_mfma_f32_16x16x32_bf16(pf1, b1, oacc[n], 0, 0, 0);
    }

    // fused gated RMSNorm over head dim + bf16 store
#pragma unroll
    for (int r = 0; r < 4; ++r) {
        int t = wave * 16 + lk * 4 + r;
        float ss = 0.f;
#pragma unroll
        for (int n = 0; n < 4; ++n) ss = fmaf(oacc[n][r], oacc[n][r], ss);
        ss += __shfl_xor(ss, 1, 64);
        ss += __shfl_xor(ss, 2, 64);
        ss += __shfl_xor(ss, 4, 64);
        ss += __shfl_xor(ss, 8, 64);
        float inv = rsqrtf(ss * (1.f / 64.f) + 1e-6f);
        size_t rowoff = (size_t)(b * T_ + t0 + t) * D_ + h * HD_;
#pragma unroll
        for (int n = 0; n < 4; ++n) {
            float zv = bf2f(zb[rowoff + n * 16 + lr]);
            float sz = zv / (1.f + expf(-zv));
            normb[rowoff + n * 16 + lr] = f2bf(oacc[n][r] * inv * sz);
        }
    }
}

extern "C" void kernel_launch(void* const* d_in, const int* in_sizes, int n_in,
                              void* d_out, int out_size, void* d_ws, size_t ws_size,
                              hipStream_t stream) {
    const float* x       = (const float*)d_in[0];
    const float* W_qkv   = (const float*)d_in[1];
    const float* conv_w  = (const float*)d_in[2];
    const float* W_z     = (const float*)d_in[3];
    const float* W_b     = (const float*)d_in[4];
    const float* W_a     = (const float*)d_in[5];
    const float* dt_bias = (const float*)d_in[6];
    const float* A_log   = (const float*)d_in[7];
    const float* W_out   = (const float*)d_in[8];
    float* out = (float*)d_out;

    float* ws = (float*)d_ws;
    // Region A: mixedb (bf16) until conv; overlays after:
    unsigned short* mixedb = (unsigned short*)ws;              // 12.6M bf16 (25 MB)
    float* dST    = ws;                        // 4M floats (ph1 -> ph2 in-place -> ph3)
    unsigned short* normb = (unsigned short*)(ws + 4194304);   // 4.2M bf16 (ph3 output)
    float* betab  = ws + 8388608;              // 65,536
    float* gb     = ws + 8454144;              // 65,536
    float* cum    = ws + 8519680;              // 65,536
    float* ac     = ws + 8585216;              // 1,024
    unsigned short* Woutb = (unsigned short*)(ws + 8586240);   // 1M bf16
    // Region B: xb/Wqkvb/Wzb pre-conv; qkvb after
    unsigned short* xb    = (unsigned short*)(ws + 12582912);  // 4M bf16
    unsigned short* Wqkvb = (unsigned short*)(ws + 14680064);  // 3M bf16 (cat head)
    unsigned short* Wzb   = (unsigned short*)(ws + 16252928);  // 1M bf16 (cat tail)
    unsigned short* qkvb  = (unsigned short*)(ws + 12582912);  // 12.6M bf16
    // Region C
    unsigned short* zb    = (unsigned short*)(ws + 18874368);  // 4M bf16
    float* bgpart = ws + 23068672;             // 1M floats (4 MB)

    const int M = B_ * T_;                     // 4096
    dim3 blk(256);

    cvt_all<<<dim3(9216), blk, 0, stream>>>(x, W_qkv, W_z, W_out, xb, Wqkvb, Wzb, Woutb);

    gemm_qkvz256<<<dim3(256), dim3(512), 131072, stream>>>(xb, Wqkvb, mixedb, zb);

    conv_silu_tt<<<dim3(B_ * (T_ / TT) * (CD_ / 4) / 256), blk, 0, stream>>>(mixedb, conv_w, qkvb);

    proj_bg_partial<<<dim3(1024), blk, 0, stream>>>(x, W_b, W_a, bgpart);
    proj_bg_reduce<<<dim3(512), blk, 0, stream>>>(bgpart, dt_bias, A_log, betab, gb);

    chunk_phase1<<<dim3(B_ * H_ * NC_), blk, 0, stream>>>(qkvb, betab, gb, dST, cum, ac);
    chunk_phase2<<<dim3(B_ * H_ * 4096 / 256), blk, 0, stream>>>(dST, ac);
    chunk_phase3<<<dim3(B_ * H_ * NC_), blk, 0, stream>>>(qkvb, betab, cum, dST, zb, normb);

    gemm_out<<<dim3(256), blk, 0, stream>>>(normb, Woutb, out);
}